// Round 6
// baseline (10441.747 us; speedup 1.0000x reference)
//
#include <hip/hip_runtime.h>
#include <stdint.h>

// ===================== problem dimensions =====================
#define NT_   16
#define NRF_  4
#define K_    4
#define M_    2
#define B_    28
#define NOUT_ 120
#define NIN_  20
#define FN_   1792   // NT*B*NRF   (complex F elements)
#define WN_   896    // K*B*NRF*M  (complex W elements)
#define XN_   3584   // K*B*NT*M   (complex X elements)
#define TJOB_ 8704
#define TSZ_  (21*TJOB_)
// output float32 offsets (rates[28,121], taus[28,121], then F, W)
#define O_TAUS 3388
#define O_F    6776
#define O_W    10360
#define NWG_   28

typedef float2 cf;
__device__ __forceinline__ cf cmul(cf a, cf b){ return make_float2(a.x*b.x - a.y*b.y, a.x*b.y + a.y*b.x); }
__device__ __forceinline__ cf cmulc(cf a, cf b){ return make_float2(a.x*b.x + a.y*b.y, a.y*b.x - a.x*b.y); } // a*conj(b)
__device__ __forceinline__ cf cadd(cf a, cf b){ return make_float2(a.x + b.x, a.y + b.y); }
__device__ __forceinline__ cf csc(float s, cf a){ return make_float2(s*a.x, s*a.y); }
__device__ __forceinline__ cf shflc(cf v, int m){ return make_float2(__shfl_xor(v.x, m, 64), __shfl_xor(v.y, m, 64)); }

// ===================== threefry2x32 (JAX-compatible) =====================
__device__ __forceinline__ uint32_t rotl32(uint32_t x, int r){ return (x << r) | (x >> (32 - r)); }

__device__ __forceinline__ void threefry(uint32_t k0, uint32_t k1, uint32_t x0, uint32_t x1,
                                         uint32_t &o0, uint32_t &o1){
  uint32_t ks2 = k0 ^ k1 ^ 0x1BD11BDAu;
  x0 += k0; x1 += k1;
#define TF4(a,b,c,d) \
  x0 += x1; x1 = rotl32(x1,(a)); x1 ^= x0; \
  x0 += x1; x1 = rotl32(x1,(b)); x1 ^= x0; \
  x0 += x1; x1 = rotl32(x1,(c)); x1 ^= x0; \
  x0 += x1; x1 = rotl32(x1,(d)); x1 ^= x0;
  TF4(13,15,26,6)  x0 += k1;  x1 += ks2 + 1u;
  TF4(17,29,16,24) x0 += ks2; x1 += k0 + 2u;
  TF4(13,15,26,6)  x0 += k0;  x1 += k1 + 3u;
  TF4(17,29,16,24) x0 += k1;  x1 += ks2 + 4u;
  TF4(13,15,26,6)  x0 += ks2; x1 += k0 + 5u;
#undef TF4
  o0 = x0; o1 = x1;
}

__device__ __forceinline__ void ksplit(uint2 k, uint2 &ka, uint2 &kb){
  threefry(k.x, k.y, 0u, 0u, ka.x, ka.y);
  threefry(k.x, k.y, 0u, 1u, kb.x, kb.y);
}
__device__ __forceinline__ uint2 kfold(uint2 k, uint32_t d){
  uint2 r; threefry(k.x, k.y, 0u, d, r.x, r.y); return r;
}
__device__ __forceinline__ uint32_t rbits(uint2 k, uint32_t i){
  uint32_t a, b; threefry(k.x, k.y, 0u, i, a, b); return a ^ b;
}

__device__ __forceinline__ float bits_to_unit(uint32_t b){
  return __uint_as_float((b >> 9) | 0x3f800000u) - 1.0f;  // [0,1)
}

// XLA (Giles 2012) float32 erf_inv
__device__ __forceinline__ float erfinv_f32(float x){
  float w = -log1pf(-x * x);
  float p;
  if (w < 5.0f){
    w = w - 2.5f;
    p =  2.81022636e-08f;
    p = fmaf(p, w,  3.43273939e-07f);
    p = fmaf(p, w, -3.5233877e-06f);
    p = fmaf(p, w, -4.39150654e-06f);
    p = fmaf(p, w,  0.00021858087f);
    p = fmaf(p, w, -0.00125372503f);
    p = fmaf(p, w, -0.00417768164f);
    p = fmaf(p, w,  0.246640727f);
    p = fmaf(p, w,  1.50140941f);
  } else {
    w = sqrtf(w) - 3.0f;
    p = -0.000200214257f;
    p = fmaf(p, w,  0.000100950558f);
    p = fmaf(p, w,  0.00134934322f);
    p = fmaf(p, w, -0.00367342844f);
    p = fmaf(p, w,  0.00573950773f);
    p = fmaf(p, w, -0.0076224613f);
    p = fmaf(p, w,  0.00943887047f);
    p = fmaf(p, w,  1.00167406f);
    p = fmaf(p, w,  2.83297682f);
  }
  return p * x;
}

#define SQRT2F 1.41421356f

__device__ __forceinline__ float normal_from_bits(uint32_t b){
  const float lo = -0.99999994f;              // nextafter(-1, 0) in f32
  float u = bits_to_unit(b);
  float v = fmaxf(lo, u * 2.0f + lo);
  return SQRT2F * erfinv_f32(v);
}

__device__ __forceinline__ cf cnormal(uint2 kre, uint2 kim, uint32_t e){
  float re = normal_from_bits(rbits(kre, e));
  float im = normal_from_bits(rbits(kim, e));
  return make_float2(re / SQRT2F, im / SQRT2F);
}

__device__ void noise_key_chain(uint32_t it, uint2 *out){
  uint2 k = kfold(make_uint2(0u, 7u), it);    // fold_in(key(7), it)
  for (int j = 0; j < NIN_; ++j){
    uint2 kk, kn;
    ksplit(k, kk, kn);
    k = kk;
    ksplit(kn, out[2*j], out[2*j + 1]);
  }
  uint2 k2, knW;
  ksplit(k, k2, knW);
  ksplit(knW, out[40], out[41]);
}

// ===================== setup kernel =====================
__global__ __launch_bounds__(1024)
void rng_kernel(float2* __restrict__ wsF, float2* __restrict__ wsW,
                float2* __restrict__ wsIW,
                float* __restrict__ wsT, float* __restrict__ wsU,
                float* __restrict__ wsC, float2* __restrict__ wsFst,
                float2* __restrict__ wsWst,
                const float* __restrict__ H_re, const float* __restrict__ H_im,
                const float* __restrict__ R_re, const float* __restrict__ R_im,
                const float* __restrict__ qF_qw, const float* __restrict__ qW_qw,
                const float* __restrict__ qF_W1, const float* __restrict__ qF_W2,
                const float* __restrict__ qF_W3, const float* __restrict__ qF_Wp,
                const float* __restrict__ qW_W1, const float* __restrict__ qW_W2,
                const float* __restrict__ qW_W3, const float* __restrict__ qW_Wp){
  __shared__ uint2 keys[42];
  const int bi = blockIdx.x, t = threadIdx.x;
  if (bi < NOUT_){
    if (t == 0) noise_key_chain((uint32_t)bi, keys);
    __syncthreads();
    for (int idx = t; idx < NIN_*FN_; idx += blockDim.x){
      int j = idx / FN_, e = idx - j*FN_;
      wsF[(size_t)bi*(NIN_*FN_) + idx] = cnormal(keys[2*j], keys[2*j + 1], (uint32_t)e);
    }
    for (int e = t; e < WN_; e += blockDim.x)
      wsW[(size_t)bi*WN_ + e] = cnormal(keys[40], keys[41], (uint32_t)e);
  } else if (bi == NOUT_){
    if (t == 0){
      uint2 k1, k2;
      ksplit(make_uint2(0u, 1u), k1, k2);
      keys[0] = k1;
      ksplit(k2, keys[1], keys[2]);
    }
    __syncthreads();
    const float TWOPI = 6.28318530717958647692f;
    for (int e = t; e < FN_; e += blockDim.x){
      float u = bits_to_unit(rbits(keys[0], (uint32_t)e));
      float ph = fmaxf(0.0f, u * TWOPI);
      float s, c; sincosf(ph, &s, &c);
      wsFst[e] = make_float2(c, s);
    }
    for (int e = t; e < WN_; e += blockDim.x){
      cf w = cnormal(keys[1], keys[2], (uint32_t)e);
      wsIW[e] = w;
      wsWst[e] = w;
    }
  } else if (bi < NOUT_ + 1 + 21){
    const int j = bi - (NOUT_ + 1);
    const bool isW = (j == 20);
    const float* W1 = isW ? qW_W1 : qF_W1 + j*(64*80);
    const float* W2 = isW ? qW_W2 : qF_W2 + j*(32*64);
    const float* W3 = isW ? qW_W3 : qF_W3 + j*(16*32);
    const float* Wp = isW ? qW_Wp : qF_Wp + j*(128*8);
    float* dst = wsT + j*TJOB_;
    for (int idx = t; idx < 5120; idx += blockDim.x){
      int q = idx >> 6, i = idx & 63;
      dst[idx] = W1[i*80 + q];
    }
    for (int idx = t; idx < 2048; idx += blockDim.x){
      int q = idx >> 5, i = idx & 31;
      dst[5120 + idx] = W2[i*64 + q];
    }
    for (int idx = t; idx < 512; idx += blockDim.x){
      int q = idx >> 4, i = idx & 15;
      dst[7168 + idx] = W3[i*32 + q];
    }
    const int nOut = isW ? 64 : 128;
    for (int idx = t; idx < 8*nOut; idx += blockDim.x){
      int z = idx / nOut, o = idx - z*nOut;
      dst[7680 + z*128 + o] = Wp[o*8 + z];
    }
  } else {
    if (t < 504){
      int j = t / 24, gg = t - j*24;
      const float* qw = (j == 20) ? qW_qw : qF_qw + j*72;
      float phi = qw[gg*3], th = qw[gg*3 + 1], om = qw[gg*3 + 2];
      float sh, ch; sincosf(0.5f*th, &sh, &ch);
      float sp, cp; sincosf(0.5f*(phi + om), &sp, &cp);
      float sm, cm; sincosf(0.5f*(phi - om), &sm, &cm);
      float* u = wsU + t*8;
      u[0] =  ch*cp; u[1] = -ch*sp;
      u[2] = -sh*cm; u[3] = -sh*sm;
      u[4] =  sh*cm; u[5] = -sh*sm;
      u[6] =  ch*cp; u[7] =  ch*sp;
    } else if (t < 520){
      int n = t - 504;
      float s = 0.f;
      for (int kbm = 0; kbm < 224; ++kbm){
        float re = H_re[kbm*16 + n], im = H_im[kbm*16 + n];
        s += sqrtf(re*re + im*im);
      }
      wsC[n] = s * (1.0f/224.0f);
    } else if (t < 776){
      int nv = t - 520;
      float s = 0.f;
      for (int kb = 0; kb < 112; ++kb){
        float re = R_re[kb*256 + nv], im = R_im[kb*256 + nv];
        s += sqrtf(re*re + im*im);
      }
      wsC[16 + nv] = s * (1.0f/112.0f);
    }
  }
}

// ===================== 8-qubit circuit =====================
__device__ __forceinline__ void gate(int q, cf u00, cf u01, cf u10, cf u11,
                                     cf &a0, cf &a1, cf &a2, cf &a3, int lane){
  if (q == 7){
    cf n0 = cadd(cmul(u00, a0), cmul(u01, a1));
    cf n1 = cadd(cmul(u10, a0), cmul(u11, a1));
    cf n2 = cadd(cmul(u00, a2), cmul(u01, a3));
    cf n3 = cadd(cmul(u10, a2), cmul(u11, a3));
    a0 = n0; a1 = n1; a2 = n2; a3 = n3;
  } else if (q == 6){
    cf n0 = cadd(cmul(u00, a0), cmul(u01, a2));
    cf n2 = cadd(cmul(u10, a0), cmul(u11, a2));
    cf n1 = cadd(cmul(u00, a1), cmul(u01, a3));
    cf n3 = cadd(cmul(u10, a1), cmul(u11, a3));
    a0 = n0; a1 = n1; a2 = n2; a3 = n3;
  } else {
    const int m = 1 << (5 - q);
    const bool hi = (lane & m) != 0;
    cf cO = hi ? u11 : u00;
    cf cP = hi ? u10 : u01;
    cf p0 = shflc(a0, m), p1 = shflc(a1, m), p2 = shflc(a2, m), p3 = shflc(a3, m);
    a0 = cadd(cmul(cO, a0), cmul(cP, p0));
    a1 = cadd(cmul(cO, a1), cmul(cP, p1));
    a2 = cadd(cmul(cO, a2), cmul(cP, p2));
    a3 = cadd(cmul(cO, a3), cmul(cP, p3));
  }
}

__device__ void run_circuit2(const float* trig, const float* uni, int lane, float z[8]){
  cf a0 = make_float2(lane == 0 ? 1.f : 0.f, 0.f);
  cf a1 = make_float2(0.f, 0.f), a2 = make_float2(0.f, 0.f), a3 = make_float2(0.f, 0.f);
  #pragma unroll
  for (int i = 0; i < 8; ++i){
    float sh = trig[2*i],      ch = trig[2*i + 1];
    float sp = trig[16 + 2*i], cp = trig[16 + 2*i + 1];
    float sm = trig[32 + 2*i], cm = trig[32 + 2*i + 1];
    cf u00 = make_float2( ch*cp, -ch*sp);
    cf u11 = make_float2( ch*cp,  ch*sp);
    cf u01 = make_float2(-sh*cm, -sh*sm);
    cf u10 = make_float2( sh*cm, -sh*sm);
    gate(i, u00, u01, u10, u11, a0, a1, a2, a3, lane);
  }
  for (int l = 0; l < 3; ++l){
    #pragma unroll
    for (int i = 0; i < 8; ++i){
      const float* u = uni + (l*8 + i)*8;
      gate(i, make_float2(u[0], u[1]), make_float2(u[2], u[3]),
              make_float2(u[4], u[5]), make_float2(u[6], u[7]), a0, a1, a2, a3, lane);
    }
    #pragma unroll
    for (int i = 0; i < 5; ++i){
      const int cm_ = 1 << (5 - i), tm = 1 << (4 - i);
      const bool c = (lane & cm_) != 0;
      cf p0 = shflc(a0, tm), p1 = shflc(a1, tm), p2 = shflc(a2, tm), p3 = shflc(a3, tm);
      a0 = c ? p0 : a0; a1 = c ? p1 : a1; a2 = c ? p2 : a2; a3 = c ? p3 : a3;
    }
    {
      const bool c = (lane & 1) != 0;
      cf t0 = c ? a2 : a0, t2 = c ? a0 : a2;
      cf t1 = c ? a3 : a1, t3 = c ? a1 : a3;
      a0 = t0; a1 = t1; a2 = t2; a3 = t3;
    }
    { cf tmp = a2; a2 = a3; a3 = tmp; }
    a1 = shflc(a1, 32);
    a3 = shflc(a3, 32);
  }
  const float p0 = a0.x*a0.x + a0.y*a0.y;
  const float p1 = a1.x*a1.x + a1.y*a1.y;
  const float p2 = a2.x*a2.x + a2.y*a2.y;
  const float p3 = a3.x*a3.x + a3.y*a3.y;
  const float tot = p0 + p1 + p2 + p3;
  z[6] = (p0 + p1) - (p2 + p3);
  z[7] = (p0 + p2) - (p1 + p3);
  #pragma unroll
  for (int i = 0; i < 6; ++i)
    z[i] = ((lane >> (5 - i)) & 1) ? -tot : tot;
  #pragma unroll
  for (int m = 1; m < 64; m <<= 1){
    #pragma unroll
    for (int i = 0; i < 8; ++i) z[i] += __shfl_xor(z[i], m, 64);
  }
}

// ===================== grid barrier (device-scope, monotonic counter) =====================
__device__ __forceinline__ void grid_barrier(uint32_t* cnt, uint32_t &barIdx){
  __syncthreads();
  if (threadIdx.x == 0){
    __threadfence();     // publish prior writes device-wide (cross-XCD)
    barIdx += 1;
    __hip_atomic_fetch_add(cnt, 1u, __ATOMIC_ACQ_REL, __HIP_MEMORY_SCOPE_AGENT);
    const uint32_t target = (uint32_t)NWG_ * barIdx;
    while (__hip_atomic_load(cnt, __ATOMIC_ACQUIRE, __HIP_MEMORY_SCOPE_AGENT) < target){
      __builtin_amdgcn_s_sleep(1);
    }
    __threadfence();     // acquire side
  }
  __syncthreads();
}

// ===================== persistent kernel: whole 120-iteration loop =====================
__global__ __launch_bounds__(128)
void persist(const float* __restrict__ H_re, const float* __restrict__ H_im,
             const float* __restrict__ R_re, const float* __restrict__ R_im,
             const float* __restrict__ Pt_p, const float* __restrict__ step_p,
             const float* __restrict__ qF_b1, const float* __restrict__ qF_b2,
             const float* __restrict__ qF_b3, const float* __restrict__ qF_bp,
             const float* __restrict__ qW_b1, const float* __restrict__ qW_b2,
             const float* __restrict__ qW_b3, const float* __restrict__ qW_bp,
             const float* __restrict__ projW, const float* __restrict__ projB,
             const float2* __restrict__ wsF, const float2* __restrict__ wsW,
             const float* __restrict__ wsT, const float* __restrict__ wsU,
             const float* __restrict__ wsC,
             const float2* __restrict__ wsFst, const float2* __restrict__ wsWst,
             float2* __restrict__ wsdF, float2* __restrict__ wsdW,
             float* __restrict__ wsFeatA, float* __restrict__ wsFeatG,
             float* __restrict__ wsPart,
             uint32_t* __restrict__ bar,
             float* __restrict__ out, int fmode)
{
  const int wg = blockIdx.x;
  const int b  = wg;
  const int t  = threadIdx.x;
  uint32_t barIdx = 0;

  // persistent per-b state
  __shared__ cf lF[64];
  __shared__ cf lW[32];
  __shared__ cf lX[128];
  __shared__ float scrA[96], scrG[96];
  __shared__ float red2[2];
  __shared__ float sscale;
  __shared__ float heR[16], heI[16];
  __shared__ float sKBl[4], sKB2l[4];
  // qblock-phase arrays
  __shared__ float sS[500];
  __shared__ float sSt[80];
  __shared__ float mlp[160];
  __shared__ float luni[192];

  const float c1 = step_p[0] * 0.001f;
  const float Ptv = Pt_p[0];

  // hoist constant unitaries for this WG's job
  if (wg < 21){
    for (int i = t; i < 192; i += 128) luni[i] = wsU[wg*192 + i];
  }

  // ---- load initial F/W slice
  if (t < 64){
    const int n = t >> 2, r = t & 3;
    lF[t] = wsFst[n*112 + b*4 + r];
  } else if (t < 96){
    const int wi = t - 64;
    const int k = wi >> 3, ru = wi & 7;
    lW[wi] = wsWst[(k*28 + b)*8 + ru];
  }
  __syncthreads();

  for (int it = -1; it < NOUT_; ++it){
    // ================= phase A: qblock (skipped for it == -1) =================
    if (it >= 0){
      if (wg < 21){
        // assemble sS[500]
        if (t < 112){ sS[t] = wsFeatA[t]; sS[112 + t] = wsFeatG[t]; }
        if (t < 4){
          float s = 0.f;
          for (int bb = 0; bb < 28; ++bb) s += wsPart[bb*4 + t];
          sS[224 + t] = s * (1.0f/448.0f);
        }
        for (int i = t; i < 272; i += 128) sS[228 + i] = wsC[i];
        __syncthreads();
        // projection: identical per-output order as before (8 lanes, stride 8)
        for (int round = 0; round < 5; ++round){
          int o = round*16 + (t >> 3), i = t & 7;
          const float* row = projW + o*500;
          float acc = 0.f;
          for (int j2 = i; j2 < 500; j2 += 8) acc = fmaf(sS[j2], row[j2], acc);
          #pragma unroll
          for (int m = 1; m < 8; m <<= 1) acc += __shfl_xor(acc, m, 64);
          if (i == 0) sSt[o] = acc + projB[o];
        }
        __syncthreads();
        // wave 0: MLP + circuit
        if (t < 64){
          const int lane = t;
          const int j = wg;
          const bool isW = (j == 20);
          const float* b1 = isW ? qW_b1 : qF_b1 + j*64;
          const float* b2 = isW ? qW_b2 : qF_b2 + j*32;
          const float* b3 = isW ? qW_b3 : qF_b3 + j*16;
          const float* bp = isW ? qW_bp : qF_bp + j*128;
          const float* w1t = wsT + j*TJOB_;
          const float* w2t = w1t + 5120;
          const float* w3t = w1t + 7168;
          const float* wpt = w1t + 7680;
          { // h1[64]
            float acc = b1[lane];
            for (int q = 0; q < 80; ++q) acc = fmaf(w1t[q*64 + lane], sSt[q], acc);
            mlp[lane] = tanhf(acc);
          }
          __builtin_amdgcn_wave_barrier();
          { // h2[32]
            int i2 = lane & 31;
            float acc = b2[i2];
            for (int q = 0; q < 64; ++q) acc = fmaf(w2t[q*32 + i2], mlp[q], acc);
            float h2 = tanhf(acc);
            __builtin_amdgcn_wave_barrier();
            if (lane < 32) mlp[64 + lane] = h2;
          }
          __builtin_amdgcn_wave_barrier();
          { // ang[16]
            int i3 = lane & 15;
            float acc = b3[i3];
            for (int q = 0; q < 32; ++q) acc = fmaf(w3t[q*16 + i3], mlp[64 + q], acc);
            __builtin_amdgcn_wave_barrier();
            if (lane < 16) mlp[96 + lane] = acc;
          }
          __builtin_amdgcn_wave_barrier();
          if (lane < 24){
            int i = lane & 7, which = lane >> 3;
            float th = mlp[96 + i], om = mlp[96 + 8 + i];
            float arg = (which == 0) ? 0.5f*th
                      : (which == 1) ? 0.5f*(0.f + om)
                                     : 0.5f*(0.f - om);
            float s, c; sincosf(arg, &s, &c);
            mlp[112 + which*16 + 2*i]     = s;
            mlp[112 + which*16 + 2*i + 1] = c;
          }
          __builtin_amdgcn_wave_barrier();
          float z[8];
          run_circuit2(mlp + 112, luni, lane, z);
          if (!isW){
            float o0 = bp[lane];
            float o1 = bp[64 + lane];
            #pragma unroll
            for (int i = 0; i < 8; ++i){
              o0 = fmaf(wpt[i*128 + lane],      z[i], o0);
              o1 = fmaf(wpt[i*128 + 64 + lane], z[i], o1);
            }
            __builtin_amdgcn_wave_barrier();
            mlp[lane] = o0; mlp[64 + lane] = o1;
            __builtin_amdgcn_wave_barrier();
            wsdF[j*64 + lane] = make_float2(mlp[2*lane], mlp[2*lane + 1]);
          } else {
            float o0 = bp[lane];
            #pragma unroll
            for (int i = 0; i < 8; ++i) o0 = fmaf(wpt[i*128 + lane], z[i], o0);
            __builtin_amdgcn_wave_barrier();
            mlp[lane] = o0;
            __builtin_amdgcn_wave_barrier();
            if (lane < 32) wsdW[lane] = make_float2(mlp[2*lane], mlp[2*lane + 1]);
          }
        }
      }
      grid_barrier(bar, barIdx);   // dF/dW published
    }

    // ================= phase B: update + normalize + X + metrics + features =================
    if (t < 64){
      cf F = lF[t];
      if (it >= 0){
        const float2* np = wsF + (size_t)it*(NIN_*FN_);
        const int e = (t >> 2)*112 + b*4 + (t & 3);
        cf nzA[10], dvA[10], nzB[10], dvB[10];
        #pragma unroll
        for (int s = 0; s < 10; ++s){ nzA[s] = np[s*FN_ + e];        dvA[s] = wsdF[s*64 + t]; }
        #pragma unroll
        for (int s = 0; s < 10; ++s){ nzB[s] = np[(10 + s)*FN_ + e]; dvB[s] = wsdF[(10 + s)*64 + t]; }
        #pragma unroll
        for (int s = 0; s < 10; ++s){
          F.x = F.x + c1*nzA[s].x + 0.001f*dvA[s].x;
          F.y = F.y + c1*nzA[s].y + 0.001f*dvA[s].y;
          float rr = sqrtf(F.x*F.x + F.y*F.y) + 1e-12f;
          F.x /= rr; F.y /= rr;
        }
        #pragma unroll
        for (int s = 0; s < 10; ++s){
          F.x = F.x + c1*nzB[s].x + 0.001f*dvB[s].x;
          F.y = F.y + c1*nzB[s].y + 0.001f*dvB[s].y;
          float rr = sqrtf(F.x*F.x + F.y*F.y) + 1e-12f;
          F.x /= rr; F.y /= rr;
        }
      }
      // _normalize F
      float rr = sqrtf(F.x*F.x + F.y*F.y) + 1e-12f;
      F.x /= rr; F.y /= rr;
      lF[t] = F;
    } else if (t < 96){
      const int wi = t - 64;
      cf w = lW[wi];
      if (it >= 0){
        const int k = wi >> 3, ru = wi & 7;
        const int ew = (k*28 + b)*8 + ru;
        cf nw = wsW[(size_t)it*WN_ + ew];
        cf dw = wsdW[k*8 + ru];
        w.x = w.x + c1*nw.x + 0.001f*dw.x;
        w.y = w.y + c1*nw.y + 0.001f*dw.y;
      }
      lW[wi] = w;
    }
    __syncthreads();
    // X[k,n,u] = sum_r F[n,r] W[k,r,u]
    {
      int u = t & 1, n = (t >> 1) & 15, k = t >> 5;
      const cf* fr = lF + n*4;
      const cf* wr = lW + k*8 + u;
      cf acc = cmul(fr[0], wr[0]);
      acc = cadd(acc, cmul(fr[1], wr[2]));
      acc = cadd(acc, cmul(fr[2], wr[4]));
      acc = cadd(acc, cmul(fr[3], wr[6]));
      lX[t] = acc;
    }
    __syncthreads();
    {
      float s = lX[t].x*lX[t].x + lX[t].y*lX[t].y;
      #pragma unroll
      for (int m = 1; m < 64; m <<= 1) s += __shfl_xor(s, m, 64);
      if ((t & 63) == 0) red2[t >> 6] = s;
    }
    __syncthreads();
    if (t == 0) sscale = sqrtf(Ptv / ((red2[0] + red2[1]) + 1e-12f));
    __syncthreads();
    const float sc = sscale;
    if (t < 32) lW[t] = csc(sc, lW[t]);
    lX[t] = csc(sc, lX[t]);
    __syncthreads();
    // He entries
    if (t < 16){
      const int k = t >> 2, ent = t & 3;
      const int m = ent >> 1, u = ent & 1;
      const float* hr = H_re + (k*28 + b)*32 + m*16;
      const float* hi = H_im + (k*28 + b)*32 + m*16;
      cf He = make_float2(0.f, 0.f);
      for (int n = 0; n < 16; ++n){
        cf h = make_float2(hr[n], hi[n]);
        He = cadd(He, cmul(h, lX[k*32 + n*2 + u]));
      }
      heR[t] = He.x; heI[t] = He.y;
    }
    __builtin_amdgcn_wave_barrier();
    if (t < 4){
      const int k = t;
      cf He00 = make_float2(heR[k*4 + 0], heI[k*4 + 0]);
      cf He01 = make_float2(heR[k*4 + 1], heI[k*4 + 1]);
      cf He10 = make_float2(heR[k*4 + 2], heI[k*4 + 2]);
      cf He11 = make_float2(heR[k*4 + 3], heI[k*4 + 3]);
      cf G00 = cadd(cmulc(He00, He00), cmulc(He01, He01));
      cf G01 = cadd(cmulc(He00, He10), cmulc(He01, He11));
      cf G10 = cadd(cmulc(He10, He00), cmulc(He11, He01));
      cf G11 = cadd(cmulc(He10, He10), cmulc(He11, He11));
      cf A00 = make_float2(1.f + Ptv*G00.x, Ptv*G00.y);
      cf A01 = csc(Ptv, G01);
      cf A10 = csc(Ptv, G10);
      cf A11 = make_float2(1.f + Ptv*G11.x, Ptv*G11.y);
      float detre = (A00.x*A11.x - A00.y*A11.y) - (A01.x*A10.x - A01.y*A10.y);
      sKBl[k] = log2f(fabsf(detre) + 1e-12f);
    }
    // beam error
    {
      const int k = t >> 5, i = t & 31;
      const float* rr = R_re + (k*28 + b)*256;
      const float* ri = R_im + (k*28 + b)*256;
      float acc = 0.f;
      #pragma unroll
      for (int c = 0; c < 8; ++c){
        int nv = c*32 + i;
        int n = nv >> 4, v = nv & 15;
        cf xn0 = lX[k*32 + n*2], xn1 = lX[k*32 + n*2 + 1];
        cf xv0 = lX[k*32 + v*2], xv1 = lX[k*32 + v*2 + 1];
        cf C = cadd(cmulc(xn0, xv0), cmulc(xn1, xv1));
        float dr = C.x - rr[nv], di = C.y - ri[nv];
        acc += dr*dr + di*di;
      }
      #pragma unroll
      for (int m = 1; m < 32; m <<= 1) acc += __shfl_xor(acc, m, 64);
      if (i == 0) sKB2l[k] = sqrtf(acc + 1e-12f);
    }
    __syncthreads();
    if (t == 0){
      const int slot = it + 1;
      out[b*121 + slot] = sKBl[0] + sKBl[1] + sKBl[2] + sKBl[3];
      out[O_TAUS + b*121 + slot] = 0.25f*(sKB2l[0] + sKB2l[1] + sKB2l[2] + sKB2l[3]);
    }
    // ---- state features for next iteration (from normalized lF, scaled lW)
    if (it < NOUT_ - 1){
      if (t < 64){
        cf f = lF[t];
        scrA[t] = sqrtf(f.x*f.x + f.y*f.y);
        scrG[t] = atan2f(f.y, f.x);
      } else if (t < 96){
        cf w = lW[t - 64];
        scrA[t] = sqrtf(w.x*w.x + w.y*w.y);
        scrG[t] = atan2f(w.y, w.x);
      }
      __syncthreads();
      if (t < 8){
        int r = t & 3;
        const float* src = (t < 4) ? scrA : scrG;
        float s = 0.f;
        for (int n = 0; n < 16; ++n) s += src[n*4 + r];
        float* dst = (t < 4) ? wsFeatA : wsFeatG;
        dst[b*4 + r] = s * (1.0f/16.0f);
      } else if (t >= 8 && t < 12){
        int tt = t - 8;
        int u = tt & 1; bool isG = tt >= 2;
        const float* src = isG ? scrG : scrA;
        float s = 0.f;
        for (int i = 0; i < 16; ++i) s += src[64 + i*2 + u];
        wsPart[b*4 + tt] = s;
      }
    }
    grid_barrier(bar, barIdx);   // state/features published
  }

  // ---- final F/W output (each WG writes its own slice)
  if (t < 64){
    const int n = t >> 2, r = t & 3;
    const int e = n*112 + b*4 + r;
    cf f = lF[t];
    if (fmode == 1){
      out[O_F + e] = f.x; out[O_F + FN_ + e] = f.y;
    } else if (fmode == 2){
      out[O_F + e] = f.x;
    } else {
      out[O_F + 2*e] = f.x; out[O_F + 2*e + 1] = f.y;
    }
  } else if (t < 96){
    const int wi = t - 64;
    const int k = wi >> 3, ru = wi & 7;
    const int e = (k*28 + b)*8 + ru;
    cf w = lW[wi];
    if (fmode == 1){
      out[O_W + e] = w.x; out[O_W + WN_ + e] = w.y;
    } else if (fmode == 2){
      out[O_F + FN_ + e] = w.x;
    } else {
      out[O_W + 2*e] = w.x; out[O_W + 2*e + 1] = w.y;
    }
  }
}

// ===================== fallback: single-WG monolith (used only if ws too small) =====================
__global__ __launch_bounds__(1024)
void main_kernel(const float* __restrict__ H_re, const float* __restrict__ H_im,
                 const float* __restrict__ R_re, const float* __restrict__ R_im,
                 const float* __restrict__ Pt_p, const float* __restrict__ step_p,
                 const float* __restrict__ qF_W1, const float* __restrict__ qF_b1,
                 const float* __restrict__ qF_W2, const float* __restrict__ qF_b2,
                 const float* __restrict__ qF_W3, const float* __restrict__ qF_b3,
                 const float* __restrict__ qF_qw, const float* __restrict__ qF_Wp,
                 const float* __restrict__ qF_bp,
                 const float* __restrict__ qW_W1, const float* __restrict__ qW_b1,
                 const float* __restrict__ qW_W2, const float* __restrict__ qW_b2,
                 const float* __restrict__ qW_W3, const float* __restrict__ qW_b3,
                 const float* __restrict__ qW_qw, const float* __restrict__ qW_Wp,
                 const float* __restrict__ qW_bp,
                 const float* __restrict__ projW, const float* __restrict__ projB,
                 float* __restrict__ out, int fmode)
{
  const int t = threadIdx.x;
  const int lane = t & 63;
  const int wv = t >> 6;

  __shared__ cf sF[FN_];
  __shared__ cf sW[WN_];
  __shared__ float sS[500];
  __shared__ float sSt[80];
  __shared__ float sScale[B_];
  __shared__ float sKB[112];
  __shared__ float sKB2[112];
  __shared__ float sRed[64];
  __shared__ uint2 sKeys[42];
  __shared__ float sPar[2];
  __shared__ float sUni[21*24*8];
  __shared__ __align__(16) unsigned char uPool[XN_ * sizeof(cf)];
  cf*    sX   = (cf*)uPool;
  cf*    sdF  = (cf*)uPool;
  cf*    sdW  = (cf*)(uPool + NIN_*64*sizeof(cf));
  float* sMLP = (float*)(uPool + NIN_*64*sizeof(cf) + 32*sizeof(cf));

  if (t == 0){ sPar[0] = step_p[0]; sPar[1] = Pt_p[0]; }

  if (t < 504){
    int j = t / 24, gg = t - j*24;
    const float* qw = (j == 20) ? qW_qw : qF_qw + j*72;
    float phi = qw[gg*3], th = qw[gg*3 + 1], om = qw[gg*3 + 2];
    float sh, ch; sincosf(0.5f*th, &sh, &ch);
    float sp, cp; sincosf(0.5f*(phi + om), &sp, &cp);
    float sm, cm; sincosf(0.5f*(phi - om), &sm, &cm);
    float* u = sUni + t*8;
    u[0] =  ch*cp; u[1] = -ch*sp;
    u[2] = -sh*cm; u[3] = -sh*sm;
    u[4] =  sh*cm; u[5] = -sh*sm;
    u[6] =  ch*cp; u[7] =  ch*sp;
  }

  {
    float* scratch = (float*)uPool;
    float local = 0.f;
    for (int i = t; i < 3584; i += 1024) local += sqrtf(H_re[i]*H_re[i] + H_im[i]*H_im[i]);
    scratch[t] = local;
    __syncthreads();
    for (int s = 512; s >= 16; s >>= 1){
      if (t < s) scratch[t] += scratch[t + s];
      __syncthreads();
    }
    if (t < 16) sS[228 + t] = scratch[t] * (1.0f/224.0f);
    __syncthreads();
    local = 0.f;
    for (int i = t; i < 28672; i += 1024) local += sqrtf(R_re[i]*R_re[i] + R_im[i]*R_im[i]);
    scratch[t] = local;
    __syncthreads();
    for (int s = 512; s >= 256; s >>= 1){
      if (t < s) scratch[t] += scratch[t + s];
      __syncthreads();
    }
    if (t < 256) sS[244 + t] = scratch[t] * (1.0f/112.0f);
    __syncthreads();
  }

  {
    if (t == 0){
      uint2 k1, k2; ksplit(make_uint2(0u, 1u), k1, k2);
      sKeys[0] = k1; ksplit(k2, sKeys[1], sKeys[2]);
    }
    __syncthreads();
    const float TWOPI = 6.28318530717958647692f;
    for (int e = t; e < FN_; e += 1024){
      float u = bits_to_unit(rbits(sKeys[0], (uint32_t)e));
      float ph = fmaxf(0.0f, u * TWOPI);
      float s, c; sincosf(ph, &s, &c);
      sF[e] = make_float2(c, s);
    }
    for (int e = t; e < WN_; e += 1024) sW[e] = cnormal(sKeys[1], sKeys[2], (uint32_t)e);
  }
  __syncthreads();

  const float stepv = sPar[0], Ptv = sPar[1];
  const float c1 = stepv * 0.001f;

  for (int it = -1; it < NOUT_; ++it){
    if (it >= 0){
      if (t == 0) noise_key_chain((uint32_t)it, sKeys);
      __syncthreads();
      if (t < 112){
        float sa = 0.f, sg = 0.f;
        for (int n = 0; n < NT_; ++n){
          cf f = sF[n*112 + t];
          sa += sqrtf(f.x*f.x + f.y*f.y);
          sg += atan2f(f.y, f.x);
        }
        sS[t]       = sa * (1.0f/16.0f);
        sS[112 + t] = sg * (1.0f/16.0f);
      }
      {
        float aW = 0.f, gW = 0.f;
        if (t < WN_){
          cf w = sW[t];
          aW = sqrtf(w.x*w.x + w.y*w.y);
          gW = atan2f(w.y, w.x);
        }
        #pragma unroll
        for (int m = 2; m < 64; m <<= 1){
          aW += __shfl_xor(aW, m, 64);
          gW += __shfl_xor(gW, m, 64);
        }
        if (t < WN_ && lane < 2){
          sRed[wv*2 + lane] = aW;
          sRed[32 + wv*2 + lane] = gW;
        }
      }
      __syncthreads();
      if (t < 4){
        int u = t & 1;
        int base = (t >= 2) ? 32 : 0;
        float s = 0.f;
        for (int w = 0; w < 14; ++w) s += sRed[base + w*2 + u];
        sS[224 + t] = s * (1.0f/448.0f);
      }
      __syncthreads();
      if (t < 640){
        int o = t >> 3, i = t & 7;
        const float* row = projW + o*500;
        float acc = 0.f;
        for (int j = i; j < 500; j += 8) acc = fmaf(sS[j], row[j], acc);
        #pragma unroll
        for (int m = 1; m < 8; m <<= 1) acc += __shfl_xor(acc, m, 64);
        if (i == 0) sSt[o] = acc + projB[o];
      }
      __syncthreads();
      for (int rnd = 0; rnd < 2; ++rnd){
        int j = wv + rnd*16;
        if (j < 21){
          const bool isW = (j == 20);
          const float* b1 = isW ? qW_b1 : qF_b1 + j*64;
          const float* b2 = isW ? qW_b2 : qF_b2 + j*32;
          const float* b3 = isW ? qW_b3 : qF_b3 + j*16;
          const float* bp = isW ? qW_bp : qF_bp + j*128;
          float* mlp = sMLP + wv*160;
          const float* W1 = isW ? qW_W1 : qF_W1 + j*(64*80);
          const float* W2 = isW ? qW_W2 : qF_W2 + j*(32*64);
          const float* W3 = isW ? qW_W3 : qF_W3 + j*(16*32);
          const float* Wp = isW ? qW_Wp : qF_Wp + j*(128*8);
          {
            const float* row = W1 + lane*80;
            float acc = b1[lane];
            for (int q = 0; q < 80; ++q) acc = fmaf(row[q], sSt[q], acc);
            mlp[lane] = tanhf(acc);
          }
          __builtin_amdgcn_wave_barrier();
          {
            int i2 = lane & 31;
            const float* row = W2 + i2*64;
            float acc = b2[i2];
            for (int q = 0; q < 64; ++q) acc = fmaf(row[q], mlp[q], acc);
            float h2 = tanhf(acc);
            __builtin_amdgcn_wave_barrier();
            if (lane < 32) mlp[64 + lane] = h2;
          }
          __builtin_amdgcn_wave_barrier();
          {
            int i3 = lane & 15;
            const float* row = W3 + i3*32;
            float acc = b3[i3];
            for (int q = 0; q < 32; ++q) acc = fmaf(row[q], mlp[64 + q], acc);
            __builtin_amdgcn_wave_barrier();
            if (lane < 16) mlp[96 + lane] = acc;
          }
          __builtin_amdgcn_wave_barrier();
          if (lane < 24){
            int i = lane & 7, which = lane >> 3;
            float th = mlp[96 + i], om = mlp[96 + 8 + i];
            float arg = (which == 0) ? 0.5f*th
                      : (which == 1) ? 0.5f*(0.f + om)
                                     : 0.5f*(0.f - om);
            float s, c; sincosf(arg, &s, &c);
            mlp[112 + which*16 + 2*i]     = s;
            mlp[112 + which*16 + 2*i + 1] = c;
          }
          __builtin_amdgcn_wave_barrier();
          float z[8];
          run_circuit2(mlp + 112, sUni + j*192, lane, z);
          if (!isW){
            float o0 = bp[lane];
            float o1 = bp[64 + lane];
            const float* r0 = Wp + lane*8;
            const float* r1 = Wp + (64 + lane)*8;
            #pragma unroll
            for (int i = 0; i < 8; ++i){
              o0 = fmaf(r0[i], z[i], o0);
              o1 = fmaf(r1[i], z[i], o1);
            }
            __builtin_amdgcn_wave_barrier();
            mlp[lane] = o0; mlp[64 + lane] = o1;
            __builtin_amdgcn_wave_barrier();
            sdF[j*64 + lane] = make_float2(mlp[2*lane], mlp[2*lane + 1]);
          } else {
            float o0 = bp[lane];
            const float* r0 = Wp + lane*8;
            #pragma unroll
            for (int i = 0; i < 8; ++i) o0 = fmaf(r0[i], z[i], o0);
            __builtin_amdgcn_wave_barrier();
            mlp[lane] = o0;
            __builtin_amdgcn_wave_barrier();
            if (lane < 32) sdW[lane] = make_float2(mlp[2*lane], mlp[2*lane + 1]);
          }
        }
      }
      __syncthreads();
      if (t < 896){
        cf f0 = sF[t], f1 = sF[t + 896];
        const int dfi0 = (t/112)*4 + (t & 3);
        const int dfi1 = dfi0 + 32;
        for (int j = 0; j < NIN_; ++j){
          cf n0 = cnormal(sKeys[2*j], sKeys[2*j + 1], (uint32_t)t);
          cf n1 = cnormal(sKeys[2*j], sKeys[2*j + 1], (uint32_t)(t + 896));
          cf d0 = sdF[j*64 + dfi0], d1 = sdF[j*64 + dfi1];
          f0.x = f0.x + c1*n0.x + 0.001f*d0.x;
          f0.y = f0.y + c1*n0.y + 0.001f*d0.y;
          f1.x = f1.x + c1*n1.x + 0.001f*d1.x;
          f1.y = f1.y + c1*n1.y + 0.001f*d1.y;
          float r0 = sqrtf(f0.x*f0.x + f0.y*f0.y) + 1e-12f;
          float r1 = sqrtf(f1.x*f1.x + f1.y*f1.y) + 1e-12f;
          f0.x /= r0; f0.y /= r0;
          f1.x /= r1; f1.y /= r1;
        }
        sF[t] = f0; sF[t + 896] = f1;
      }
      if (t < 448){
        cf w0 = sW[t], w1 = sW[t + 448];
        cf n0 = cnormal(sKeys[40], sKeys[41], (uint32_t)t);
        cf n1 = cnormal(sKeys[40], sKeys[41], (uint32_t)(t + 448));
        int dwi0 = (t/224)*8 + (t & 7);
        int dwi1 = ((t + 448)/224)*8 + (t & 7);
        cf d0 = sdW[dwi0], d1 = sdW[dwi1];
        w0.x = w0.x + c1*n0.x + 0.001f*d0.x;
        w0.y = w0.y + c1*n0.y + 0.001f*d0.y;
        w1.x = w1.x + c1*n1.x + 0.001f*d1.x;
        w1.y = w1.y + c1*n1.y + 0.001f*d1.y;
        sW[t] = w0; sW[t + 448] = w1;
      }
      __syncthreads();
    }

    for (int e = t; e < FN_; e += 1024){
      cf f = sF[e];
      float r = sqrtf(f.x*f.x + f.y*f.y) + 1e-12f;
      f.x /= r; f.y /= r;
      sF[e] = f;
    }
    __syncthreads();
    for (int x = t; x < XN_; x += 1024){
      int u = x & 1, n = (x >> 1) & 15, kb = x >> 5;
      int b = kb - (kb/28)*28;
      const cf* fr = sF + n*112 + b*4;
      const cf* wr = sW + kb*8 + u;
      cf acc = cmul(fr[0], wr[0]);
      acc = cadd(acc, cmul(fr[1], wr[2]));
      acc = cadd(acc, cmul(fr[2], wr[4]));
      acc = cadd(acc, cmul(fr[3], wr[6]));
      sX[x] = acc;
    }
    __syncthreads();
    if (t < 896){
      int b = t >> 5, i = t & 31;
      float s = 0.f;
      #pragma unroll
      for (int k = 0; k < 4; ++k){
        cf v = sX[(k*28 + b)*32 + i];
        s += v.x*v.x + v.y*v.y;
      }
      #pragma unroll
      for (int m = 1; m < 32; m <<= 1) s += __shfl_xor(s, m, 64);
      if (i == 0) sScale[b] = sqrtf(Ptv / (s + 1e-12f));
    }
    __syncthreads();
    for (int e = t; e < WN_; e += 1024){
      int kb = e >> 3;
      sW[e] = csc(sScale[kb - (kb/28)*28], sW[e]);
    }
    for (int x = t; x < XN_; x += 1024){
      int kb = x >> 5;
      sX[x] = csc(sScale[kb - (kb/28)*28], sX[x]);
    }
    __syncthreads();
    if (t < 112){
      const int kb = t;
      cf He00 = make_float2(0.f,0.f), He01 = He00, He10 = He00, He11 = He00;
      const float* hr = H_re + kb*32;
      const float* hi = H_im + kb*32;
      for (int n = 0; n < 16; ++n){
        cf x0 = sX[kb*32 + n*2], x1 = sX[kb*32 + n*2 + 1];
        cf h0 = make_float2(hr[n],      hi[n]);
        cf h1 = make_float2(hr[16 + n], hi[16 + n]);
        He00 = cadd(He00, cmul(h0, x0));
        He01 = cadd(He01, cmul(h0, x1));
        He10 = cadd(He10, cmul(h1, x0));
        He11 = cadd(He11, cmul(h1, x1));
      }
      cf G00 = cadd(cmulc(He00, He00), cmulc(He01, He01));
      cf G01 = cadd(cmulc(He00, He10), cmulc(He01, He11));
      cf G10 = cadd(cmulc(He10, He00), cmulc(He11, He01));
      cf G11 = cadd(cmulc(He10, He10), cmulc(He11, He11));
      cf A00 = make_float2(1.f + Ptv*G00.x, Ptv*G00.y);
      cf A01 = csc(Ptv, G01);
      cf A10 = csc(Ptv, G10);
      cf A11 = make_float2(1.f + Ptv*G11.x, Ptv*G11.y);
      float detre = (A00.x*A11.x - A00.y*A11.y) - (A01.x*A10.x - A01.y*A10.y);
      sKB[kb] = log2f(fabsf(detre) + 1e-12f);
    }
    if (t >= 128){
      int tt = t - 128, kb = tt >> 3, i = tt & 7;
      const float* rr = R_re + kb*256;
      const float* ri = R_im + kb*256;
      float acc = 0.f;
      for (int c = 0; c < 32; ++c){
        int nv = i + (c << 3);
        int n = nv >> 4, v = nv & 15;
        cf xn0 = sX[kb*32 + n*2], xn1 = sX[kb*32 + n*2 + 1];
        cf xv0 = sX[kb*32 + v*2], xv1 = sX[kb*32 + v*2 + 1];
        cf C = cadd(cmulc(xn0, xv0), cmulc(xn1, xv1));
        float dr = C.x - rr[nv], di = C.y - ri[nv];
        acc += dr*dr + di*di;
      }
      #pragma unroll
      for (int m = 1; m < 8; m <<= 1) acc += __shfl_xor(acc, m, 64);
      if (i == 0) sKB2[kb] = sqrtf(acc + 1e-12f);
    }
    __syncthreads();
    if (t < 28){
      const int slot = it + 1;
      out[t*121 + slot] = sKB[t] + sKB[28 + t] + sKB[56 + t] + sKB[84 + t];
      out[O_TAUS + t*121 + slot] = 0.25f*(sKB2[t] + sKB2[28 + t] + sKB2[56 + t] + sKB2[84 + t]);
    }
    __syncthreads();
  }

  if (fmode == 1){
    for (int e = t; e < FN_; e += 1024){
      out[O_F + e]       = sF[e].x;
      out[O_F + FN_ + e] = sF[e].y;
    }
    for (int e = t; e < WN_; e += 1024){
      out[O_W + e]       = sW[e].x;
      out[O_W + WN_ + e] = sW[e].y;
    }
  } else if (fmode == 2){
    for (int e = t; e < FN_; e += 1024) out[O_F + e] = sF[e].x;
    for (int e = t; e < WN_; e += 1024) out[O_F + FN_ + e] = sW[e].x;
  } else {
    for (int e = t; e < FN_; e += 1024){
      out[O_F + 2*e]     = sF[e].x;
      out[O_F + 2*e + 1] = sF[e].y;
    }
    for (int e = t; e < WN_; e += 1024){
      out[O_W + 2*e]     = sW[e].x;
      out[O_W + 2*e + 1] = sW[e].y;
    }
  }
}

// ===================== host =====================
extern "C" void kernel_launch(void* const* d_in, const int* in_sizes, int n_in,
                              void* d_out, int out_size, void* d_ws, size_t ws_size,
                              hipStream_t stream){
  (void)in_sizes; (void)n_in;
  const float* H_re  = (const float*)d_in[0];
  const float* H_im  = (const float*)d_in[1];
  const float* R_re  = (const float*)d_in[2];
  const float* R_im  = (const float*)d_in[3];
  const float* Pt    = (const float*)d_in[4];
  const float* stp   = (const float*)d_in[5];
  const float* qF_W1 = (const float*)d_in[6];
  const float* qF_b1 = (const float*)d_in[7];
  const float* qF_W2 = (const float*)d_in[8];
  const float* qF_b2 = (const float*)d_in[9];
  const float* qF_W3 = (const float*)d_in[10];
  const float* qF_b3 = (const float*)d_in[11];
  const float* qF_qw = (const float*)d_in[12];
  const float* qF_Wp = (const float*)d_in[13];
  const float* qF_bp = (const float*)d_in[14];
  const float* qW_W1 = (const float*)d_in[15];
  const float* qW_b1 = (const float*)d_in[16];
  const float* qW_W2 = (const float*)d_in[17];
  const float* qW_b2 = (const float*)d_in[18];
  const float* qW_W3 = (const float*)d_in[19];
  const float* qW_b3 = (const float*)d_in[20];
  const float* qW_qw = (const float*)d_in[21];
  const float* qW_Wp = (const float*)d_in[22];
  const float* qW_bp = (const float*)d_in[23];
  const float* projW = (const float*)d_in[24];
  const float* projB = (const float*)d_in[25];
  float* out = (float*)d_out;

  int fmode = 0;
  if (out_size == 12152) fmode = 1;
  else if (out_size == 9464) fmode = 2;

  const size_t nF = (size_t)NOUT_ * NIN_ * FN_;      // F-noise float2 count
  const size_t nW = (size_t)NOUT_ * WN_;             // W-noise float2 count
  // layout: wsF f2[nF] | wsW f2[nW] | wsIW f2[WN_] | wsT f[TSZ_] | wsU f[4032]
  //       | wsC f[272] | wsFst f2[FN_] | wsWst f2[WN_] | wsdF f2[1280] | wsdW f2[32]
  //       | wsFeatA f[112] | wsFeatG f[112] | wsPart f[112] | bar u32[4]
  const size_t need = (nF + nW + WN_ + FN_ + WN_ + 1280 + 32) * sizeof(float2)
                    + (TSZ_ + 4032 + 272 + 112 + 112 + 112 + 4) * sizeof(float);
  const int useWs = (d_ws != nullptr && ws_size >= need) ? 1 : 0;

  float2* wsF  = (float2*)d_ws;
  float2* wsW  = wsF + nF;
  float2* wsIW = wsW + nW;
  float*  wsT  = (float*)(wsIW + WN_);
  float*  wsU  = wsT + TSZ_;
  float*  wsC  = wsU + 4032;
  float2* wsFst = (float2*)(wsC + 272);
  float2* wsWst = wsFst + FN_;
  float2* wsdF  = wsWst + WN_;
  float2* wsdW  = wsdF + 1280;
  float*  wsFeatA = (float*)(wsdW + 32);
  float*  wsFeatG = wsFeatA + 112;
  float*  wsPart  = wsFeatG + 112;
  uint32_t* bar   = (uint32_t*)(wsPart + 112);

  if (useWs){
    hipMemsetAsync(bar, 0, 16, stream);
    rng_kernel<<<dim3(NOUT_ + 1 + 21 + 1), dim3(1024), 0, stream>>>(
        wsF, wsW, wsIW, wsT, wsU, wsC, wsFst, wsWst,
        H_re, H_im, R_re, R_im, qF_qw, qW_qw,
        qF_W1, qF_W2, qF_W3, qF_Wp, qW_W1, qW_W2, qW_W3, qW_Wp);
    persist<<<dim3(NWG_), dim3(128), 0, stream>>>(
        H_re, H_im, R_re, R_im, Pt, stp,
        qF_b1, qF_b2, qF_b3, qF_bp, qW_b1, qW_b2, qW_b3, qW_bp,
        projW, projB, wsF, wsW, wsT, wsU, wsC, wsFst, wsWst,
        wsdF, wsdW, wsFeatA, wsFeatG, wsPart, bar, out, fmode);
  } else {
    main_kernel<<<dim3(1), dim3(1024), 0, stream>>>(
        H_re, H_im, R_re, R_im, Pt, stp,
        qF_W1, qF_b1, qF_W2, qF_b2, qF_W3, qF_b3, qF_qw, qF_Wp, qF_bp,
        qW_W1, qW_b1, qW_W2, qW_b2, qW_W3, qW_b3, qW_qw, qW_Wp, qW_bp,
        projW, projB, out, fmode);
  }
}

// Round 7
// 10233.319 us; speedup vs baseline: 1.0204x; 1.0204x over previous
//
#include <hip/hip_runtime.h>
#include <stdint.h>

// ===================== problem dimensions =====================
#define NT_   16
#define NRF_  4
#define K_    4
#define M_    2
#define B_    28
#define NOUT_ 120
#define NIN_  20
#define FN_   1792   // NT*B*NRF   (complex F elements)
#define WN_   896    // K*B*NRF*M  (complex W elements)
#define XN_   3584   // K*B*NT*M   (complex X elements)
#define TJOB_ 8704
#define TSZ_  (21*TJOB_)
// output float32 offsets (rates[28,121], taus[28,121], then F, W)
#define O_TAUS 3388
#define O_F    6776
#define O_W    10360

typedef float2 cf;
__device__ __forceinline__ cf cmul(cf a, cf b){ return make_float2(a.x*b.x - a.y*b.y, a.x*b.y + a.y*b.x); }
__device__ __forceinline__ cf cmulc(cf a, cf b){ return make_float2(a.x*b.x + a.y*b.y, a.y*b.x - a.x*b.y); } // a*conj(b)
__device__ __forceinline__ cf cadd(cf a, cf b){ return make_float2(a.x + b.x, a.y + b.y); }
__device__ __forceinline__ cf csc(float s, cf a){ return make_float2(s*a.x, s*a.y); }
__device__ __forceinline__ cf shflc(cf v, int m){ return make_float2(__shfl_xor(v.x, m, 64), __shfl_xor(v.y, m, 64)); }

// ===================== threefry2x32 (JAX-compatible) =====================
__device__ __forceinline__ uint32_t rotl32(uint32_t x, int r){ return (x << r) | (x >> (32 - r)); }

__device__ __forceinline__ void threefry(uint32_t k0, uint32_t k1, uint32_t x0, uint32_t x1,
                                         uint32_t &o0, uint32_t &o1){
  uint32_t ks2 = k0 ^ k1 ^ 0x1BD11BDAu;
  x0 += k0; x1 += k1;
#define TF4(a,b,c,d) \
  x0 += x1; x1 = rotl32(x1,(a)); x1 ^= x0; \
  x0 += x1; x1 = rotl32(x1,(b)); x1 ^= x0; \
  x0 += x1; x1 = rotl32(x1,(c)); x1 ^= x0; \
  x0 += x1; x1 = rotl32(x1,(d)); x1 ^= x0;
  TF4(13,15,26,6)  x0 += k1;  x1 += ks2 + 1u;
  TF4(17,29,16,24) x0 += ks2; x1 += k0 + 2u;
  TF4(13,15,26,6)  x0 += k0;  x1 += k1 + 3u;
  TF4(17,29,16,24) x0 += k1;  x1 += ks2 + 4u;
  TF4(13,15,26,6)  x0 += ks2; x1 += k0 + 5u;
#undef TF4
  o0 = x0; o1 = x1;
}

__device__ __forceinline__ void ksplit(uint2 k, uint2 &ka, uint2 &kb){
  threefry(k.x, k.y, 0u, 0u, ka.x, ka.y);
  threefry(k.x, k.y, 0u, 1u, kb.x, kb.y);
}
__device__ __forceinline__ uint2 kfold(uint2 k, uint32_t d){
  uint2 r; threefry(k.x, k.y, 0u, d, r.x, r.y); return r;
}
__device__ __forceinline__ uint32_t rbits(uint2 k, uint32_t i){
  uint32_t a, b; threefry(k.x, k.y, 0u, i, a, b); return a ^ b;
}

__device__ __forceinline__ float bits_to_unit(uint32_t b){
  return __uint_as_float((b >> 9) | 0x3f800000u) - 1.0f;  // [0,1)
}

// XLA (Giles 2012) float32 erf_inv
__device__ __forceinline__ float erfinv_f32(float x){
  float w = -log1pf(-x * x);
  float p;
  if (w < 5.0f){
    w = w - 2.5f;
    p =  2.81022636e-08f;
    p = fmaf(p, w,  3.43273939e-07f);
    p = fmaf(p, w, -3.5233877e-06f);
    p = fmaf(p, w, -4.39150654e-06f);
    p = fmaf(p, w,  0.00021858087f);
    p = fmaf(p, w, -0.00125372503f);
    p = fmaf(p, w, -0.00417768164f);
    p = fmaf(p, w,  0.246640727f);
    p = fmaf(p, w,  1.50140941f);
  } else {
    w = sqrtf(w) - 3.0f;
    p = -0.000200214257f;
    p = fmaf(p, w,  0.000100950558f);
    p = fmaf(p, w,  0.00134934322f);
    p = fmaf(p, w, -0.00367342844f);
    p = fmaf(p, w,  0.00573950773f);
    p = fmaf(p, w, -0.0076224613f);
    p = fmaf(p, w,  0.00943887047f);
    p = fmaf(p, w,  1.00167406f);
    p = fmaf(p, w,  2.83297682f);
  }
  return p * x;
}

#define SQRT2F 1.41421356f

__device__ __forceinline__ float normal_from_bits(uint32_t b){
  const float lo = -0.99999994f;              // nextafter(-1, 0) in f32
  float u = bits_to_unit(b);
  float v = fmaxf(lo, u * 2.0f + lo);
  return SQRT2F * erfinv_f32(v);
}

__device__ __forceinline__ cf cnormal(uint2 kre, uint2 kim, uint32_t e){
  float re = normal_from_bits(rbits(kre, e));
  float im = normal_from_bits(rbits(kim, e));
  return make_float2(re / SQRT2F, im / SQRT2F);
}

__device__ void noise_key_chain(uint32_t it, uint2 *out){
  uint2 k = kfold(make_uint2(0u, 7u), it);    // fold_in(key(7), it)
  for (int j = 0; j < NIN_; ++j){
    uint2 kk, kn;
    ksplit(k, kk, kn);
    k = kk;
    ksplit(kn, out[2*j], out[2*j + 1]);
  }
  uint2 k2, knW;
  ksplit(k, k2, knW);
  ksplit(knW, out[40], out[41]);
}

// ===================== setup kernel =====================
__global__ __launch_bounds__(1024)
void rng_kernel(float2* __restrict__ wsF, float2* __restrict__ wsW,
                float2* __restrict__ wsIW,
                float* __restrict__ wsT, float* __restrict__ wsU,
                float* __restrict__ wsC, float2* __restrict__ wsFst,
                float2* __restrict__ wsWst,
                const float* __restrict__ H_re, const float* __restrict__ H_im,
                const float* __restrict__ R_re, const float* __restrict__ R_im,
                const float* __restrict__ qF_qw, const float* __restrict__ qW_qw,
                const float* __restrict__ qF_W1, const float* __restrict__ qF_W2,
                const float* __restrict__ qF_W3, const float* __restrict__ qF_Wp,
                const float* __restrict__ qW_W1, const float* __restrict__ qW_W2,
                const float* __restrict__ qW_W3, const float* __restrict__ qW_Wp){
  __shared__ uint2 keys[42];
  const int bi = blockIdx.x, t = threadIdx.x;
  if (bi < NOUT_){
    if (t == 0) noise_key_chain((uint32_t)bi, keys);
    __syncthreads();
    for (int idx = t; idx < NIN_*FN_; idx += blockDim.x){
      int j = idx / FN_, e = idx - j*FN_;
      wsF[(size_t)bi*(NIN_*FN_) + idx] = cnormal(keys[2*j], keys[2*j + 1], (uint32_t)e);
    }
    for (int e = t; e < WN_; e += blockDim.x)
      wsW[(size_t)bi*WN_ + e] = cnormal(keys[40], keys[41], (uint32_t)e);
  } else if (bi == NOUT_){
    if (t == 0){
      uint2 k1, k2;
      ksplit(make_uint2(0u, 1u), k1, k2);
      keys[0] = k1;
      ksplit(k2, keys[1], keys[2]);
    }
    __syncthreads();
    const float TWOPI = 6.28318530717958647692f;
    for (int e = t; e < FN_; e += blockDim.x){
      float u = bits_to_unit(rbits(keys[0], (uint32_t)e));
      float ph = fmaxf(0.0f, u * TWOPI);
      float s, c; sincosf(ph, &s, &c);
      wsFst[e] = make_float2(c, s);
    }
    for (int e = t; e < WN_; e += blockDim.x){
      cf w = cnormal(keys[1], keys[2], (uint32_t)e);
      wsIW[e] = w;
      wsWst[e] = w;
    }
  } else if (bi < NOUT_ + 1 + 21){
    const int j = bi - (NOUT_ + 1);
    const bool isW = (j == 20);
    const float* W1 = isW ? qW_W1 : qF_W1 + j*(64*80);
    const float* W2 = isW ? qW_W2 : qF_W2 + j*(32*64);
    const float* W3 = isW ? qW_W3 : qF_W3 + j*(16*32);
    const float* Wp = isW ? qW_Wp : qF_Wp + j*(128*8);
    float* dst = wsT + j*TJOB_;
    for (int idx = t; idx < 5120; idx += blockDim.x){
      int q = idx >> 6, i = idx & 63;
      dst[idx] = W1[i*80 + q];
    }
    for (int idx = t; idx < 2048; idx += blockDim.x){
      int q = idx >> 5, i = idx & 31;
      dst[5120 + idx] = W2[i*64 + q];
    }
    for (int idx = t; idx < 512; idx += blockDim.x){
      int q = idx >> 4, i = idx & 15;
      dst[7168 + idx] = W3[i*32 + q];
    }
    const int nOut = isW ? 64 : 128;
    for (int idx = t; idx < 8*nOut; idx += blockDim.x){
      int z = idx / nOut, o = idx - z*nOut;
      dst[7680 + z*128 + o] = Wp[o*8 + z];
    }
  } else {
    if (t < 504){
      int j = t / 24, gg = t - j*24;
      const float* qw = (j == 20) ? qW_qw : qF_qw + j*72;
      float phi = qw[gg*3], th = qw[gg*3 + 1], om = qw[gg*3 + 2];
      float sh, ch; sincosf(0.5f*th, &sh, &ch);
      float sp, cp; sincosf(0.5f*(phi + om), &sp, &cp);
      float sm, cm; sincosf(0.5f*(phi - om), &sm, &cm);
      float* u = wsU + t*8;
      u[0] =  ch*cp; u[1] = -ch*sp;
      u[2] = -sh*cm; u[3] = -sh*sm;
      u[4] =  sh*cm; u[5] = -sh*sm;
      u[6] =  ch*cp; u[7] =  ch*sp;
    } else if (t < 520){
      int n = t - 504;
      float s = 0.f;
      for (int kbm = 0; kbm < 224; ++kbm){
        float re = H_re[kbm*16 + n], im = H_im[kbm*16 + n];
        s += sqrtf(re*re + im*im);
      }
      wsC[n] = s * (1.0f/224.0f);
    } else if (t < 776){
      int nv = t - 520;
      float s = 0.f;
      for (int kb = 0; kb < 112; ++kb){
        float re = R_re[kb*256 + nv], im = R_im[kb*256 + nv];
        s += sqrtf(re*re + im*im);
      }
      wsC[16 + nv] = s * (1.0f/112.0f);
    }
  }
}

// ===================== 8-qubit circuit =====================
__device__ __forceinline__ void gate(int q, cf u00, cf u01, cf u10, cf u11,
                                     cf &a0, cf &a1, cf &a2, cf &a3, int lane){
  if (q == 7){
    cf n0 = cadd(cmul(u00, a0), cmul(u01, a1));
    cf n1 = cadd(cmul(u10, a0), cmul(u11, a1));
    cf n2 = cadd(cmul(u00, a2), cmul(u01, a3));
    cf n3 = cadd(cmul(u10, a2), cmul(u11, a3));
    a0 = n0; a1 = n1; a2 = n2; a3 = n3;
  } else if (q == 6){
    cf n0 = cadd(cmul(u00, a0), cmul(u01, a2));
    cf n2 = cadd(cmul(u10, a0), cmul(u11, a2));
    cf n1 = cadd(cmul(u00, a1), cmul(u01, a3));
    cf n3 = cadd(cmul(u10, a1), cmul(u11, a3));
    a0 = n0; a1 = n1; a2 = n2; a3 = n3;
  } else {
    const int m = 1 << (5 - q);
    const bool hi = (lane & m) != 0;
    cf cO = hi ? u11 : u00;
    cf cP = hi ? u10 : u01;
    cf p0 = shflc(a0, m), p1 = shflc(a1, m), p2 = shflc(a2, m), p3 = shflc(a3, m);
    a0 = cadd(cmul(cO, a0), cmul(cP, p0));
    a1 = cadd(cmul(cO, a1), cmul(cP, p1));
    a2 = cadd(cmul(cO, a2), cmul(cP, p2));
    a3 = cadd(cmul(cO, a3), cmul(cP, p3));
  }
}

__device__ void run_circuit2(const float* trig, const float* uni, int lane, float z[8]){
  cf a0 = make_float2(lane == 0 ? 1.f : 0.f, 0.f);
  cf a1 = make_float2(0.f, 0.f), a2 = make_float2(0.f, 0.f), a3 = make_float2(0.f, 0.f);
  #pragma unroll
  for (int i = 0; i < 8; ++i){
    float sh = trig[2*i],      ch = trig[2*i + 1];
    float sp = trig[16 + 2*i], cp = trig[16 + 2*i + 1];
    float sm = trig[32 + 2*i], cm = trig[32 + 2*i + 1];
    cf u00 = make_float2( ch*cp, -ch*sp);
    cf u11 = make_float2( ch*cp,  ch*sp);
    cf u01 = make_float2(-sh*cm, -sh*sm);
    cf u10 = make_float2( sh*cm, -sh*sm);
    gate(i, u00, u01, u10, u11, a0, a1, a2, a3, lane);
  }
  for (int l = 0; l < 3; ++l){
    #pragma unroll
    for (int i = 0; i < 8; ++i){
      const float* u = uni + (l*8 + i)*8;
      gate(i, make_float2(u[0], u[1]), make_float2(u[2], u[3]),
              make_float2(u[4], u[5]), make_float2(u[6], u[7]), a0, a1, a2, a3, lane);
    }
    #pragma unroll
    for (int i = 0; i < 5; ++i){
      const int cm_ = 1 << (5 - i), tm = 1 << (4 - i);
      const bool c = (lane & cm_) != 0;
      cf p0 = shflc(a0, tm), p1 = shflc(a1, tm), p2 = shflc(a2, tm), p3 = shflc(a3, tm);
      a0 = c ? p0 : a0; a1 = c ? p1 : a1; a2 = c ? p2 : a2; a3 = c ? p3 : a3;
    }
    {
      const bool c = (lane & 1) != 0;
      cf t0 = c ? a2 : a0, t2 = c ? a0 : a2;
      cf t1 = c ? a3 : a1, t3 = c ? a1 : a3;
      a0 = t0; a1 = t1; a2 = t2; a3 = t3;
    }
    { cf tmp = a2; a2 = a3; a3 = tmp; }
    a1 = shflc(a1, 32);
    a3 = shflc(a3, 32);
  }
  const float p0 = a0.x*a0.x + a0.y*a0.y;
  const float p1 = a1.x*a1.x + a1.y*a1.y;
  const float p2 = a2.x*a2.x + a2.y*a2.y;
  const float p3 = a3.x*a3.x + a3.y*a3.y;
  const float tot = p0 + p1 + p2 + p3;
  z[6] = (p0 + p1) - (p2 + p3);
  z[7] = (p0 + p2) - (p1 + p3);
  #pragma unroll
  for (int i = 0; i < 6; ++i)
    z[i] = ((lane >> (5 - i)) & 1) ? -tot : tot;
  #pragma unroll
  for (int m = 1; m < 64; m <<= 1){
    #pragma unroll
    for (int i = 0; i < 8; ++i) z[i] += __shfl_xor(z[i], m, 64);
  }
}

// ===================== K2: feature-assemble + projection + MLP + circuit (21 WGs x 64) =====================
__global__ __launch_bounds__(64)
void k_qblock2(const float* __restrict__ wsT, const float* __restrict__ wsU,
               const float* __restrict__ wsC,
               const float* __restrict__ wsFeatA, const float* __restrict__ wsFeatG,
               const float* __restrict__ wsPart,
               const float* __restrict__ projW, const float* __restrict__ projB,
               const float* __restrict__ qF_b1, const float* __restrict__ qF_b2,
               const float* __restrict__ qF_b3, const float* __restrict__ qF_bp,
               const float* __restrict__ qW_b1, const float* __restrict__ qW_b2,
               const float* __restrict__ qW_b3, const float* __restrict__ qW_bp,
               float2* __restrict__ wsdF, float2* __restrict__ wsdW){
  const int j = blockIdx.x;
  const int lane = threadIdx.x;
  const bool isW = (j == 20);
  __shared__ float sS[500];
  __shared__ float sSt[80];
  __shared__ float mlp[160];
  __shared__ float luni[192];
  for (int i = lane; i < 192; i += 64) luni[i] = wsU[j*192 + i];
  // assemble sS[500] (identical to R6-persist phase A, proven)
  for (int i = lane; i < 112; i += 64){ sS[i] = wsFeatA[i]; sS[112 + i] = wsFeatG[i]; }
  if (lane < 4){
    float s = 0.f;
    for (int bb = 0; bb < 28; ++bb) s += wsPart[bb*4 + lane];
    sS[224 + lane] = s * (1.0f/448.0f);
  }
  for (int i = lane; i < 272; i += 64) sS[228 + i] = wsC[i];
  __syncthreads();
  // projection (identical per-output order as R4/R5: 8 lanes, stride 8)
  for (int round = 0; round < 10; ++round){
    int o = round*8 + (lane >> 3), i = lane & 7;
    const float* row = projW + o*500;
    float acc = 0.f;
    for (int j2 = i; j2 < 500; j2 += 8) acc = fmaf(sS[j2], row[j2], acc);
    #pragma unroll
    for (int m = 1; m < 8; m <<= 1) acc += __shfl_xor(acc, m, 64);
    if (i == 0) sSt[o] = acc + projB[o];
  }
  __syncthreads();

  const float* b1 = isW ? qW_b1 : qF_b1 + j*64;
  const float* b2 = isW ? qW_b2 : qF_b2 + j*32;
  const float* b3 = isW ? qW_b3 : qF_b3 + j*16;
  const float* bp = isW ? qW_bp : qF_bp + j*128;
  const float* w1t = wsT + j*TJOB_;
  const float* w2t = w1t + 5120;
  const float* w3t = w1t + 7168;
  const float* wpt = w1t + 7680;

  { // h1[64]
    float acc = b1[lane];
    for (int q = 0; q < 80; ++q) acc = fmaf(w1t[q*64 + lane], sSt[q], acc);
    mlp[lane] = tanhf(acc);
  }
  __builtin_amdgcn_wave_barrier();
  { // h2[32]
    int i2 = lane & 31;
    float acc = b2[i2];
    for (int q = 0; q < 64; ++q) acc = fmaf(w2t[q*32 + i2], mlp[q], acc);
    float h2 = tanhf(acc);
    __builtin_amdgcn_wave_barrier();
    if (lane < 32) mlp[64 + lane] = h2;
  }
  __builtin_amdgcn_wave_barrier();
  { // ang[16]
    int i3 = lane & 15;
    float acc = b3[i3];
    for (int q = 0; q < 32; ++q) acc = fmaf(w3t[q*16 + i3], mlp[64 + q], acc);
    __builtin_amdgcn_wave_barrier();
    if (lane < 16) mlp[96 + lane] = acc;
  }
  __builtin_amdgcn_wave_barrier();
  if (lane < 24){
    int i = lane & 7, which = lane >> 3;
    float th = mlp[96 + i], om = mlp[96 + 8 + i];
    float arg = (which == 0) ? 0.5f*th
              : (which == 1) ? 0.5f*(0.f + om)
                             : 0.5f*(0.f - om);
    float s, c; sincosf(arg, &s, &c);
    mlp[112 + which*16 + 2*i]     = s;
    mlp[112 + which*16 + 2*i + 1] = c;
  }
  __builtin_amdgcn_wave_barrier();
  float z[8];
  run_circuit2(mlp + 112, luni, lane, z);
  if (!isW){
    float o0 = bp[lane];
    float o1 = bp[64 + lane];
    #pragma unroll
    for (int i = 0; i < 8; ++i){
      o0 = fmaf(wpt[i*128 + lane],      z[i], o0);
      o1 = fmaf(wpt[i*128 + 64 + lane], z[i], o1);
    }
    __builtin_amdgcn_wave_barrier();
    mlp[lane] = o0; mlp[64 + lane] = o1;
    __builtin_amdgcn_wave_barrier();
    wsdF[j*64 + lane] = make_float2(mlp[2*lane], mlp[2*lane + 1]);
  } else {
    float o0 = bp[lane];
    #pragma unroll
    for (int i = 0; i < 8; ++i) o0 = fmaf(wpt[i*128 + lane], z[i], o0);
    __builtin_amdgcn_wave_barrier();
    mlp[lane] = o0;
    __builtin_amdgcn_wave_barrier();
    if (lane < 32) wsdW[lane] = make_float2(mlp[2*lane], mlp[2*lane + 1]);
  }
}

// ===================== K3: per-b update + normalize + X + metrics + features (28 WGs x 128) =====================
__global__ __launch_bounds__(128)
void k_update(const float* __restrict__ H_re, const float* __restrict__ H_im,
              const float* __restrict__ R_re, const float* __restrict__ R_im,
              const float* __restrict__ Pt_p, const float* __restrict__ step_p,
              const float2* __restrict__ wsF, const float2* __restrict__ wsW,
              const float2* __restrict__ wsdF, const float2* __restrict__ wsdW,
              float2* __restrict__ wsFst, float2* __restrict__ wsWst,
              float* __restrict__ wsFeatA, float* __restrict__ wsFeatG,
              float* __restrict__ wsPart,
              float* __restrict__ out, int it, int mode){
  const int b = blockIdx.x;
  const int t = threadIdx.x;
  const int lane = t & 63;
  __shared__ cf lF[64];
  __shared__ cf lW[32];
  __shared__ cf lX[128];
  __shared__ float scrA[96], scrG[96];
  __shared__ float red2[2];
  __shared__ float sscale;
  __shared__ float heR[16], heI[16];
  __shared__ float sKBl[4], sKB2l[4];
  const float c1 = step_p[0] * 0.001f;
  const float Ptv = Pt_p[0];

  if (t < 64){
    const int n = t >> 2, r = t & 3;
    const int e = n*112 + b*4 + r;
    cf F = wsFst[e];
    if (mode){
      const float2* np = wsF + (size_t)it*(NIN_*FN_);
      cf nzA[10], dvA[10], nzB[10], dvB[10];
      #pragma unroll
      for (int s = 0; s < 10; ++s){ nzA[s] = np[s*FN_ + e];        dvA[s] = wsdF[s*64 + t]; }
      #pragma unroll
      for (int s = 0; s < 10; ++s){ nzB[s] = np[(10 + s)*FN_ + e]; dvB[s] = wsdF[(10 + s)*64 + t]; }
      #pragma unroll
      for (int s = 0; s < 10; ++s){
        F.x = F.x + c1*nzA[s].x + 0.001f*dvA[s].x;
        F.y = F.y + c1*nzA[s].y + 0.001f*dvA[s].y;
        float rr = sqrtf(F.x*F.x + F.y*F.y) + 1e-12f;
        F.x /= rr; F.y /= rr;
      }
      #pragma unroll
      for (int s = 0; s < 10; ++s){
        F.x = F.x + c1*nzB[s].x + 0.001f*dvB[s].x;
        F.y = F.y + c1*nzB[s].y + 0.001f*dvB[s].y;
        float rr = sqrtf(F.x*F.x + F.y*F.y) + 1e-12f;
        F.x /= rr; F.y /= rr;
      }
    }
    // _normalize
    float rr = sqrtf(F.x*F.x + F.y*F.y) + 1e-12f;
    F.x /= rr; F.y /= rr;
    lF[t] = F;
    wsFst[e] = F;
  } else if (t < 96){
    const int wi = t - 64;
    const int k = wi >> 3, ru = wi & 7;
    const int ew = (k*28 + b)*8 + ru;
    cf w = wsWst[ew];
    if (mode){
      cf nw = wsW[(size_t)it*WN_ + ew];
      cf dw = wsdW[k*8 + ru];
      w.x = w.x + c1*nw.x + 0.001f*dw.x;
      w.y = w.y + c1*nw.y + 0.001f*dw.y;
    }
    lW[wi] = w;
  }
  __syncthreads();
  // X[k,n,u] = sum_r F[n,r] W[k,r,u]
  {
    int u = t & 1, n = (t >> 1) & 15, k = t >> 5;
    const cf* fr = lF + n*4;
    const cf* wr = lW + k*8 + u;
    cf acc = cmul(fr[0], wr[0]);
    acc = cadd(acc, cmul(fr[1], wr[2]));
    acc = cadd(acc, cmul(fr[2], wr[4]));
    acc = cadd(acc, cmul(fr[3], wr[6]));
    lX[t] = acc;
  }
  __syncthreads();
  {
    float s = lX[t].x*lX[t].x + lX[t].y*lX[t].y;
    #pragma unroll
    for (int m = 1; m < 64; m <<= 1) s += __shfl_xor(s, m, 64);
    if ((t & 63) == 0) red2[t >> 6] = s;
  }
  __syncthreads();
  if (t == 0) sscale = sqrtf(Ptv / ((red2[0] + red2[1]) + 1e-12f));
  __syncthreads();
  const float sc = sscale;
  if (t < 32){
    const int k = t >> 3, ru = t & 7;
    const int ew = (k*28 + b)*8 + ru;
    cf w = csc(sc, lW[t]);
    lW[t] = w;
    wsWst[ew] = w;
  }
  lX[t] = csc(sc, lX[t]);
  __syncthreads();
  // He entries
  if (t < 16){
    const int k = t >> 2, ent = t & 3;
    const int m = ent >> 1, u = ent & 1;
    const float* hr = H_re + (k*28 + b)*32 + m*16;
    const float* hi = H_im + (k*28 + b)*32 + m*16;
    cf He = make_float2(0.f, 0.f);
    for (int n = 0; n < 16; ++n){
      cf h = make_float2(hr[n], hi[n]);
      He = cadd(He, cmul(h, lX[k*32 + n*2 + u]));
    }
    heR[t] = He.x; heI[t] = He.y;
  }
  __builtin_amdgcn_wave_barrier();
  if (t < 4){
    const int k = t;
    cf He00 = make_float2(heR[k*4 + 0], heI[k*4 + 0]);
    cf He01 = make_float2(heR[k*4 + 1], heI[k*4 + 1]);
    cf He10 = make_float2(heR[k*4 + 2], heI[k*4 + 2]);
    cf He11 = make_float2(heR[k*4 + 3], heI[k*4 + 3]);
    cf G00 = cadd(cmulc(He00, He00), cmulc(He01, He01));
    cf G01 = cadd(cmulc(He00, He10), cmulc(He01, He11));
    cf G10 = cadd(cmulc(He10, He00), cmulc(He11, He01));
    cf G11 = cadd(cmulc(He10, He10), cmulc(He11, He11));
    cf A00 = make_float2(1.f + Ptv*G00.x, Ptv*G00.y);
    cf A01 = csc(Ptv, G01);
    cf A10 = csc(Ptv, G10);
    cf A11 = make_float2(1.f + Ptv*G11.x, Ptv*G11.y);
    float detre = (A00.x*A11.x - A00.y*A11.y) - (A01.x*A10.x - A01.y*A10.y);
    sKBl[k] = log2f(fabsf(detre) + 1e-12f);
  }
  // beam error
  {
    const int k = t >> 5, i = t & 31;
    const float* rr = R_re + (k*28 + b)*256;
    const float* ri = R_im + (k*28 + b)*256;
    float acc = 0.f;
    #pragma unroll
    for (int c = 0; c < 8; ++c){
      int nv = c*32 + i;
      int n = nv >> 4, v = nv & 15;
      cf xn0 = lX[k*32 + n*2], xn1 = lX[k*32 + n*2 + 1];
      cf xv0 = lX[k*32 + v*2], xv1 = lX[k*32 + v*2 + 1];
      cf C = cadd(cmulc(xn0, xv0), cmulc(xn1, xv1));
      float dr = C.x - rr[nv], di = C.y - ri[nv];
      acc += dr*dr + di*di;
    }
    #pragma unroll
    for (int m = 1; m < 32; m <<= 1) acc += __shfl_xor(acc, m, 64);
    if (i == 0) sKB2l[k] = sqrtf(acc + 1e-12f);
  }
  __syncthreads();
  if (t == 0){
    const int slot = mode ? (it + 1) : 0;
    out[b*121 + slot] = sKBl[0] + sKBl[1] + sKBl[2] + sKBl[3];
    out[O_TAUS + b*121 + slot] = 0.25f*(sKB2l[0] + sKB2l[1] + sKB2l[2] + sKB2l[3]);
  }
  // ---- state features for next iteration (proven in R6-persist)
  if (t < 64){
    cf f = lF[t];
    scrA[t] = sqrtf(f.x*f.x + f.y*f.y);
    scrG[t] = atan2f(f.y, f.x);
  } else if (t < 96){
    cf w = lW[t - 64];
    scrA[t] = sqrtf(w.x*w.x + w.y*w.y);
    scrG[t] = atan2f(w.y, w.x);
  }
  __syncthreads();
  if (t < 8){
    int r = t & 3;
    const float* src = (t < 4) ? scrA : scrG;
    float s = 0.f;
    for (int n = 0; n < 16; ++n) s += src[n*4 + r];
    float* dst = (t < 4) ? wsFeatA : wsFeatG;
    dst[b*4 + r] = s * (1.0f/16.0f);
  } else if (t >= 8 && t < 12){
    int tt = t - 8;
    int u = tt & 1; bool isG = tt >= 2;
    const float* src = isG ? scrG : scrA;
    float s = 0.f;
    for (int i = 0; i < 16; ++i) s += src[64 + i*2 + u];
    wsPart[b*4 + tt] = s;
  }
}

// ===================== K4: final F/W serialization =====================
__global__ __launch_bounds__(1024)
void k_out(const float2* __restrict__ wsFst, const float2* __restrict__ wsWst,
           float* __restrict__ out, int fmode){
  const int t = threadIdx.x;
  if (fmode == 1){
    for (int e = t; e < FN_; e += 1024){
      out[O_F + e]       = wsFst[e].x;
      out[O_F + FN_ + e] = wsFst[e].y;
    }
    for (int e = t; e < WN_; e += 1024){
      out[O_W + e]       = wsWst[e].x;
      out[O_W + WN_ + e] = wsWst[e].y;
    }
  } else if (fmode == 2){
    for (int e = t; e < FN_; e += 1024) out[O_F + e] = wsFst[e].x;
    for (int e = t; e < WN_; e += 1024) out[O_F + FN_ + e] = wsWst[e].x;
  } else {
    for (int e = t; e < FN_; e += 1024){
      out[O_F + 2*e]     = wsFst[e].x;
      out[O_F + 2*e + 1] = wsFst[e].y;
    }
    for (int e = t; e < WN_; e += 1024){
      out[O_W + 2*e]     = wsWst[e].x;
      out[O_W + 2*e + 1] = wsWst[e].y;
    }
  }
}

// ===================== fallback: single-WG monolith (used only if ws too small) =====================
__global__ __launch_bounds__(1024)
void main_kernel(const float* __restrict__ H_re, const float* __restrict__ H_im,
                 const float* __restrict__ R_re, const float* __restrict__ R_im,
                 const float* __restrict__ Pt_p, const float* __restrict__ step_p,
                 const float* __restrict__ qF_W1, const float* __restrict__ qF_b1,
                 const float* __restrict__ qF_W2, const float* __restrict__ qF_b2,
                 const float* __restrict__ qF_W3, const float* __restrict__ qF_b3,
                 const float* __restrict__ qF_qw, const float* __restrict__ qF_Wp,
                 const float* __restrict__ qF_bp,
                 const float* __restrict__ qW_W1, const float* __restrict__ qW_b1,
                 const float* __restrict__ qW_W2, const float* __restrict__ qW_b2,
                 const float* __restrict__ qW_W3, const float* __restrict__ qW_b3,
                 const float* __restrict__ qW_qw, const float* __restrict__ qW_Wp,
                 const float* __restrict__ qW_bp,
                 const float* __restrict__ projW, const float* __restrict__ projB,
                 float* __restrict__ out, int fmode)
{
  const int t = threadIdx.x;
  const int lane = t & 63;
  const int wv = t >> 6;

  __shared__ cf sF[FN_];
  __shared__ cf sW[WN_];
  __shared__ float sS[500];
  __shared__ float sSt[80];
  __shared__ float sScale[B_];
  __shared__ float sKB[112];
  __shared__ float sKB2[112];
  __shared__ float sRed[64];
  __shared__ uint2 sKeys[42];
  __shared__ float sPar[2];
  __shared__ float sUni[21*24*8];
  __shared__ __align__(16) unsigned char uPool[XN_ * sizeof(cf)];
  cf*    sX   = (cf*)uPool;
  cf*    sdF  = (cf*)uPool;
  cf*    sdW  = (cf*)(uPool + NIN_*64*sizeof(cf));
  float* sMLP = (float*)(uPool + NIN_*64*sizeof(cf) + 32*sizeof(cf));

  if (t == 0){ sPar[0] = step_p[0]; sPar[1] = Pt_p[0]; }

  if (t < 504){
    int j = t / 24, gg = t - j*24;
    const float* qw = (j == 20) ? qW_qw : qF_qw + j*72;
    float phi = qw[gg*3], th = qw[gg*3 + 1], om = qw[gg*3 + 2];
    float sh, ch; sincosf(0.5f*th, &sh, &ch);
    float sp, cp; sincosf(0.5f*(phi + om), &sp, &cp);
    float sm, cm; sincosf(0.5f*(phi - om), &sm, &cm);
    float* u = sUni + t*8;
    u[0] =  ch*cp; u[1] = -ch*sp;
    u[2] = -sh*cm; u[3] = -sh*sm;
    u[4] =  sh*cm; u[5] = -sh*sm;
    u[6] =  ch*cp; u[7] =  ch*sp;
  }

  {
    float* scratch = (float*)uPool;
    float local = 0.f;
    for (int i = t; i < 3584; i += 1024) local += sqrtf(H_re[i]*H_re[i] + H_im[i]*H_im[i]);
    scratch[t] = local;
    __syncthreads();
    for (int s = 512; s >= 16; s >>= 1){
      if (t < s) scratch[t] += scratch[t + s];
      __syncthreads();
    }
    if (t < 16) sS[228 + t] = scratch[t] * (1.0f/224.0f);
    __syncthreads();
    local = 0.f;
    for (int i = t; i < 28672; i += 1024) local += sqrtf(R_re[i]*R_re[i] + R_im[i]*R_im[i]);
    scratch[t] = local;
    __syncthreads();
    for (int s = 512; s >= 256; s >>= 1){
      if (t < s) scratch[t] += scratch[t + s];
      __syncthreads();
    }
    if (t < 256) sS[244 + t] = scratch[t] * (1.0f/112.0f);
    __syncthreads();
  }

  {
    if (t == 0){
      uint2 k1, k2; ksplit(make_uint2(0u, 1u), k1, k2);
      sKeys[0] = k1; ksplit(k2, sKeys[1], sKeys[2]);
    }
    __syncthreads();
    const float TWOPI = 6.28318530717958647692f;
    for (int e = t; e < FN_; e += 1024){
      float u = bits_to_unit(rbits(sKeys[0], (uint32_t)e));
      float ph = fmaxf(0.0f, u * TWOPI);
      float s, c; sincosf(ph, &s, &c);
      sF[e] = make_float2(c, s);
    }
    for (int e = t; e < WN_; e += 1024) sW[e] = cnormal(sKeys[1], sKeys[2], (uint32_t)e);
  }
  __syncthreads();

  const float stepv = sPar[0], Ptv = sPar[1];
  const float c1 = stepv * 0.001f;

  for (int it = -1; it < NOUT_; ++it){
    if (it >= 0){
      if (t == 0) noise_key_chain((uint32_t)it, sKeys);
      __syncthreads();
      if (t < 112){
        float sa = 0.f, sg = 0.f;
        for (int n = 0; n < NT_; ++n){
          cf f = sF[n*112 + t];
          sa += sqrtf(f.x*f.x + f.y*f.y);
          sg += atan2f(f.y, f.x);
        }
        sS[t]       = sa * (1.0f/16.0f);
        sS[112 + t] = sg * (1.0f/16.0f);
      }
      {
        float aW = 0.f, gW = 0.f;
        if (t < WN_){
          cf w = sW[t];
          aW = sqrtf(w.x*w.x + w.y*w.y);
          gW = atan2f(w.y, w.x);
        }
        #pragma unroll
        for (int m = 2; m < 64; m <<= 1){
          aW += __shfl_xor(aW, m, 64);
          gW += __shfl_xor(gW, m, 64);
        }
        if (t < WN_ && lane < 2){
          sRed[wv*2 + lane] = aW;
          sRed[32 + wv*2 + lane] = gW;
        }
      }
      __syncthreads();
      if (t < 4){
        int u = t & 1;
        int base = (t >= 2) ? 32 : 0;
        float s = 0.f;
        for (int w = 0; w < 14; ++w) s += sRed[base + w*2 + u];
        sS[224 + t] = s * (1.0f/448.0f);
      }
      __syncthreads();
      if (t < 640){
        int o = t >> 3, i = t & 7;
        const float* row = projW + o*500;
        float acc = 0.f;
        for (int j = i; j < 500; j += 8) acc = fmaf(sS[j], row[j], acc);
        #pragma unroll
        for (int m = 1; m < 8; m <<= 1) acc += __shfl_xor(acc, m, 64);
        if (i == 0) sSt[o] = acc + projB[o];
      }
      __syncthreads();
      for (int rnd = 0; rnd < 2; ++rnd){
        int j = wv + rnd*16;
        if (j < 21){
          const bool isW = (j == 20);
          const float* b1 = isW ? qW_b1 : qF_b1 + j*64;
          const float* b2 = isW ? qW_b2 : qF_b2 + j*32;
          const float* b3 = isW ? qW_b3 : qF_b3 + j*16;
          const float* bp = isW ? qW_bp : qF_bp + j*128;
          float* mlp = sMLP + wv*160;
          const float* W1 = isW ? qW_W1 : qF_W1 + j*(64*80);
          const float* W2 = isW ? qW_W2 : qF_W2 + j*(32*64);
          const float* W3 = isW ? qW_W3 : qF_W3 + j*(16*32);
          const float* Wp = isW ? qW_Wp : qF_Wp + j*(128*8);
          {
            const float* row = W1 + lane*80;
            float acc = b1[lane];
            for (int q = 0; q < 80; ++q) acc = fmaf(row[q], sSt[q], acc);
            mlp[lane] = tanhf(acc);
          }
          __builtin_amdgcn_wave_barrier();
          {
            int i2 = lane & 31;
            const float* row = W2 + i2*64;
            float acc = b2[i2];
            for (int q = 0; q < 64; ++q) acc = fmaf(row[q], mlp[q], acc);
            float h2 = tanhf(acc);
            __builtin_amdgcn_wave_barrier();
            if (lane < 32) mlp[64 + lane] = h2;
          }
          __builtin_amdgcn_wave_barrier();
          {
            int i3 = lane & 15;
            const float* row = W3 + i3*32;
            float acc = b3[i3];
            for (int q = 0; q < 32; ++q) acc = fmaf(row[q], mlp[64 + q], acc);
            __builtin_amdgcn_wave_barrier();
            if (lane < 16) mlp[96 + lane] = acc;
          }
          __builtin_amdgcn_wave_barrier();
          if (lane < 24){
            int i = lane & 7, which = lane >> 3;
            float th = mlp[96 + i], om = mlp[96 + 8 + i];
            float arg = (which == 0) ? 0.5f*th
                      : (which == 1) ? 0.5f*(0.f + om)
                                     : 0.5f*(0.f - om);
            float s, c; sincosf(arg, &s, &c);
            mlp[112 + which*16 + 2*i]     = s;
            mlp[112 + which*16 + 2*i + 1] = c;
          }
          __builtin_amdgcn_wave_barrier();
          float z[8];
          run_circuit2(mlp + 112, sUni + j*192, lane, z);
          if (!isW){
            float o0 = bp[lane];
            float o1 = bp[64 + lane];
            const float* r0 = Wp + lane*8;
            const float* r1 = Wp + (64 + lane)*8;
            #pragma unroll
            for (int i = 0; i < 8; ++i){
              o0 = fmaf(r0[i], z[i], o0);
              o1 = fmaf(r1[i], z[i], o1);
            }
            __builtin_amdgcn_wave_barrier();
            mlp[lane] = o0; mlp[64 + lane] = o1;
            __builtin_amdgcn_wave_barrier();
            sdF[j*64 + lane] = make_float2(mlp[2*lane], mlp[2*lane + 1]);
          } else {
            float o0 = bp[lane];
            const float* r0 = Wp + lane*8;
            #pragma unroll
            for (int i = 0; i < 8; ++i) o0 = fmaf(r0[i], z[i], o0);
            __builtin_amdgcn_wave_barrier();
            mlp[lane] = o0;
            __builtin_amdgcn_wave_barrier();
            if (lane < 32) sdW[lane] = make_float2(mlp[2*lane], mlp[2*lane + 1]);
          }
        }
      }
      __syncthreads();
      if (t < 896){
        cf f0 = sF[t], f1 = sF[t + 896];
        const int dfi0 = (t/112)*4 + (t & 3);
        const int dfi1 = dfi0 + 32;
        for (int j = 0; j < NIN_; ++j){
          cf n0 = cnormal(sKeys[2*j], sKeys[2*j + 1], (uint32_t)t);
          cf n1 = cnormal(sKeys[2*j], sKeys[2*j + 1], (uint32_t)(t + 896));
          cf d0 = sdF[j*64 + dfi0], d1 = sdF[j*64 + dfi1];
          f0.x = f0.x + c1*n0.x + 0.001f*d0.x;
          f0.y = f0.y + c1*n0.y + 0.001f*d0.y;
          f1.x = f1.x + c1*n1.x + 0.001f*d1.x;
          f1.y = f1.y + c1*n1.y + 0.001f*d1.y;
          float r0 = sqrtf(f0.x*f0.x + f0.y*f0.y) + 1e-12f;
          float r1 = sqrtf(f1.x*f1.x + f1.y*f1.y) + 1e-12f;
          f0.x /= r0; f0.y /= r0;
          f1.x /= r1; f1.y /= r1;
        }
        sF[t] = f0; sF[t + 896] = f1;
      }
      if (t < 448){
        cf w0 = sW[t], w1 = sW[t + 448];
        cf n0 = cnormal(sKeys[40], sKeys[41], (uint32_t)t);
        cf n1 = cnormal(sKeys[40], sKeys[41], (uint32_t)(t + 448));
        int dwi0 = (t/224)*8 + (t & 7);
        int dwi1 = ((t + 448)/224)*8 + (t & 7);
        cf d0 = sdW[dwi0], d1 = sdW[dwi1];
        w0.x = w0.x + c1*n0.x + 0.001f*d0.x;
        w0.y = w0.y + c1*n0.y + 0.001f*d0.y;
        w1.x = w1.x + c1*n1.x + 0.001f*d1.x;
        w1.y = w1.y + c1*n1.y + 0.001f*d1.y;
        sW[t] = w0; sW[t + 448] = w1;
      }
      __syncthreads();
    }

    for (int e = t; e < FN_; e += 1024){
      cf f = sF[e];
      float r = sqrtf(f.x*f.x + f.y*f.y) + 1e-12f;
      f.x /= r; f.y /= r;
      sF[e] = f;
    }
    __syncthreads();
    for (int x = t; x < XN_; x += 1024){
      int u = x & 1, n = (x >> 1) & 15, kb = x >> 5;
      int b = kb - (kb/28)*28;
      const cf* fr = sF + n*112 + b*4;
      const cf* wr = sW + kb*8 + u;
      cf acc = cmul(fr[0], wr[0]);
      acc = cadd(acc, cmul(fr[1], wr[2]));
      acc = cadd(acc, cmul(fr[2], wr[4]));
      acc = cadd(acc, cmul(fr[3], wr[6]));
      sX[x] = acc;
    }
    __syncthreads();
    if (t < 896){
      int b = t >> 5, i = t & 31;
      float s = 0.f;
      #pragma unroll
      for (int k = 0; k < 4; ++k){
        cf v = sX[(k*28 + b)*32 + i];
        s += v.x*v.x + v.y*v.y;
      }
      #pragma unroll
      for (int m = 1; m < 32; m <<= 1) s += __shfl_xor(s, m, 64);
      if (i == 0) sScale[b] = sqrtf(Ptv / (s + 1e-12f));
    }
    __syncthreads();
    for (int e = t; e < WN_; e += 1024){
      int kb = e >> 3;
      sW[e] = csc(sScale[kb - (kb/28)*28], sW[e]);
    }
    for (int x = t; x < XN_; x += 1024){
      int kb = x >> 5;
      sX[x] = csc(sScale[kb - (kb/28)*28], sX[x]);
    }
    __syncthreads();
    if (t < 112){
      const int kb = t;
      cf He00 = make_float2(0.f,0.f), He01 = He00, He10 = He00, He11 = He00;
      const float* hr = H_re + kb*32;
      const float* hi = H_im + kb*32;
      for (int n = 0; n < 16; ++n){
        cf x0 = sX[kb*32 + n*2], x1 = sX[kb*32 + n*2 + 1];
        cf h0 = make_float2(hr[n],      hi[n]);
        cf h1 = make_float2(hr[16 + n], hi[16 + n]);
        He00 = cadd(He00, cmul(h0, x0));
        He01 = cadd(He01, cmul(h0, x1));
        He10 = cadd(He10, cmul(h1, x0));
        He11 = cadd(He11, cmul(h1, x1));
      }
      cf G00 = cadd(cmulc(He00, He00), cmulc(He01, He01));
      cf G01 = cadd(cmulc(He00, He10), cmulc(He01, He11));
      cf G10 = cadd(cmulc(He10, He00), cmulc(He11, He01));
      cf G11 = cadd(cmulc(He10, He10), cmulc(He11, He11));
      cf A00 = make_float2(1.f + Ptv*G00.x, Ptv*G00.y);
      cf A01 = csc(Ptv, G01);
      cf A10 = csc(Ptv, G10);
      cf A11 = make_float2(1.f + Ptv*G11.x, Ptv*G11.y);
      float detre = (A00.x*A11.x - A00.y*A11.y) - (A01.x*A10.x - A01.y*A10.y);
      sKB[kb] = log2f(fabsf(detre) + 1e-12f);
    }
    if (t >= 128){
      int tt = t - 128, kb = tt >> 3, i = tt & 7;
      const float* rr = R_re + kb*256;
      const float* ri = R_im + kb*256;
      float acc = 0.f;
      for (int c = 0; c < 32; ++c){
        int nv = i + (c << 3);
        int n = nv >> 4, v = nv & 15;
        cf xn0 = sX[kb*32 + n*2], xn1 = sX[kb*32 + n*2 + 1];
        cf xv0 = sX[kb*32 + v*2], xv1 = sX[kb*32 + v*2 + 1];
        cf C = cadd(cmulc(xn0, xv0), cmulc(xn1, xv1));
        float dr = C.x - rr[nv], di = C.y - ri[nv];
        acc += dr*dr + di*di;
      }
      #pragma unroll
      for (int m = 1; m < 8; m <<= 1) acc += __shfl_xor(acc, m, 64);
      if (i == 0) sKB2[kb] = sqrtf(acc + 1e-12f);
    }
    __syncthreads();
    if (t < 28){
      const int slot = it + 1;
      out[t*121 + slot] = sKB[t] + sKB[28 + t] + sKB[56 + t] + sKB[84 + t];
      out[O_TAUS + t*121 + slot] = 0.25f*(sKB2[t] + sKB2[28 + t] + sKB2[56 + t] + sKB2[84 + t]);
    }
    __syncthreads();
  }

  if (fmode == 1){
    for (int e = t; e < FN_; e += 1024){
      out[O_F + e]       = sF[e].x;
      out[O_F + FN_ + e] = sF[e].y;
    }
    for (int e = t; e < WN_; e += 1024){
      out[O_W + e]       = sW[e].x;
      out[O_W + WN_ + e] = sW[e].y;
    }
  } else if (fmode == 2){
    for (int e = t; e < FN_; e += 1024) out[O_F + e] = sF[e].x;
    for (int e = t; e < WN_; e += 1024) out[O_F + FN_ + e] = sW[e].x;
  } else {
    for (int e = t; e < FN_; e += 1024){
      out[O_F + 2*e]     = sF[e].x;
      out[O_F + 2*e + 1] = sF[e].y;
    }
    for (int e = t; e < WN_; e += 1024){
      out[O_W + 2*e]     = sW[e].x;
      out[O_W + 2*e + 1] = sW[e].y;
    }
  }
}

// ===================== host =====================
extern "C" void kernel_launch(void* const* d_in, const int* in_sizes, int n_in,
                              void* d_out, int out_size, void* d_ws, size_t ws_size,
                              hipStream_t stream){
  (void)in_sizes; (void)n_in;
  const float* H_re  = (const float*)d_in[0];
  const float* H_im  = (const float*)d_in[1];
  const float* R_re  = (const float*)d_in[2];
  const float* R_im  = (const float*)d_in[3];
  const float* Pt    = (const float*)d_in[4];
  const float* stp   = (const float*)d_in[5];
  const float* qF_W1 = (const float*)d_in[6];
  const float* qF_b1 = (const float*)d_in[7];
  const float* qF_W2 = (const float*)d_in[8];
  const float* qF_b2 = (const float*)d_in[9];
  const float* qF_W3 = (const float*)d_in[10];
  const float* qF_b3 = (const float*)d_in[11];
  const float* qF_qw = (const float*)d_in[12];
  const float* qF_Wp = (const float*)d_in[13];
  const float* qF_bp = (const float*)d_in[14];
  const float* qW_W1 = (const float*)d_in[15];
  const float* qW_b1 = (const float*)d_in[16];
  const float* qW_W2 = (const float*)d_in[17];
  const float* qW_b2 = (const float*)d_in[18];
  const float* qW_W3 = (const float*)d_in[19];
  const float* qW_b3 = (const float*)d_in[20];
  const float* qW_qw = (const float*)d_in[21];
  const float* qW_Wp = (const float*)d_in[22];
  const float* qW_bp = (const float*)d_in[23];
  const float* projW = (const float*)d_in[24];
  const float* projB = (const float*)d_in[25];
  float* out = (float*)d_out;

  int fmode = 0;
  if (out_size == 12152) fmode = 1;
  else if (out_size == 9464) fmode = 2;

  const size_t nF = (size_t)NOUT_ * NIN_ * FN_;      // F-noise float2 count
  const size_t nW = (size_t)NOUT_ * WN_;             // W-noise float2 count
  // layout: wsF f2[nF] | wsW f2[nW] | wsIW f2[WN_] | wsT f[TSZ_] | wsU f[4032]
  //       | wsC f[272] | wsFst f2[FN_] | wsWst f2[WN_] | wsdF f2[1280] | wsdW f2[32]
  //       | wsFeatA f[112] | wsFeatG f[112] | wsPart f[112]
  const size_t need = (nF + nW + WN_ + FN_ + WN_ + 1280 + 32) * sizeof(float2)
                    + (TSZ_ + 4032 + 272 + 112 + 112 + 112 + 4) * sizeof(float);
  const int useWs = (d_ws != nullptr && ws_size >= need) ? 1 : 0;

  float2* wsF  = (float2*)d_ws;
  float2* wsW  = wsF + nF;
  float2* wsIW = wsW + nW;
  float*  wsT  = (float*)(wsIW + WN_);
  float*  wsU  = wsT + TSZ_;
  float*  wsC  = wsU + 4032;
  float2* wsFst = (float2*)(wsC + 272);
  float2* wsWst = wsFst + FN_;
  float2* wsdF  = wsWst + WN_;
  float2* wsdW  = wsdF + 1280;
  float*  wsFeatA = (float*)(wsdW + 32);
  float*  wsFeatG = wsFeatA + 112;
  float*  wsPart  = wsFeatG + 112;

  if (useWs){
    rng_kernel<<<dim3(NOUT_ + 1 + 21 + 1), dim3(1024), 0, stream>>>(
        wsF, wsW, wsIW, wsT, wsU, wsC, wsFst, wsWst,
        H_re, H_im, R_re, R_im, qF_qw, qW_qw,
        qF_W1, qF_W2, qF_W3, qF_Wp, qW_W1, qW_W2, qW_W3, qW_Wp);
    // init: normalize + slot-0 metrics + features for it=0
    k_update<<<dim3(B_), dim3(128), 0, stream>>>(
        H_re, H_im, R_re, R_im, Pt, stp, wsF, wsW, wsdF, wsdW,
        wsFst, wsWst, wsFeatA, wsFeatG, wsPart, out, 0, 0);
    for (int it = 0; it < NOUT_; ++it){
      k_qblock2<<<dim3(21), dim3(64), 0, stream>>>(
          wsT, wsU, wsC, wsFeatA, wsFeatG, wsPart, projW, projB,
          qF_b1, qF_b2, qF_b3, qF_bp, qW_b1, qW_b2, qW_b3, qW_bp,
          wsdF, wsdW);
      k_update<<<dim3(B_), dim3(128), 0, stream>>>(
          H_re, H_im, R_re, R_im, Pt, stp, wsF, wsW, wsdF, wsdW,
          wsFst, wsWst, wsFeatA, wsFeatG, wsPart, out, it, 1);
    }
    k_out<<<dim3(1), dim3(1024), 0, stream>>>(wsFst, wsWst, out, fmode);
  } else {
    main_kernel<<<dim3(1), dim3(1024), 0, stream>>>(
        H_re, H_im, R_re, R_im, Pt, stp,
        qF_W1, qF_b1, qF_W2, qF_b2, qF_W3, qF_b3, qF_qw, qF_Wp, qF_bp,
        qW_W1, qW_b1, qW_W2, qW_b2, qW_W3, qW_b3, qW_qw, qW_Wp, qW_bp,
        projW, projB, out, fmode);
  }
}

// Round 8
// 4050.255 us; speedup vs baseline: 2.5780x; 2.5266x over previous
//
#include <hip/hip_runtime.h>
#include <stdint.h>

// ===================== problem dimensions =====================
#define NT_   16
#define NRF_  4
#define K_    4
#define M_    2
#define B_    28
#define NOUT_ 120
#define NIN_  20
#define FN_   1792   // NT*B*NRF   (complex F elements)
#define WN_   896    // K*B*NRF*M  (complex W elements)
#define XN_   3584   // K*B*NT*M   (complex X elements)
#define TJOB_ 8704
#define TSZ_  (21*TJOB_)
// output float32 offsets (rates[28,121], taus[28,121], then F, W)
#define O_TAUS 3388
#define O_F    6776
#define O_W    10360

typedef float2 cf;
__device__ __forceinline__ cf cmul(cf a, cf b){ return make_float2(a.x*b.x - a.y*b.y, a.x*b.y + a.y*b.x); }
__device__ __forceinline__ cf cmulc(cf a, cf b){ return make_float2(a.x*b.x + a.y*b.y, a.y*b.x - a.x*b.y); } // a*conj(b)
__device__ __forceinline__ cf cadd(cf a, cf b){ return make_float2(a.x + b.x, a.y + b.y); }
__device__ __forceinline__ cf csc(float s, cf a){ return make_float2(s*a.x, s*a.y); }
__device__ __forceinline__ cf shflc(cf v, int m){ return make_float2(__shfl_xor(v.x, m, 64), __shfl_xor(v.y, m, 64)); }

// ===================== threefry2x32 (JAX-compatible) =====================
__device__ __forceinline__ uint32_t rotl32(uint32_t x, int r){ return (x << r) | (x >> (32 - r)); }

__device__ __forceinline__ void threefry(uint32_t k0, uint32_t k1, uint32_t x0, uint32_t x1,
                                         uint32_t &o0, uint32_t &o1){
  uint32_t ks2 = k0 ^ k1 ^ 0x1BD11BDAu;
  x0 += k0; x1 += k1;
#define TF4(a,b,c,d) \
  x0 += x1; x1 = rotl32(x1,(a)); x1 ^= x0; \
  x0 += x1; x1 = rotl32(x1,(b)); x1 ^= x0; \
  x0 += x1; x1 = rotl32(x1,(c)); x1 ^= x0; \
  x0 += x1; x1 = rotl32(x1,(d)); x1 ^= x0;
  TF4(13,15,26,6)  x0 += k1;  x1 += ks2 + 1u;
  TF4(17,29,16,24) x0 += ks2; x1 += k0 + 2u;
  TF4(13,15,26,6)  x0 += k0;  x1 += k1 + 3u;
  TF4(17,29,16,24) x0 += k1;  x1 += ks2 + 4u;
  TF4(13,15,26,6)  x0 += ks2; x1 += k0 + 5u;
#undef TF4
  o0 = x0; o1 = x1;
}

__device__ __forceinline__ void ksplit(uint2 k, uint2 &ka, uint2 &kb){
  threefry(k.x, k.y, 0u, 0u, ka.x, ka.y);
  threefry(k.x, k.y, 0u, 1u, kb.x, kb.y);
}
__device__ __forceinline__ uint2 kfold(uint2 k, uint32_t d){
  uint2 r; threefry(k.x, k.y, 0u, d, r.x, r.y); return r;
}
__device__ __forceinline__ uint32_t rbits(uint2 k, uint32_t i){
  uint32_t a, b; threefry(k.x, k.y, 0u, i, a, b); return a ^ b;
}

__device__ __forceinline__ float bits_to_unit(uint32_t b){
  return __uint_as_float((b >> 9) | 0x3f800000u) - 1.0f;  // [0,1)
}

// XLA (Giles 2012) float32 erf_inv
__device__ __forceinline__ float erfinv_f32(float x){
  float w = -log1pf(-x * x);
  float p;
  if (w < 5.0f){
    w = w - 2.5f;
    p =  2.81022636e-08f;
    p = fmaf(p, w,  3.43273939e-07f);
    p = fmaf(p, w, -3.5233877e-06f);
    p = fmaf(p, w, -4.39150654e-06f);
    p = fmaf(p, w,  0.00021858087f);
    p = fmaf(p, w, -0.00125372503f);
    p = fmaf(p, w, -0.00417768164f);
    p = fmaf(p, w,  0.246640727f);
    p = fmaf(p, w,  1.50140941f);
  } else {
    w = sqrtf(w) - 3.0f;
    p = -0.000200214257f;
    p = fmaf(p, w,  0.000100950558f);
    p = fmaf(p, w,  0.00134934322f);
    p = fmaf(p, w, -0.00367342844f);
    p = fmaf(p, w,  0.00573950773f);
    p = fmaf(p, w, -0.0076224613f);
    p = fmaf(p, w,  0.00943887047f);
    p = fmaf(p, w,  1.00167406f);
    p = fmaf(p, w,  2.83297682f);
  }
  return p * x;
}

#define SQRT2F 1.41421356f

__device__ __forceinline__ float normal_from_bits(uint32_t b){
  const float lo = -0.99999994f;              // nextafter(-1, 0) in f32
  float u = bits_to_unit(b);
  float v = fmaxf(lo, u * 2.0f + lo);
  return SQRT2F * erfinv_f32(v);
}

__device__ __forceinline__ cf cnormal(uint2 kre, uint2 kim, uint32_t e){
  float re = normal_from_bits(rbits(kre, e));
  float im = normal_from_bits(rbits(kim, e));
  return make_float2(re / SQRT2F, im / SQRT2F);
}

__device__ void noise_key_chain(uint32_t it, uint2 *out){
  uint2 k = kfold(make_uint2(0u, 7u), it);    // fold_in(key(7), it)
  for (int j = 0; j < NIN_; ++j){
    uint2 kk, kn;
    ksplit(k, kk, kn);
    k = kk;
    ksplit(kn, out[2*j], out[2*j + 1]);
  }
  uint2 k2, knW;
  ksplit(k, k2, knW);
  ksplit(knW, out[40], out[41]);
}

// ===================== setup kernel =====================
__global__ __launch_bounds__(1024)
void rng_kernel(float2* __restrict__ wsF, float2* __restrict__ wsW,
                float2* __restrict__ wsIW,
                float* __restrict__ wsT, float* __restrict__ wsU,
                float* __restrict__ wsC, float2* __restrict__ wsFst,
                float2* __restrict__ wsWst,
                const float* __restrict__ H_re, const float* __restrict__ H_im,
                const float* __restrict__ R_re, const float* __restrict__ R_im,
                const float* __restrict__ qF_qw, const float* __restrict__ qW_qw,
                const float* __restrict__ qF_W1, const float* __restrict__ qF_W2,
                const float* __restrict__ qF_W3, const float* __restrict__ qF_Wp,
                const float* __restrict__ qW_W1, const float* __restrict__ qW_W2,
                const float* __restrict__ qW_W3, const float* __restrict__ qW_Wp){
  __shared__ uint2 keys[42];
  const int bi = blockIdx.x, t = threadIdx.x;
  if (bi < NOUT_){
    if (t == 0) noise_key_chain((uint32_t)bi, keys);
    __syncthreads();
    for (int idx = t; idx < NIN_*FN_; idx += blockDim.x){
      int j = idx / FN_, e = idx - j*FN_;
      wsF[(size_t)bi*(NIN_*FN_) + idx] = cnormal(keys[2*j], keys[2*j + 1], (uint32_t)e);
    }
    for (int e = t; e < WN_; e += blockDim.x)
      wsW[(size_t)bi*WN_ + e] = cnormal(keys[40], keys[41], (uint32_t)e);
  } else if (bi == NOUT_){
    if (t == 0){
      uint2 k1, k2;
      ksplit(make_uint2(0u, 1u), k1, k2);
      keys[0] = k1;
      ksplit(k2, keys[1], keys[2]);
    }
    __syncthreads();
    const float TWOPI = 6.28318530717958647692f;
    for (int e = t; e < FN_; e += blockDim.x){
      float u = bits_to_unit(rbits(keys[0], (uint32_t)e));
      float ph = fmaxf(0.0f, u * TWOPI);
      float s, c; sincosf(ph, &s, &c);
      wsFst[e] = make_float2(c, s);
    }
    for (int e = t; e < WN_; e += blockDim.x){
      cf w = cnormal(keys[1], keys[2], (uint32_t)e);
      wsIW[e] = w;
      wsWst[e] = w;
    }
  } else if (bi < NOUT_ + 1 + 21){
    const int j = bi - (NOUT_ + 1);
    const bool isW = (j == 20);
    const float* W1 = isW ? qW_W1 : qF_W1 + j*(64*80);
    const float* W2 = isW ? qW_W2 : qF_W2 + j*(32*64);
    const float* W3 = isW ? qW_W3 : qF_W3 + j*(16*32);
    const float* Wp = isW ? qW_Wp : qF_Wp + j*(128*8);
    float* dst = wsT + j*TJOB_;
    for (int idx = t; idx < 5120; idx += blockDim.x){
      int q = idx >> 6, i = idx & 63;
      dst[idx] = W1[i*80 + q];
    }
    for (int idx = t; idx < 2048; idx += blockDim.x){
      int q = idx >> 5, i = idx & 31;
      dst[5120 + idx] = W2[i*64 + q];
    }
    for (int idx = t; idx < 512; idx += blockDim.x){
      int q = idx >> 4, i = idx & 15;
      dst[7168 + idx] = W3[i*32 + q];
    }
    const int nOut = isW ? 64 : 128;
    for (int idx = t; idx < 8*nOut; idx += blockDim.x){
      int z = idx / nOut, o = idx - z*nOut;
      dst[7680 + z*128 + o] = Wp[o*8 + z];
    }
  } else {
    if (t < 504){
      int j = t / 24, gg = t - j*24;
      const float* qw = (j == 20) ? qW_qw : qF_qw + j*72;
      float phi = qw[gg*3], th = qw[gg*3 + 1], om = qw[gg*3 + 2];
      float sh, ch; sincosf(0.5f*th, &sh, &ch);
      float sp, cp; sincosf(0.5f*(phi + om), &sp, &cp);
      float sm, cm; sincosf(0.5f*(phi - om), &sm, &cm);
      float* u = wsU + t*8;
      u[0] =  ch*cp; u[1] = -ch*sp;
      u[2] = -sh*cm; u[3] = -sh*sm;
      u[4] =  sh*cm; u[5] = -sh*sm;
      u[6] =  ch*cp; u[7] =  ch*sp;
    } else if (t < 520){
      int n = t - 504;
      float s = 0.f;
      for (int kbm = 0; kbm < 224; ++kbm){
        float re = H_re[kbm*16 + n], im = H_im[kbm*16 + n];
        s += sqrtf(re*re + im*im);
      }
      wsC[n] = s * (1.0f/224.0f);
    } else if (t < 776){
      int nv = t - 520;
      float s = 0.f;
      for (int kb = 0; kb < 112; ++kb){
        float re = R_re[kb*256 + nv], im = R_im[kb*256 + nv];
        s += sqrtf(re*re + im*im);
      }
      wsC[16 + nv] = s * (1.0f/112.0f);
    }
  }
}

// ===================== 8-qubit circuit =====================
__device__ __forceinline__ void gate(int q, cf u00, cf u01, cf u10, cf u11,
                                     cf &a0, cf &a1, cf &a2, cf &a3, int lane){
  if (q == 7){
    cf n0 = cadd(cmul(u00, a0), cmul(u01, a1));
    cf n1 = cadd(cmul(u10, a0), cmul(u11, a1));
    cf n2 = cadd(cmul(u00, a2), cmul(u01, a3));
    cf n3 = cadd(cmul(u10, a2), cmul(u11, a3));
    a0 = n0; a1 = n1; a2 = n2; a3 = n3;
  } else if (q == 6){
    cf n0 = cadd(cmul(u00, a0), cmul(u01, a2));
    cf n2 = cadd(cmul(u10, a0), cmul(u11, a2));
    cf n1 = cadd(cmul(u00, a1), cmul(u01, a3));
    cf n3 = cadd(cmul(u10, a1), cmul(u11, a3));
    a0 = n0; a1 = n1; a2 = n2; a3 = n3;
  } else {
    const int m = 1 << (5 - q);
    const bool hi = (lane & m) != 0;
    cf cO = hi ? u11 : u00;
    cf cP = hi ? u10 : u01;
    cf p0 = shflc(a0, m), p1 = shflc(a1, m), p2 = shflc(a2, m), p3 = shflc(a3, m);
    a0 = cadd(cmul(cO, a0), cmul(cP, p0));
    a1 = cadd(cmul(cO, a1), cmul(cP, p1));
    a2 = cadd(cmul(cO, a2), cmul(cP, p2));
    a3 = cadd(cmul(cO, a3), cmul(cP, p3));
  }
}

__device__ void run_circuit2(const float* trig, const float* uni, int lane, float z[8]){
  cf a0 = make_float2(lane == 0 ? 1.f : 0.f, 0.f);
  cf a1 = make_float2(0.f, 0.f), a2 = make_float2(0.f, 0.f), a3 = make_float2(0.f, 0.f);
  #pragma unroll
  for (int i = 0; i < 8; ++i){
    float sh = trig[2*i],      ch = trig[2*i + 1];
    float sp = trig[16 + 2*i], cp = trig[16 + 2*i + 1];
    float sm = trig[32 + 2*i], cm = trig[32 + 2*i + 1];
    cf u00 = make_float2( ch*cp, -ch*sp);
    cf u11 = make_float2( ch*cp,  ch*sp);
    cf u01 = make_float2(-sh*cm, -sh*sm);
    cf u10 = make_float2( sh*cm, -sh*sm);
    gate(i, u00, u01, u10, u11, a0, a1, a2, a3, lane);
  }
  for (int l = 0; l < 3; ++l){
    #pragma unroll
    for (int i = 0; i < 8; ++i){
      const float* u = uni + (l*8 + i)*8;
      gate(i, make_float2(u[0], u[1]), make_float2(u[2], u[3]),
              make_float2(u[4], u[5]), make_float2(u[6], u[7]), a0, a1, a2, a3, lane);
    }
    #pragma unroll
    for (int i = 0; i < 5; ++i){
      const int cm_ = 1 << (5 - i), tm = 1 << (4 - i);
      const bool c = (lane & cm_) != 0;
      cf p0 = shflc(a0, tm), p1 = shflc(a1, tm), p2 = shflc(a2, tm), p3 = shflc(a3, tm);
      a0 = c ? p0 : a0; a1 = c ? p1 : a1; a2 = c ? p2 : a2; a3 = c ? p3 : a3;
    }
    {
      const bool c = (lane & 1) != 0;
      cf t0 = c ? a2 : a0, t2 = c ? a0 : a2;
      cf t1 = c ? a3 : a1, t3 = c ? a1 : a3;
      a0 = t0; a1 = t1; a2 = t2; a3 = t3;
    }
    { cf tmp = a2; a2 = a3; a3 = tmp; }
    a1 = shflc(a1, 32);
    a3 = shflc(a3, 32);
  }
  const float p0 = a0.x*a0.x + a0.y*a0.y;
  const float p1 = a1.x*a1.x + a1.y*a1.y;
  const float p2 = a2.x*a2.x + a2.y*a2.y;
  const float p3 = a3.x*a3.x + a3.y*a3.y;
  const float tot = p0 + p1 + p2 + p3;
  z[6] = (p0 + p1) - (p2 + p3);
  z[7] = (p0 + p2) - (p1 + p3);
  #pragma unroll
  for (int i = 0; i < 6; ++i)
    z[i] = ((lane >> (5 - i)) & 1) ? -tot : tot;
  #pragma unroll
  for (int m = 1; m < 64; m <<= 1){
    #pragma unroll
    for (int i = 0; i < 8; ++i) z[i] += __shfl_xor(z[i], m, 64);
  }
}

// ===================== K2: feature-assemble + projection + MLP + circuit (21 WGs x 128) =====================
__global__ __launch_bounds__(128)
void k_qblock2(const float* __restrict__ wsT, const float* __restrict__ wsU,
               const float* __restrict__ wsC,
               const float* __restrict__ wsFeatA, const float* __restrict__ wsFeatG,
               const float* __restrict__ wsPart,
               const float* __restrict__ projW, const float* __restrict__ projB,
               const float* __restrict__ qF_b1, const float* __restrict__ qF_b2,
               const float* __restrict__ qF_b3, const float* __restrict__ qF_bp,
               const float* __restrict__ qW_b1, const float* __restrict__ qW_b2,
               const float* __restrict__ qW_b3, const float* __restrict__ qW_bp,
               float2* __restrict__ wsdF, float2* __restrict__ wsdW){
  const int j = blockIdx.x;
  const int t = threadIdx.x;
  const int lane = t & 63;
  const int wv = t >> 6;
  const bool isW = (j == 20);
  __shared__ float sS[500];
  __shared__ float sSt[80];
  __shared__ float mlp[160];
  __shared__ float luni[192];
  for (int i = t; i < 192; i += 128) luni[i] = wsU[j*192 + i];
  // assemble sS[500] (identical values/order to R6-persist phase A, proven)
  for (int i = t; i < 112; i += 128){ sS[i] = wsFeatA[i]; sS[112 + i] = wsFeatG[i]; }
  if (t < 4){
    float s = 0.f;
    for (int bb = 0; bb < 28; ++bb) s += wsPart[bb*4 + t];
    sS[224 + t] = s * (1.0f/448.0f);
  }
  for (int i = t; i < 272; i += 128) sS[228 + i] = wsC[i];
  __syncthreads();
  // projection: 10 rounds split across 2 waves (5 each); per-(o,i) fma order
  // identical to R4/R5 (j2 = i, i+8, ..., <500). Compile-time trip count so
  // hipcc unrolls and pipelines the loads (R7's runtime-start loop serialized
  // at one L2/L3 latency per iteration -> 180us/dispatch).
  for (int r5 = 0; r5 < 5; ++r5){
    int round = wv*5 + r5;
    int o = round*8 + (lane >> 3), i = lane & 7;
    const float* row = projW + o*500;
    float acc = 0.f;
    #pragma unroll
    for (int s = 0; s < 63; ++s){
      int j2 = i + 8*s;
      if (j2 < 500) acc = fmaf(sS[j2], row[j2], acc);
    }
    #pragma unroll
    for (int m = 1; m < 8; m <<= 1) acc += __shfl_xor(acc, m, 64);
    if (i == 0) sSt[o] = acc + projB[o];
  }
  __syncthreads();

  if (t < 64){
    const float* b1 = isW ? qW_b1 : qF_b1 + j*64;
    const float* b2 = isW ? qW_b2 : qF_b2 + j*32;
    const float* b3 = isW ? qW_b3 : qF_b3 + j*16;
    const float* bp = isW ? qW_bp : qF_bp + j*128;
    const float* w1t = wsT + j*TJOB_;
    const float* w2t = w1t + 5120;
    const float* w3t = w1t + 7168;
    const float* wpt = w1t + 7680;

    { // h1[64]
      float acc = b1[lane];
      for (int q = 0; q < 80; ++q) acc = fmaf(w1t[q*64 + lane], sSt[q], acc);
      mlp[lane] = tanhf(acc);
    }
    __builtin_amdgcn_wave_barrier();
    { // h2[32]
      int i2 = lane & 31;
      float acc = b2[i2];
      for (int q = 0; q < 64; ++q) acc = fmaf(w2t[q*32 + i2], mlp[q], acc);
      float h2 = tanhf(acc);
      __builtin_amdgcn_wave_barrier();
      if (lane < 32) mlp[64 + lane] = h2;
    }
    __builtin_amdgcn_wave_barrier();
    { // ang[16]
      int i3 = lane & 15;
      float acc = b3[i3];
      for (int q = 0; q < 32; ++q) acc = fmaf(w3t[q*16 + i3], mlp[64 + q], acc);
      __builtin_amdgcn_wave_barrier();
      if (lane < 16) mlp[96 + lane] = acc;
    }
    __builtin_amdgcn_wave_barrier();
    if (lane < 24){
      int i = lane & 7, which = lane >> 3;
      float th = mlp[96 + i], om = mlp[96 + 8 + i];
      float arg = (which == 0) ? 0.5f*th
                : (which == 1) ? 0.5f*(0.f + om)
                               : 0.5f*(0.f - om);
      float s, c; sincosf(arg, &s, &c);
      mlp[112 + which*16 + 2*i]     = s;
      mlp[112 + which*16 + 2*i + 1] = c;
    }
    __builtin_amdgcn_wave_barrier();
    float z[8];
    run_circuit2(mlp + 112, luni, lane, z);
    if (!isW){
      float o0 = bp[lane];
      float o1 = bp[64 + lane];
      #pragma unroll
      for (int i = 0; i < 8; ++i){
        o0 = fmaf(wpt[i*128 + lane],      z[i], o0);
        o1 = fmaf(wpt[i*128 + 64 + lane], z[i], o1);
      }
      __builtin_amdgcn_wave_barrier();
      mlp[lane] = o0; mlp[64 + lane] = o1;
      __builtin_amdgcn_wave_barrier();
      wsdF[j*64 + lane] = make_float2(mlp[2*lane], mlp[2*lane + 1]);
    } else {
      float o0 = bp[lane];
      #pragma unroll
      for (int i = 0; i < 8; ++i) o0 = fmaf(wpt[i*128 + lane], z[i], o0);
      __builtin_amdgcn_wave_barrier();
      mlp[lane] = o0;
      __builtin_amdgcn_wave_barrier();
      if (lane < 32) wsdW[lane] = make_float2(mlp[2*lane], mlp[2*lane + 1]);
    }
  }
}

// ===================== K3: per-b update + normalize + X + metrics + features (28 WGs x 128) =====================
__global__ __launch_bounds__(128)
void k_update(const float* __restrict__ H_re, const float* __restrict__ H_im,
              const float* __restrict__ R_re, const float* __restrict__ R_im,
              const float* __restrict__ Pt_p, const float* __restrict__ step_p,
              const float2* __restrict__ wsF, const float2* __restrict__ wsW,
              const float2* __restrict__ wsdF, const float2* __restrict__ wsdW,
              float2* __restrict__ wsFst, float2* __restrict__ wsWst,
              float* __restrict__ wsFeatA, float* __restrict__ wsFeatG,
              float* __restrict__ wsPart,
              float* __restrict__ out, int it, int mode){
  const int b = blockIdx.x;
  const int t = threadIdx.x;
  __shared__ cf lF[64];
  __shared__ cf lW[32];
  __shared__ cf lX[128];
  __shared__ float scrA[96], scrG[96];
  __shared__ float red2[2];
  __shared__ float sscale;
  __shared__ float heR[16], heI[16];
  __shared__ float sKBl[4], sKB2l[4];
  const float c1 = step_p[0] * 0.001f;
  const float Ptv = Pt_p[0];

  if (t < 64){
    const int n = t >> 2, r = t & 3;
    const int e = n*112 + b*4 + r;
    cf F = wsFst[e];
    if (mode){
      const float2* np = wsF + (size_t)it*(NIN_*FN_);
      cf nzA[10], dvA[10], nzB[10], dvB[10];
      #pragma unroll
      for (int s = 0; s < 10; ++s){ nzA[s] = np[s*FN_ + e];        dvA[s] = wsdF[s*64 + t]; }
      #pragma unroll
      for (int s = 0; s < 10; ++s){ nzB[s] = np[(10 + s)*FN_ + e]; dvB[s] = wsdF[(10 + s)*64 + t]; }
      #pragma unroll
      for (int s = 0; s < 10; ++s){
        F.x = F.x + c1*nzA[s].x + 0.001f*dvA[s].x;
        F.y = F.y + c1*nzA[s].y + 0.001f*dvA[s].y;
        float rr = sqrtf(F.x*F.x + F.y*F.y) + 1e-12f;
        F.x /= rr; F.y /= rr;
      }
      #pragma unroll
      for (int s = 0; s < 10; ++s){
        F.x = F.x + c1*nzB[s].x + 0.001f*dvB[s].x;
        F.y = F.y + c1*nzB[s].y + 0.001f*dvB[s].y;
        float rr = sqrtf(F.x*F.x + F.y*F.y) + 1e-12f;
        F.x /= rr; F.y /= rr;
      }
    }
    // _normalize
    float rr = sqrtf(F.x*F.x + F.y*F.y) + 1e-12f;
    F.x /= rr; F.y /= rr;
    lF[t] = F;
    wsFst[e] = F;
  } else if (t < 96){
    const int wi = t - 64;
    const int k = wi >> 3, ru = wi & 7;
    const int ew = (k*28 + b)*8 + ru;
    cf w = wsWst[ew];
    if (mode){
      cf nw = wsW[(size_t)it*WN_ + ew];
      cf dw = wsdW[k*8 + ru];
      w.x = w.x + c1*nw.x + 0.001f*dw.x;
      w.y = w.y + c1*nw.y + 0.001f*dw.y;
    }
    lW[wi] = w;
  }
  __syncthreads();
  // X[k,n,u] = sum_r F[n,r] W[k,r,u]
  {
    int u = t & 1, n = (t >> 1) & 15, k = t >> 5;
    const cf* fr = lF + n*4;
    const cf* wr = lW + k*8 + u;
    cf acc = cmul(fr[0], wr[0]);
    acc = cadd(acc, cmul(fr[1], wr[2]));
    acc = cadd(acc, cmul(fr[2], wr[4]));
    acc = cadd(acc, cmul(fr[3], wr[6]));
    lX[t] = acc;
  }
  __syncthreads();
  {
    float s = lX[t].x*lX[t].x + lX[t].y*lX[t].y;
    #pragma unroll
    for (int m = 1; m < 64; m <<= 1) s += __shfl_xor(s, m, 64);
    if ((t & 63) == 0) red2[t >> 6] = s;
  }
  __syncthreads();
  if (t == 0) sscale = sqrtf(Ptv / ((red2[0] + red2[1]) + 1e-12f));
  __syncthreads();
  const float sc = sscale;
  if (t < 32){
    const int k = t >> 3, ru = t & 7;
    const int ew = (k*28 + b)*8 + ru;
    cf w = csc(sc, lW[t]);
    lW[t] = w;
    wsWst[ew] = w;
  }
  lX[t] = csc(sc, lX[t]);
  __syncthreads();
  // He entries
  if (t < 16){
    const int k = t >> 2, ent = t & 3;
    const int m = ent >> 1, u = ent & 1;
    const float* hr = H_re + (k*28 + b)*32 + m*16;
    const float* hi = H_im + (k*28 + b)*32 + m*16;
    cf He = make_float2(0.f, 0.f);
    for (int n = 0; n < 16; ++n){
      cf h = make_float2(hr[n], hi[n]);
      He = cadd(He, cmul(h, lX[k*32 + n*2 + u]));
    }
    heR[t] = He.x; heI[t] = He.y;
  }
  __builtin_amdgcn_wave_barrier();
  if (t < 4){
    const int k = t;
    cf He00 = make_float2(heR[k*4 + 0], heI[k*4 + 0]);
    cf He01 = make_float2(heR[k*4 + 1], heI[k*4 + 1]);
    cf He10 = make_float2(heR[k*4 + 2], heI[k*4 + 2]);
    cf He11 = make_float2(heR[k*4 + 3], heI[k*4 + 3]);
    cf G00 = cadd(cmulc(He00, He00), cmulc(He01, He01));
    cf G01 = cadd(cmulc(He00, He10), cmulc(He01, He11));
    cf G10 = cadd(cmulc(He10, He00), cmulc(He11, He01));
    cf G11 = cadd(cmulc(He10, He10), cmulc(He11, He11));
    cf A00 = make_float2(1.f + Ptv*G00.x, Ptv*G00.y);
    cf A01 = csc(Ptv, G01);
    cf A10 = csc(Ptv, G10);
    cf A11 = make_float2(1.f + Ptv*G11.x, Ptv*G11.y);
    float detre = (A00.x*A11.x - A00.y*A11.y) - (A01.x*A10.x - A01.y*A10.y);
    sKBl[k] = log2f(fabsf(detre) + 1e-12f);
  }
  // beam error
  {
    const int k = t >> 5, i = t & 31;
    const float* rr = R_re + (k*28 + b)*256;
    const float* ri = R_im + (k*28 + b)*256;
    float acc = 0.f;
    #pragma unroll
    for (int c = 0; c < 8; ++c){
      int nv = c*32 + i;
      int n = nv >> 4, v = nv & 15;
      cf xn0 = lX[k*32 + n*2], xn1 = lX[k*32 + n*2 + 1];
      cf xv0 = lX[k*32 + v*2], xv1 = lX[k*32 + v*2 + 1];
      cf C = cadd(cmulc(xn0, xv0), cmulc(xn1, xv1));
      float dr = C.x - rr[nv], di = C.y - ri[nv];
      acc += dr*dr + di*di;
    }
    #pragma unroll
    for (int m = 1; m < 32; m <<= 1) acc += __shfl_xor(acc, m, 64);
    if (i == 0) sKB2l[k] = sqrtf(acc + 1e-12f);
  }
  __syncthreads();
  if (t == 0){
    const int slot = mode ? (it + 1) : 0;
    out[b*121 + slot] = sKBl[0] + sKBl[1] + sKBl[2] + sKBl[3];
    out[O_TAUS + b*121 + slot] = 0.25f*(sKB2l[0] + sKB2l[1] + sKB2l[2] + sKB2l[3]);
  }
  // ---- state features for next iteration (proven in R6-persist)
  if (t < 64){
    cf f = lF[t];
    scrA[t] = sqrtf(f.x*f.x + f.y*f.y);
    scrG[t] = atan2f(f.y, f.x);
  } else if (t < 96){
    cf w = lW[t - 64];
    scrA[t] = sqrtf(w.x*w.x + w.y*w.y);
    scrG[t] = atan2f(w.y, w.x);
  }
  __syncthreads();
  if (t < 8){
    int r = t & 3;
    const float* src = (t < 4) ? scrA : scrG;
    float s = 0.f;
    for (int n = 0; n < 16; ++n) s += src[n*4 + r];
    float* dst = (t < 4) ? wsFeatA : wsFeatG;
    dst[b*4 + r] = s * (1.0f/16.0f);
  } else if (t >= 8 && t < 12){
    int tt = t - 8;
    int u = tt & 1; bool isG = tt >= 2;
    const float* src = isG ? scrG : scrA;
    float s = 0.f;
    for (int i = 0; i < 16; ++i) s += src[64 + i*2 + u];
    wsPart[b*4 + tt] = s;
  }
}

// ===================== K4: final F/W serialization =====================
__global__ __launch_bounds__(1024)
void k_out(const float2* __restrict__ wsFst, const float2* __restrict__ wsWst,
           float* __restrict__ out, int fmode){
  const int t = threadIdx.x;
  if (fmode == 1){
    for (int e = t; e < FN_; e += 1024){
      out[O_F + e]       = wsFst[e].x;
      out[O_F + FN_ + e] = wsFst[e].y;
    }
    for (int e = t; e < WN_; e += 1024){
      out[O_W + e]       = wsWst[e].x;
      out[O_W + WN_ + e] = wsWst[e].y;
    }
  } else if (fmode == 2){
    for (int e = t; e < FN_; e += 1024) out[O_F + e] = wsFst[e].x;
    for (int e = t; e < WN_; e += 1024) out[O_F + FN_ + e] = wsWst[e].x;
  } else {
    for (int e = t; e < FN_; e += 1024){
      out[O_F + 2*e]     = wsFst[e].x;
      out[O_F + 2*e + 1] = wsFst[e].y;
    }
    for (int e = t; e < WN_; e += 1024){
      out[O_W + 2*e]     = wsWst[e].x;
      out[O_W + 2*e + 1] = wsWst[e].y;
    }
  }
}

// ===================== fallback: single-WG monolith (used only if ws too small) =====================
__global__ __launch_bounds__(1024)
void main_kernel(const float* __restrict__ H_re, const float* __restrict__ H_im,
                 const float* __restrict__ R_re, const float* __restrict__ R_im,
                 const float* __restrict__ Pt_p, const float* __restrict__ step_p,
                 const float* __restrict__ qF_W1, const float* __restrict__ qF_b1,
                 const float* __restrict__ qF_W2, const float* __restrict__ qF_b2,
                 const float* __restrict__ qF_W3, const float* __restrict__ qF_b3,
                 const float* __restrict__ qF_qw, const float* __restrict__ qF_Wp,
                 const float* __restrict__ qF_bp,
                 const float* __restrict__ qW_W1, const float* __restrict__ qW_b1,
                 const float* __restrict__ qW_W2, const float* __restrict__ qW_b2,
                 const float* __restrict__ qW_W3, const float* __restrict__ qW_b3,
                 const float* __restrict__ qW_qw, const float* __restrict__ qW_Wp,
                 const float* __restrict__ qW_bp,
                 const float* __restrict__ projW, const float* __restrict__ projB,
                 float* __restrict__ out, int fmode)
{
  const int t = threadIdx.x;
  const int lane = t & 63;
  const int wv = t >> 6;

  __shared__ cf sF[FN_];
  __shared__ cf sW[WN_];
  __shared__ float sS[500];
  __shared__ float sSt[80];
  __shared__ float sScale[B_];
  __shared__ float sKB[112];
  __shared__ float sKB2[112];
  __shared__ float sRed[64];
  __shared__ uint2 sKeys[42];
  __shared__ float sPar[2];
  __shared__ float sUni[21*24*8];
  __shared__ __align__(16) unsigned char uPool[XN_ * sizeof(cf)];
  cf*    sX   = (cf*)uPool;
  cf*    sdF  = (cf*)uPool;
  cf*    sdW  = (cf*)(uPool + NIN_*64*sizeof(cf));
  float* sMLP = (float*)(uPool + NIN_*64*sizeof(cf) + 32*sizeof(cf));

  if (t == 0){ sPar[0] = step_p[0]; sPar[1] = Pt_p[0]; }

  if (t < 504){
    int j = t / 24, gg = t - j*24;
    const float* qw = (j == 20) ? qW_qw : qF_qw + j*72;
    float phi = qw[gg*3], th = qw[gg*3 + 1], om = qw[gg*3 + 2];
    float sh, ch; sincosf(0.5f*th, &sh, &ch);
    float sp, cp; sincosf(0.5f*(phi + om), &sp, &cp);
    float sm, cm; sincosf(0.5f*(phi - om), &sm, &cm);
    float* u = sUni + t*8;
    u[0] =  ch*cp; u[1] = -ch*sp;
    u[2] = -sh*cm; u[3] = -sh*sm;
    u[4] =  sh*cm; u[5] = -sh*sm;
    u[6] =  ch*cp; u[7] =  ch*sp;
  }

  {
    float* scratch = (float*)uPool;
    float local = 0.f;
    for (int i = t; i < 3584; i += 1024) local += sqrtf(H_re[i]*H_re[i] + H_im[i]*H_im[i]);
    scratch[t] = local;
    __syncthreads();
    for (int s = 512; s >= 16; s >>= 1){
      if (t < s) scratch[t] += scratch[t + s];
      __syncthreads();
    }
    if (t < 16) sS[228 + t] = scratch[t] * (1.0f/224.0f);
    __syncthreads();
    local = 0.f;
    for (int i = t; i < 28672; i += 1024) local += sqrtf(R_re[i]*R_re[i] + R_im[i]*R_im[i]);
    scratch[t] = local;
    __syncthreads();
    for (int s = 512; s >= 256; s >>= 1){
      if (t < s) scratch[t] += scratch[t + s];
      __syncthreads();
    }
    if (t < 256) sS[244 + t] = scratch[t] * (1.0f/112.0f);
    __syncthreads();
  }

  {
    if (t == 0){
      uint2 k1, k2; ksplit(make_uint2(0u, 1u), k1, k2);
      sKeys[0] = k1; ksplit(k2, sKeys[1], sKeys[2]);
    }
    __syncthreads();
    const float TWOPI = 6.28318530717958647692f;
    for (int e = t; e < FN_; e += 1024){
      float u = bits_to_unit(rbits(sKeys[0], (uint32_t)e));
      float ph = fmaxf(0.0f, u * TWOPI);
      float s, c; sincosf(ph, &s, &c);
      sF[e] = make_float2(c, s);
    }
    for (int e = t; e < WN_; e += 1024) sW[e] = cnormal(sKeys[1], sKeys[2], (uint32_t)e);
  }
  __syncthreads();

  const float stepv = sPar[0], Ptv = sPar[1];
  const float c1 = stepv * 0.001f;

  for (int it = -1; it < NOUT_; ++it){
    if (it >= 0){
      if (t == 0) noise_key_chain((uint32_t)it, sKeys);
      __syncthreads();
      if (t < 112){
        float sa = 0.f, sg = 0.f;
        for (int n = 0; n < NT_; ++n){
          cf f = sF[n*112 + t];
          sa += sqrtf(f.x*f.x + f.y*f.y);
          sg += atan2f(f.y, f.x);
        }
        sS[t]       = sa * (1.0f/16.0f);
        sS[112 + t] = sg * (1.0f/16.0f);
      }
      {
        float aW = 0.f, gW = 0.f;
        if (t < WN_){
          cf w = sW[t];
          aW = sqrtf(w.x*w.x + w.y*w.y);
          gW = atan2f(w.y, w.x);
        }
        #pragma unroll
        for (int m = 2; m < 64; m <<= 1){
          aW += __shfl_xor(aW, m, 64);
          gW += __shfl_xor(gW, m, 64);
        }
        if (t < WN_ && lane < 2){
          sRed[wv*2 + lane] = aW;
          sRed[32 + wv*2 + lane] = gW;
        }
      }
      __syncthreads();
      if (t < 4){
        int u = t & 1;
        int base = (t >= 2) ? 32 : 0;
        float s = 0.f;
        for (int w = 0; w < 14; ++w) s += sRed[base + w*2 + u];
        sS[224 + t] = s * (1.0f/448.0f);
      }
      __syncthreads();
      if (t < 640){
        int o = t >> 3, i = t & 7;
        const float* row = projW + o*500;
        float acc = 0.f;
        for (int j = i; j < 500; j += 8) acc = fmaf(sS[j], row[j], acc);
        #pragma unroll
        for (int m = 1; m < 8; m <<= 1) acc += __shfl_xor(acc, m, 64);
        if (i == 0) sSt[o] = acc + projB[o];
      }
      __syncthreads();
      for (int rnd = 0; rnd < 2; ++rnd){
        int j = wv + rnd*16;
        if (j < 21){
          const bool isW = (j == 20);
          const float* b1 = isW ? qW_b1 : qF_b1 + j*64;
          const float* b2 = isW ? qW_b2 : qF_b2 + j*32;
          const float* b3 = isW ? qW_b3 : qF_b3 + j*16;
          const float* bp = isW ? qW_bp : qF_bp + j*128;
          float* mlp = sMLP + wv*160;
          const float* W1 = isW ? qW_W1 : qF_W1 + j*(64*80);
          const float* W2 = isW ? qW_W2 : qF_W2 + j*(32*64);
          const float* W3 = isW ? qW_W3 : qF_W3 + j*(16*32);
          const float* Wp = isW ? qW_Wp : qF_Wp + j*(128*8);
          {
            const float* row = W1 + lane*80;
            float acc = b1[lane];
            for (int q = 0; q < 80; ++q) acc = fmaf(row[q], sSt[q], acc);
            mlp[lane] = tanhf(acc);
          }
          __builtin_amdgcn_wave_barrier();
          {
            int i2 = lane & 31;
            const float* row = W2 + i2*64;
            float acc = b2[i2];
            for (int q = 0; q < 64; ++q) acc = fmaf(row[q], mlp[q], acc);
            float h2 = tanhf(acc);
            __builtin_amdgcn_wave_barrier();
            if (lane < 32) mlp[64 + lane] = h2;
          }
          __builtin_amdgcn_wave_barrier();
          {
            int i3 = lane & 15;
            const float* row = W3 + i3*32;
            float acc = b3[i3];
            for (int q = 0; q < 32; ++q) acc = fmaf(row[q], mlp[64 + q], acc);
            __builtin_amdgcn_wave_barrier();
            if (lane < 16) mlp[96 + lane] = acc;
          }
          __builtin_amdgcn_wave_barrier();
          if (lane < 24){
            int i = lane & 7, which = lane >> 3;
            float th = mlp[96 + i], om = mlp[96 + 8 + i];
            float arg = (which == 0) ? 0.5f*th
                      : (which == 1) ? 0.5f*(0.f + om)
                                     : 0.5f*(0.f - om);
            float s, c; sincosf(arg, &s, &c);
            mlp[112 + which*16 + 2*i]     = s;
            mlp[112 + which*16 + 2*i + 1] = c;
          }
          __builtin_amdgcn_wave_barrier();
          float z[8];
          run_circuit2(mlp + 112, sUni + j*192, lane, z);
          if (!isW){
            float o0 = bp[lane];
            float o1 = bp[64 + lane];
            const float* r0 = Wp + lane*8;
            const float* r1 = Wp + (64 + lane)*8;
            #pragma unroll
            for (int i = 0; i < 8; ++i){
              o0 = fmaf(r0[i], z[i], o0);
              o1 = fmaf(r1[i], z[i], o1);
            }
            __builtin_amdgcn_wave_barrier();
            mlp[lane] = o0; mlp[64 + lane] = o1;
            __builtin_amdgcn_wave_barrier();
            sdF[j*64 + lane] = make_float2(mlp[2*lane], mlp[2*lane + 1]);
          } else {
            float o0 = bp[lane];
            const float* r0 = Wp + lane*8;
            #pragma unroll
            for (int i = 0; i < 8; ++i) o0 = fmaf(r0[i], z[i], o0);
            __builtin_amdgcn_wave_barrier();
            mlp[lane] = o0;
            __builtin_amdgcn_wave_barrier();
            if (lane < 32) sdW[lane] = make_float2(mlp[2*lane], mlp[2*lane + 1]);
          }
        }
      }
      __syncthreads();
      if (t < 896){
        cf f0 = sF[t], f1 = sF[t + 896];
        const int dfi0 = (t/112)*4 + (t & 3);
        const int dfi1 = dfi0 + 32;
        for (int j = 0; j < NIN_; ++j){
          cf n0 = cnormal(sKeys[2*j], sKeys[2*j + 1], (uint32_t)t);
          cf n1 = cnormal(sKeys[2*j], sKeys[2*j + 1], (uint32_t)(t + 896));
          cf d0 = sdF[j*64 + dfi0], d1 = sdF[j*64 + dfi1];
          f0.x = f0.x + c1*n0.x + 0.001f*d0.x;
          f0.y = f0.y + c1*n0.y + 0.001f*d0.y;
          f1.x = f1.x + c1*n1.x + 0.001f*d1.x;
          f1.y = f1.y + c1*n1.y + 0.001f*d1.y;
          float r0 = sqrtf(f0.x*f0.x + f0.y*f0.y) + 1e-12f;
          float r1 = sqrtf(f1.x*f1.x + f1.y*f1.y) + 1e-12f;
          f0.x /= r0; f0.y /= r0;
          f1.x /= r1; f1.y /= r1;
        }
        sF[t] = f0; sF[t + 896] = f1;
      }
      if (t < 448){
        cf w0 = sW[t], w1 = sW[t + 448];
        cf n0 = cnormal(sKeys[40], sKeys[41], (uint32_t)t);
        cf n1 = cnormal(sKeys[40], sKeys[41], (uint32_t)(t + 448));
        int dwi0 = (t/224)*8 + (t & 7);
        int dwi1 = ((t + 448)/224)*8 + (t & 7);
        cf d0 = sdW[dwi0], d1 = sdW[dwi1];
        w0.x = w0.x + c1*n0.x + 0.001f*d0.x;
        w0.y = w0.y + c1*n0.y + 0.001f*d0.y;
        w1.x = w1.x + c1*n1.x + 0.001f*d1.x;
        w1.y = w1.y + c1*n1.y + 0.001f*d1.y;
        sW[t] = w0; sW[t + 448] = w1;
      }
      __syncthreads();
    }

    for (int e = t; e < FN_; e += 1024){
      cf f = sF[e];
      float r = sqrtf(f.x*f.x + f.y*f.y) + 1e-12f;
      f.x /= r; f.y /= r;
      sF[e] = f;
    }
    __syncthreads();
    for (int x = t; x < XN_; x += 1024){
      int u = x & 1, n = (x >> 1) & 15, kb = x >> 5;
      int b = kb - (kb/28)*28;
      const cf* fr = sF + n*112 + b*4;
      const cf* wr = sW + kb*8 + u;
      cf acc = cmul(fr[0], wr[0]);
      acc = cadd(acc, cmul(fr[1], wr[2]));
      acc = cadd(acc, cmul(fr[2], wr[4]));
      acc = cadd(acc, cmul(fr[3], wr[6]));
      sX[x] = acc;
    }
    __syncthreads();
    if (t < 896){
      int b = t >> 5, i = t & 31;
      float s = 0.f;
      #pragma unroll
      for (int k = 0; k < 4; ++k){
        cf v = sX[(k*28 + b)*32 + i];
        s += v.x*v.x + v.y*v.y;
      }
      #pragma unroll
      for (int m = 1; m < 32; m <<= 1) s += __shfl_xor(s, m, 64);
      if (i == 0) sScale[b] = sqrtf(Ptv / (s + 1e-12f));
    }
    __syncthreads();
    for (int e = t; e < WN_; e += 1024){
      int kb = e >> 3;
      sW[e] = csc(sScale[kb - (kb/28)*28], sW[e]);
    }
    for (int x = t; x < XN_; x += 1024){
      int kb = x >> 5;
      sX[x] = csc(sScale[kb - (kb/28)*28], sX[x]);
    }
    __syncthreads();
    if (t < 112){
      const int kb = t;
      cf He00 = make_float2(0.f,0.f), He01 = He00, He10 = He00, He11 = He00;
      const float* hr = H_re + kb*32;
      const float* hi = H_im + kb*32;
      for (int n = 0; n < 16; ++n){
        cf x0 = sX[kb*32 + n*2], x1 = sX[kb*32 + n*2 + 1];
        cf h0 = make_float2(hr[n],      hi[n]);
        cf h1 = make_float2(hr[16 + n], hi[16 + n]);
        He00 = cadd(He00, cmul(h0, x0));
        He01 = cadd(He01, cmul(h0, x1));
        He10 = cadd(He10, cmul(h1, x0));
        He11 = cadd(He11, cmul(h1, x1));
      }
      cf G00 = cadd(cmulc(He00, He00), cmulc(He01, He01));
      cf G01 = cadd(cmulc(He00, He10), cmulc(He01, He11));
      cf G10 = cadd(cmulc(He10, He00), cmulc(He11, He01));
      cf G11 = cadd(cmulc(He10, He10), cmulc(He11, He11));
      cf A00 = make_float2(1.f + Ptv*G00.x, Ptv*G00.y);
      cf A01 = csc(Ptv, G01);
      cf A10 = csc(Ptv, G10);
      cf A11 = make_float2(1.f + Ptv*G11.x, Ptv*G11.y);
      float detre = (A00.x*A11.x - A00.y*A11.y) - (A01.x*A10.x - A01.y*A10.y);
      sKB[kb] = log2f(fabsf(detre) + 1e-12f);
    }
    if (t >= 128){
      int tt = t - 128, kb = tt >> 3, i = tt & 7;
      const float* rr = R_re + kb*256;
      const float* ri = R_im + kb*256;
      float acc = 0.f;
      for (int c = 0; c < 32; ++c){
        int nv = i + (c << 3);
        int n = nv >> 4, v = nv & 15;
        cf xn0 = sX[kb*32 + n*2], xn1 = sX[kb*32 + n*2 + 1];
        cf xv0 = sX[kb*32 + v*2], xv1 = sX[kb*32 + v*2 + 1];
        cf C = cadd(cmulc(xn0, xv0), cmulc(xn1, xv1));
        float dr = C.x - rr[nv], di = C.y - ri[nv];
        acc += dr*dr + di*di;
      }
      #pragma unroll
      for (int m = 1; m < 8; m <<= 1) acc += __shfl_xor(acc, m, 64);
      if (i == 0) sKB2[kb] = sqrtf(acc + 1e-12f);
    }
    __syncthreads();
    if (t < 28){
      const int slot = it + 1;
      out[t*121 + slot] = sKB[t] + sKB[28 + t] + sKB[56 + t] + sKB[84 + t];
      out[O_TAUS + t*121 + slot] = 0.25f*(sKB2[t] + sKB2[28 + t] + sKB2[56 + t] + sKB2[84 + t]);
    }
    __syncthreads();
  }

  if (fmode == 1){
    for (int e = t; e < FN_; e += 1024){
      out[O_F + e]       = sF[e].x;
      out[O_F + FN_ + e] = sF[e].y;
    }
    for (int e = t; e < WN_; e += 1024){
      out[O_W + e]       = sW[e].x;
      out[O_W + WN_ + e] = sW[e].y;
    }
  } else if (fmode == 2){
    for (int e = t; e < FN_; e += 1024) out[O_F + e] = sF[e].x;
    for (int e = t; e < WN_; e += 1024) out[O_F + FN_ + e] = sW[e].x;
  } else {
    for (int e = t; e < FN_; e += 1024){
      out[O_F + 2*e]     = sF[e].x;
      out[O_F + 2*e + 1] = sF[e].y;
    }
    for (int e = t; e < WN_; e += 1024){
      out[O_W + 2*e]     = sW[e].x;
      out[O_W + 2*e + 1] = sW[e].y;
    }
  }
}

// ===================== host =====================
extern "C" void kernel_launch(void* const* d_in, const int* in_sizes, int n_in,
                              void* d_out, int out_size, void* d_ws, size_t ws_size,
                              hipStream_t stream){
  (void)in_sizes; (void)n_in;
  const float* H_re  = (const float*)d_in[0];
  const float* H_im  = (const float*)d_in[1];
  const float* R_re  = (const float*)d_in[2];
  const float* R_im  = (const float*)d_in[3];
  const float* Pt    = (const float*)d_in[4];
  const float* stp   = (const float*)d_in[5];
  const float* qF_W1 = (const float*)d_in[6];
  const float* qF_b1 = (const float*)d_in[7];
  const float* qF_W2 = (const float*)d_in[8];
  const float* qF_b2 = (const float*)d_in[9];
  const float* qF_W3 = (const float*)d_in[10];
  const float* qF_b3 = (const float*)d_in[11];
  const float* qF_qw = (const float*)d_in[12];
  const float* qF_Wp = (const float*)d_in[13];
  const float* qF_bp = (const float*)d_in[14];
  const float* qW_W1 = (const float*)d_in[15];
  const float* qW_b1 = (const float*)d_in[16];
  const float* qW_W2 = (const float*)d_in[17];
  const float* qW_b2 = (const float*)d_in[18];
  const float* qW_W3 = (const float*)d_in[19];
  const float* qW_b3 = (const float*)d_in[20];
  const float* qW_qw = (const float*)d_in[21];
  const float* qW_Wp = (const float*)d_in[22];
  const float* qW_bp = (const float*)d_in[23];
  const float* projW = (const float*)d_in[24];
  const float* projB = (const float*)d_in[25];
  float* out = (float*)d_out;

  int fmode = 0;
  if (out_size == 12152) fmode = 1;
  else if (out_size == 9464) fmode = 2;

  const size_t nF = (size_t)NOUT_ * NIN_ * FN_;      // F-noise float2 count
  const size_t nW = (size_t)NOUT_ * WN_;             // W-noise float2 count
  const size_t need = (nF + nW + WN_ + FN_ + WN_ + 1280 + 32) * sizeof(float2)
                    + (TSZ_ + 4032 + 272 + 112 + 112 + 112 + 4) * sizeof(float);
  const int useWs = (d_ws != nullptr && ws_size >= need) ? 1 : 0;

  float2* wsF  = (float2*)d_ws;
  float2* wsW  = wsF + nF;
  float2* wsIW = wsW + nW;
  float*  wsT  = (float*)(wsIW + WN_);
  float*  wsU  = wsT + TSZ_;
  float*  wsC  = wsU + 4032;
  float2* wsFst = (float2*)(wsC + 272);
  float2* wsWst = wsFst + FN_;
  float2* wsdF  = wsWst + WN_;
  float2* wsdW  = wsdF + 1280;
  float*  wsFeatA = (float*)(wsdW + 32);
  float*  wsFeatG = wsFeatA + 112;
  float*  wsPart  = wsFeatG + 112;

  if (useWs){
    rng_kernel<<<dim3(NOUT_ + 1 + 21 + 1), dim3(1024), 0, stream>>>(
        wsF, wsW, wsIW, wsT, wsU, wsC, wsFst, wsWst,
        H_re, H_im, R_re, R_im, qF_qw, qW_qw,
        qF_W1, qF_W2, qF_W3, qF_Wp, qW_W1, qW_W2, qW_W3, qW_Wp);
    // init: normalize + slot-0 metrics + features for it=0
    k_update<<<dim3(B_), dim3(128), 0, stream>>>(
        H_re, H_im, R_re, R_im, Pt, stp, wsF, wsW, wsdF, wsdW,
        wsFst, wsWst, wsFeatA, wsFeatG, wsPart, out, 0, 0);
    for (int it = 0; it < NOUT_; ++it){
      k_qblock2<<<dim3(21), dim3(128), 0, stream>>>(
          wsT, wsU, wsC, wsFeatA, wsFeatG, wsPart, projW, projB,
          qF_b1, qF_b2, qF_b3, qF_bp, qW_b1, qW_b2, qW_b3, qW_bp,
          wsdF, wsdW);
      k_update<<<dim3(B_), dim3(128), 0, stream>>>(
          H_re, H_im, R_re, R_im, Pt, stp, wsF, wsW, wsdF, wsdW,
          wsFst, wsWst, wsFeatA, wsFeatG, wsPart, out, it, 1);
    }
    k_out<<<dim3(1), dim3(1024), 0, stream>>>(wsFst, wsWst, out, fmode);
  } else {
    main_kernel<<<dim3(1), dim3(1024), 0, stream>>>(
        H_re, H_im, R_re, R_im, Pt, stp,
        qF_W1, qF_b1, qF_W2, qF_b2, qF_W3, qF_b3, qF_qw, qF_Wp, qF_bp,
        qW_W1, qW_b1, qW_W2, qW_b2, qW_W3, qW_b3, qW_qw, qW_Wp, qW_bp,
        projW, projB, out, fmode);
  }
}

// Round 9
// 2492.993 us; speedup vs baseline: 4.1884x; 1.6247x over previous
//
#include <hip/hip_runtime.h>
#include <stdint.h>

// ===================== problem dimensions =====================
#define NT_   16
#define NRF_  4
#define K_    4
#define M_    2
#define B_    28
#define NOUT_ 120
#define NIN_  20
#define FN_   1792   // NT*B*NRF   (complex F elements)
#define WN_   896    // K*B*NRF*M  (complex W elements)
#define XN_   3584   // K*B*NT*M   (complex X elements)
#define TJOB_ 8704
#define TSZ_  (21*TJOB_)
// output float32 offsets (rates[28,121], taus[28,121], then F, W)
#define O_TAUS 3388
#define O_F    6776
#define O_W    10360

typedef float2 cf;
__device__ __forceinline__ cf cmul(cf a, cf b){ return make_float2(a.x*b.x - a.y*b.y, a.x*b.y + a.y*b.x); }
__device__ __forceinline__ cf cmulc(cf a, cf b){ return make_float2(a.x*b.x + a.y*b.y, a.y*b.x - a.x*b.y); } // a*conj(b)
__device__ __forceinline__ cf cadd(cf a, cf b){ return make_float2(a.x + b.x, a.y + b.y); }
__device__ __forceinline__ cf csc(float s, cf a){ return make_float2(s*a.x, s*a.y); }
__device__ __forceinline__ cf shflc(cf v, int m){ return make_float2(__shfl_xor(v.x, m, 64), __shfl_xor(v.y, m, 64)); }

// ===================== threefry2x32 (JAX-compatible) =====================
__device__ __forceinline__ uint32_t rotl32(uint32_t x, int r){ return (x << r) | (x >> (32 - r)); }

__device__ __forceinline__ void threefry(uint32_t k0, uint32_t k1, uint32_t x0, uint32_t x1,
                                         uint32_t &o0, uint32_t &o1){
  uint32_t ks2 = k0 ^ k1 ^ 0x1BD11BDAu;
  x0 += k0; x1 += k1;
#define TF4(a,b,c,d) \
  x0 += x1; x1 = rotl32(x1,(a)); x1 ^= x0; \
  x0 += x1; x1 = rotl32(x1,(b)); x1 ^= x0; \
  x0 += x1; x1 = rotl32(x1,(c)); x1 ^= x0; \
  x0 += x1; x1 = rotl32(x1,(d)); x1 ^= x0;
  TF4(13,15,26,6)  x0 += k1;  x1 += ks2 + 1u;
  TF4(17,29,16,24) x0 += ks2; x1 += k0 + 2u;
  TF4(13,15,26,6)  x0 += k0;  x1 += k1 + 3u;
  TF4(17,29,16,24) x0 += k1;  x1 += ks2 + 4u;
  TF4(13,15,26,6)  x0 += ks2; x1 += k0 + 5u;
#undef TF4
  o0 = x0; o1 = x1;
}

__device__ __forceinline__ void ksplit(uint2 k, uint2 &ka, uint2 &kb){
  threefry(k.x, k.y, 0u, 0u, ka.x, ka.y);
  threefry(k.x, k.y, 0u, 1u, kb.x, kb.y);
}
__device__ __forceinline__ uint2 kfold(uint2 k, uint32_t d){
  uint2 r; threefry(k.x, k.y, 0u, d, r.x, r.y); return r;
}
__device__ __forceinline__ uint32_t rbits(uint2 k, uint32_t i){
  uint32_t a, b; threefry(k.x, k.y, 0u, i, a, b); return a ^ b;
}

__device__ __forceinline__ float bits_to_unit(uint32_t b){
  return __uint_as_float((b >> 9) | 0x3f800000u) - 1.0f;  // [0,1)
}

// XLA (Giles 2012) float32 erf_inv
__device__ __forceinline__ float erfinv_f32(float x){
  float w = -log1pf(-x * x);
  float p;
  if (w < 5.0f){
    w = w - 2.5f;
    p =  2.81022636e-08f;
    p = fmaf(p, w,  3.43273939e-07f);
    p = fmaf(p, w, -3.5233877e-06f);
    p = fmaf(p, w, -4.39150654e-06f);
    p = fmaf(p, w,  0.00021858087f);
    p = fmaf(p, w, -0.00125372503f);
    p = fmaf(p, w, -0.00417768164f);
    p = fmaf(p, w,  0.246640727f);
    p = fmaf(p, w,  1.50140941f);
  } else {
    w = sqrtf(w) - 3.0f;
    p = -0.000200214257f;
    p = fmaf(p, w,  0.000100950558f);
    p = fmaf(p, w,  0.00134934322f);
    p = fmaf(p, w, -0.00367342844f);
    p = fmaf(p, w,  0.00573950773f);
    p = fmaf(p, w, -0.0076224613f);
    p = fmaf(p, w,  0.00943887047f);
    p = fmaf(p, w,  1.00167406f);
    p = fmaf(p, w,  2.83297682f);
  }
  return p * x;
}

#define SQRT2F 1.41421356f

__device__ __forceinline__ float normal_from_bits(uint32_t b){
  const float lo = -0.99999994f;              // nextafter(-1, 0) in f32
  float u = bits_to_unit(b);
  float v = fmaxf(lo, u * 2.0f + lo);
  return SQRT2F * erfinv_f32(v);
}

__device__ __forceinline__ cf cnormal(uint2 kre, uint2 kim, uint32_t e){
  float re = normal_from_bits(rbits(kre, e));
  float im = normal_from_bits(rbits(kim, e));
  return make_float2(re / SQRT2F, im / SQRT2F);
}

__device__ void noise_key_chain(uint32_t it, uint2 *out){
  uint2 k = kfold(make_uint2(0u, 7u), it);    // fold_in(key(7), it)
  for (int j = 0; j < NIN_; ++j){
    uint2 kk, kn;
    ksplit(k, kk, kn);
    k = kk;
    ksplit(kn, out[2*j], out[2*j + 1]);
  }
  uint2 k2, knW;
  ksplit(k, k2, knW);
  ksplit(knW, out[40], out[41]);
}

// ===================== setup kernel =====================
// grid: [0,480): F-noise quarter-blocks (it = bi>>2, q = bi&3; q==0 also does W-noise)
//        480: init F/W ; 481..501: weight transpose ; 502: unitaries + const features
#define QELEM_ ((NIN_*FN_)/4)   // 8960
__global__ __launch_bounds__(1024)
void rng_kernel(float2* __restrict__ wsF, float2* __restrict__ wsW,
                float2* __restrict__ wsIW,
                float* __restrict__ wsT, float* __restrict__ wsU,
                float* __restrict__ wsC, float2* __restrict__ wsFst,
                float2* __restrict__ wsWst,
                const float* __restrict__ H_re, const float* __restrict__ H_im,
                const float* __restrict__ R_re, const float* __restrict__ R_im,
                const float* __restrict__ qF_qw, const float* __restrict__ qW_qw,
                const float* __restrict__ qF_W1, const float* __restrict__ qF_W2,
                const float* __restrict__ qF_W3, const float* __restrict__ qF_Wp,
                const float* __restrict__ qW_W1, const float* __restrict__ qW_W2,
                const float* __restrict__ qW_W3, const float* __restrict__ qW_Wp){
  __shared__ uint2 keys[42];
  const int bi = blockIdx.x, t = threadIdx.x;
  if (bi < 4*NOUT_){
    const int it = bi >> 2, q = bi & 3;
    if (t == 0) noise_key_chain((uint32_t)it, keys);
    __syncthreads();
    const int base = q*QELEM_;
    for (int idx = base + t; idx < base + QELEM_; idx += 1024){
      int j = idx / FN_, e = idx - j*FN_;
      wsF[(size_t)it*(NIN_*FN_) + idx] = cnormal(keys[2*j], keys[2*j + 1], (uint32_t)e);
    }
    if (q == 0){
      for (int e = t; e < WN_; e += 1024)
        wsW[(size_t)it*WN_ + e] = cnormal(keys[40], keys[41], (uint32_t)e);
    }
  } else if (bi == 4*NOUT_){
    if (t == 0){
      uint2 k1, k2;
      ksplit(make_uint2(0u, 1u), k1, k2);
      keys[0] = k1;
      ksplit(k2, keys[1], keys[2]);
    }
    __syncthreads();
    const float TWOPI = 6.28318530717958647692f;
    for (int e = t; e < FN_; e += 1024){
      float u = bits_to_unit(rbits(keys[0], (uint32_t)e));
      float ph = fmaxf(0.0f, u * TWOPI);
      float s, c; sincosf(ph, &s, &c);
      wsFst[e] = make_float2(c, s);
    }
    for (int e = t; e < WN_; e += 1024){
      cf w = cnormal(keys[1], keys[2], (uint32_t)e);
      wsIW[e] = w;
      wsWst[e] = w;
    }
  } else if (bi < 4*NOUT_ + 1 + 21){
    const int j = bi - (4*NOUT_ + 1);
    const bool isW = (j == 20);
    const float* W1 = isW ? qW_W1 : qF_W1 + j*(64*80);
    const float* W2 = isW ? qW_W2 : qF_W2 + j*(32*64);
    const float* W3 = isW ? qW_W3 : qF_W3 + j*(16*32);
    const float* Wp = isW ? qW_Wp : qF_Wp + j*(128*8);
    float* dst = wsT + j*TJOB_;
    for (int idx = t; idx < 5120; idx += 1024){
      int q = idx >> 6, i = idx & 63;
      dst[idx] = W1[i*80 + q];
    }
    for (int idx = t; idx < 2048; idx += 1024){
      int q = idx >> 5, i = idx & 31;
      dst[5120 + idx] = W2[i*64 + q];
    }
    for (int idx = t; idx < 512; idx += 1024){
      int q = idx >> 4, i = idx & 15;
      dst[7168 + idx] = W3[i*32 + q];
    }
    const int nOut = isW ? 64 : 128;
    for (int idx = t; idx < 8*nOut; idx += 1024){
      int z = idx / nOut, o = idx - z*nOut;
      dst[7680 + z*128 + o] = Wp[o*8 + z];
    }
  } else {
    if (t < 504){
      int j = t / 24, gg = t - j*24;
      const float* qw = (j == 20) ? qW_qw : qF_qw + j*72;
      float phi = qw[gg*3], th = qw[gg*3 + 1], om = qw[gg*3 + 2];
      float sh, ch; sincosf(0.5f*th, &sh, &ch);
      float sp, cp; sincosf(0.5f*(phi + om), &sp, &cp);
      float sm, cm; sincosf(0.5f*(phi - om), &sm, &cm);
      float* u = wsU + t*8;
      u[0] =  ch*cp; u[1] = -ch*sp;
      u[2] = -sh*cm; u[3] = -sh*sm;
      u[4] =  sh*cm; u[5] = -sh*sm;
      u[6] =  ch*cp; u[7] =  ch*sp;
    } else if (t < 520){
      int n = t - 504;
      float s = 0.f;
      for (int kbm = 0; kbm < 224; ++kbm){
        float re = H_re[kbm*16 + n], im = H_im[kbm*16 + n];
        s += sqrtf(re*re + im*im);
      }
      wsC[n] = s * (1.0f/224.0f);
    } else if (t < 776){
      int nv = t - 520;
      float s = 0.f;
      for (int kb = 0; kb < 112; ++kb){
        float re = R_re[kb*256 + nv], im = R_im[kb*256 + nv];
        s += sqrtf(re*re + im*im);
      }
      wsC[16 + nv] = s * (1.0f/112.0f);
    }
  }
}

// ===================== 8-qubit circuit =====================
__device__ __forceinline__ void gate(int q, cf u00, cf u01, cf u10, cf u11,
                                     cf &a0, cf &a1, cf &a2, cf &a3, int lane){
  if (q == 7){
    cf n0 = cadd(cmul(u00, a0), cmul(u01, a1));
    cf n1 = cadd(cmul(u10, a0), cmul(u11, a1));
    cf n2 = cadd(cmul(u00, a2), cmul(u01, a3));
    cf n3 = cadd(cmul(u10, a2), cmul(u11, a3));
    a0 = n0; a1 = n1; a2 = n2; a3 = n3;
  } else if (q == 6){
    cf n0 = cadd(cmul(u00, a0), cmul(u01, a2));
    cf n2 = cadd(cmul(u10, a0), cmul(u11, a2));
    cf n1 = cadd(cmul(u00, a1), cmul(u01, a3));
    cf n3 = cadd(cmul(u10, a1), cmul(u11, a3));
    a0 = n0; a1 = n1; a2 = n2; a3 = n3;
  } else {
    const int m = 1 << (5 - q);
    const bool hi = (lane & m) != 0;
    cf cO = hi ? u11 : u00;
    cf cP = hi ? u10 : u01;
    cf p0 = shflc(a0, m), p1 = shflc(a1, m), p2 = shflc(a2, m), p3 = shflc(a3, m);
    a0 = cadd(cmul(cO, a0), cmul(cP, p0));
    a1 = cadd(cmul(cO, a1), cmul(cP, p1));
    a2 = cadd(cmul(cO, a2), cmul(cP, p2));
    a3 = cadd(cmul(cO, a3), cmul(cP, p3));
  }
}

__device__ void run_circuit2(const float* trig, const float* uni, int lane, float z[8]){
  cf a0 = make_float2(lane == 0 ? 1.f : 0.f, 0.f);
  cf a1 = make_float2(0.f, 0.f), a2 = make_float2(0.f, 0.f), a3 = make_float2(0.f, 0.f);
  #pragma unroll
  for (int i = 0; i < 8; ++i){
    float sh = trig[2*i],      ch = trig[2*i + 1];
    float sp = trig[16 + 2*i], cp = trig[16 + 2*i + 1];
    float sm = trig[32 + 2*i], cm = trig[32 + 2*i + 1];
    cf u00 = make_float2( ch*cp, -ch*sp);
    cf u11 = make_float2( ch*cp,  ch*sp);
    cf u01 = make_float2(-sh*cm, -sh*sm);
    cf u10 = make_float2( sh*cm, -sh*sm);
    gate(i, u00, u01, u10, u11, a0, a1, a2, a3, lane);
  }
  for (int l = 0; l < 3; ++l){
    #pragma unroll
    for (int i = 0; i < 8; ++i){
      const float* u = uni + (l*8 + i)*8;
      gate(i, make_float2(u[0], u[1]), make_float2(u[2], u[3]),
              make_float2(u[4], u[5]), make_float2(u[6], u[7]), a0, a1, a2, a3, lane);
    }
    #pragma unroll
    for (int i = 0; i < 5; ++i){
      const int cm_ = 1 << (5 - i), tm = 1 << (4 - i);
      const bool c = (lane & cm_) != 0;
      cf p0 = shflc(a0, tm), p1 = shflc(a1, tm), p2 = shflc(a2, tm), p3 = shflc(a3, tm);
      a0 = c ? p0 : a0; a1 = c ? p1 : a1; a2 = c ? p2 : a2; a3 = c ? p3 : a3;
    }
    {
      const bool c = (lane & 1) != 0;
      cf t0 = c ? a2 : a0, t2 = c ? a0 : a2;
      cf t1 = c ? a3 : a1, t3 = c ? a1 : a3;
      a0 = t0; a1 = t1; a2 = t2; a3 = t3;
    }
    { cf tmp = a2; a2 = a3; a3 = tmp; }
    a1 = shflc(a1, 32);
    a3 = shflc(a3, 32);
  }
  const float p0 = a0.x*a0.x + a0.y*a0.y;
  const float p1 = a1.x*a1.x + a1.y*a1.y;
  const float p2 = a2.x*a2.x + a2.y*a2.y;
  const float p3 = a3.x*a3.x + a3.y*a3.y;
  const float tot = p0 + p1 + p2 + p3;
  z[6] = (p0 + p1) - (p2 + p3);
  z[7] = (p0 + p2) - (p1 + p3);
  #pragma unroll
  for (int i = 0; i < 6; ++i)
    z[i] = ((lane >> (5 - i)) & 1) ? -tot : tot;
  #pragma unroll
  for (int m = 1; m < 64; m <<= 1){
    #pragma unroll
    for (int i = 0; i < 8; ++i) z[i] += __shfl_xor(z[i], m, 64);
  }
}

// ===================== K2: feature-assemble + projection + MLP + circuit (21 WGs x 640) =====================
__global__ __launch_bounds__(640)
void k_qblock2(const float* __restrict__ wsT, const float* __restrict__ wsU,
               const float* __restrict__ wsC,
               const float* __restrict__ wsFeatA, const float* __restrict__ wsFeatG,
               const float* __restrict__ wsPart,
               const float* __restrict__ projW, const float* __restrict__ projB,
               const float* __restrict__ qF_b1, const float* __restrict__ qF_b2,
               const float* __restrict__ qF_b3, const float* __restrict__ qF_bp,
               const float* __restrict__ qW_b1, const float* __restrict__ qW_b2,
               const float* __restrict__ qW_b3, const float* __restrict__ qW_bp,
               float2* __restrict__ wsdF, float2* __restrict__ wsdW){
  const int j = blockIdx.x;
  const int t = threadIdx.x;
  const int lane = t & 63;
  const int wv = t >> 6;            // 0..9
  const bool isW = (j == 20);
  __shared__ float sS[500];
  __shared__ float sSt[80];
  __shared__ float mlp[160];
  __shared__ float luni[192];
  for (int i = t; i < 192; i += 640) luni[i] = wsU[j*192 + i];
  // assemble sS[500] (identical values/order to R6-persist phase A, proven)
  for (int i = t; i < 112; i += 640){ sS[i] = wsFeatA[i]; sS[112 + i] = wsFeatG[i]; }
  if (t < 4){
    float s = 0.f;
    for (int bb = 0; bb < 28; ++bb) s += wsPart[bb*4 + t];
    sS[224 + t] = s * (1.0f/448.0f);
  }
  for (int i = t; i < 272; i += 640) sS[228 + i] = wsC[i];
  __syncthreads();
  // projection: 10 rounds, one per wave (mapping == R5 k_state's t<640 layout:
  // o = t>>3, i = t&7 -> bit-identical fma order). Compile-time trip count so
  // loads pipeline.
  {
    int o = wv*8 + (lane >> 3), i = lane & 7;
    const float* row = projW + o*500;
    float acc = 0.f;
    #pragma unroll
    for (int s = 0; s < 63; ++s){
      int j2 = i + 8*s;
      if (j2 < 500) acc = fmaf(sS[j2], row[j2], acc);
    }
    #pragma unroll
    for (int m = 1; m < 8; m <<= 1) acc += __shfl_xor(acc, m, 64);
    if (i == 0) sSt[o] = acc + projB[o];
  }
  __syncthreads();

  if (t < 64){
    const float* b1 = isW ? qW_b1 : qF_b1 + j*64;
    const float* b2 = isW ? qW_b2 : qF_b2 + j*32;
    const float* b3 = isW ? qW_b3 : qF_b3 + j*16;
    const float* bp = isW ? qW_bp : qF_bp + j*128;
    const float* w1t = wsT + j*TJOB_;
    const float* w2t = w1t + 5120;
    const float* w3t = w1t + 7168;
    const float* wpt = w1t + 7680;

    { // h1[64]
      float acc = b1[lane];
      for (int q = 0; q < 80; ++q) acc = fmaf(w1t[q*64 + lane], sSt[q], acc);
      mlp[lane] = tanhf(acc);
    }
    __builtin_amdgcn_wave_barrier();
    { // h2[32]
      int i2 = lane & 31;
      float acc = b2[i2];
      for (int q = 0; q < 64; ++q) acc = fmaf(w2t[q*32 + i2], mlp[q], acc);
      float h2 = tanhf(acc);
      __builtin_amdgcn_wave_barrier();
      if (lane < 32) mlp[64 + lane] = h2;
    }
    __builtin_amdgcn_wave_barrier();
    { // ang[16]
      int i3 = lane & 15;
      float acc = b3[i3];
      for (int q = 0; q < 32; ++q) acc = fmaf(w3t[q*16 + i3], mlp[64 + q], acc);
      __builtin_amdgcn_wave_barrier();
      if (lane < 16) mlp[96 + lane] = acc;
    }
    __builtin_amdgcn_wave_barrier();
    if (lane < 24){
      int i = lane & 7, which = lane >> 3;
      float th = mlp[96 + i], om = mlp[96 + 8 + i];
      float arg = (which == 0) ? 0.5f*th
                : (which == 1) ? 0.5f*(0.f + om)
                               : 0.5f*(0.f - om);
      float s, c; sincosf(arg, &s, &c);
      mlp[112 + which*16 + 2*i]     = s;
      mlp[112 + which*16 + 2*i + 1] = c;
    }
    __builtin_amdgcn_wave_barrier();
    float z[8];
    run_circuit2(mlp + 112, luni, lane, z);
    if (!isW){
      float o0 = bp[lane];
      float o1 = bp[64 + lane];
      #pragma unroll
      for (int i = 0; i < 8; ++i){
        o0 = fmaf(wpt[i*128 + lane],      z[i], o0);
        o1 = fmaf(wpt[i*128 + 64 + lane], z[i], o1);
      }
      __builtin_amdgcn_wave_barrier();
      mlp[lane] = o0; mlp[64 + lane] = o1;
      __builtin_amdgcn_wave_barrier();
      wsdF[j*64 + lane] = make_float2(mlp[2*lane], mlp[2*lane + 1]);
    } else {
      float o0 = bp[lane];
      #pragma unroll
      for (int i = 0; i < 8; ++i) o0 = fmaf(wpt[i*128 + lane], z[i], o0);
      __builtin_amdgcn_wave_barrier();
      mlp[lane] = o0;
      __builtin_amdgcn_wave_barrier();
      if (lane < 32) wsdW[lane] = make_float2(mlp[2*lane], mlp[2*lane + 1]);
    }
  }
}

// ===================== K3: per-b update + normalize + X + metrics + features (28 WGs x 128) =====================
__global__ __launch_bounds__(128)
void k_update(const float* __restrict__ H_re, const float* __restrict__ H_im,
              const float* __restrict__ R_re, const float* __restrict__ R_im,
              const float* __restrict__ Pt_p, const float* __restrict__ step_p,
              const float2* __restrict__ wsF, const float2* __restrict__ wsW,
              const float2* __restrict__ wsdF, const float2* __restrict__ wsdW,
              float2* __restrict__ wsFst, float2* __restrict__ wsWst,
              float* __restrict__ wsFeatA, float* __restrict__ wsFeatG,
              float* __restrict__ wsPart,
              float* __restrict__ out, int it, int mode){
  const int b = blockIdx.x;
  const int t = threadIdx.x;
  __shared__ cf lF[64];
  __shared__ cf lW[32];
  __shared__ cf lX[128];
  __shared__ float scrA[96], scrG[96];
  __shared__ float red2[2];
  __shared__ float sscale;
  __shared__ float heR[16], heI[16];
  __shared__ float sKBl[4], sKB2l[4];
  const float c1 = step_p[0] * 0.001f;
  const float Ptv = Pt_p[0];

  if (t < 64){
    const int n = t >> 2, r = t & 3;
    const int e = n*112 + b*4 + r;
    cf F = wsFst[e];
    if (mode){
      const float2* np = wsF + (size_t)it*(NIN_*FN_);
      cf nzA[10], dvA[10], nzB[10], dvB[10];
      #pragma unroll
      for (int s = 0; s < 10; ++s){ nzA[s] = np[s*FN_ + e];        dvA[s] = wsdF[s*64 + t]; }
      #pragma unroll
      for (int s = 0; s < 10; ++s){ nzB[s] = np[(10 + s)*FN_ + e]; dvB[s] = wsdF[(10 + s)*64 + t]; }
      #pragma unroll
      for (int s = 0; s < 10; ++s){
        F.x = F.x + c1*nzA[s].x + 0.001f*dvA[s].x;
        F.y = F.y + c1*nzA[s].y + 0.001f*dvA[s].y;
        float rr = sqrtf(F.x*F.x + F.y*F.y) + 1e-12f;
        F.x /= rr; F.y /= rr;
      }
      #pragma unroll
      for (int s = 0; s < 10; ++s){
        F.x = F.x + c1*nzB[s].x + 0.001f*dvB[s].x;
        F.y = F.y + c1*nzB[s].y + 0.001f*dvB[s].y;
        float rr = sqrtf(F.x*F.x + F.y*F.y) + 1e-12f;
        F.x /= rr; F.y /= rr;
      }
    }
    // _normalize
    float rr = sqrtf(F.x*F.x + F.y*F.y) + 1e-12f;
    F.x /= rr; F.y /= rr;
    lF[t] = F;
    wsFst[e] = F;
  } else if (t < 96){
    const int wi = t - 64;
    const int k = wi >> 3, ru = wi & 7;
    const int ew = (k*28 + b)*8 + ru;
    cf w = wsWst[ew];
    if (mode){
      cf nw = wsW[(size_t)it*WN_ + ew];
      cf dw = wsdW[k*8 + ru];
      w.x = w.x + c1*nw.x + 0.001f*dw.x;
      w.y = w.y + c1*nw.y + 0.001f*dw.y;
    }
    lW[wi] = w;
  }
  __syncthreads();
  // X[k,n,u] = sum_r F[n,r] W[k,r,u]
  {
    int u = t & 1, n = (t >> 1) & 15, k = t >> 5;
    const cf* fr = lF + n*4;
    const cf* wr = lW + k*8 + u;
    cf acc = cmul(fr[0], wr[0]);
    acc = cadd(acc, cmul(fr[1], wr[2]));
    acc = cadd(acc, cmul(fr[2], wr[4]));
    acc = cadd(acc, cmul(fr[3], wr[6]));
    lX[t] = acc;
  }
  __syncthreads();
  {
    float s = lX[t].x*lX[t].x + lX[t].y*lX[t].y;
    #pragma unroll
    for (int m = 1; m < 64; m <<= 1) s += __shfl_xor(s, m, 64);
    if ((t & 63) == 0) red2[t >> 6] = s;
  }
  __syncthreads();
  if (t == 0) sscale = sqrtf(Ptv / ((red2[0] + red2[1]) + 1e-12f));
  __syncthreads();
  const float sc = sscale;
  if (t < 32){
    const int k = t >> 3, ru = t & 7;
    const int ew = (k*28 + b)*8 + ru;
    cf w = csc(sc, lW[t]);
    lW[t] = w;
    wsWst[ew] = w;
  }
  lX[t] = csc(sc, lX[t]);
  __syncthreads();
  // He entries
  if (t < 16){
    const int k = t >> 2, ent = t & 3;
    const int m = ent >> 1, u = ent & 1;
    const float* hr = H_re + (k*28 + b)*32 + m*16;
    const float* hi = H_im + (k*28 + b)*32 + m*16;
    cf He = make_float2(0.f, 0.f);
    for (int n = 0; n < 16; ++n){
      cf h = make_float2(hr[n], hi[n]);
      He = cadd(He, cmul(h, lX[k*32 + n*2 + u]));
    }
    heR[t] = He.x; heI[t] = He.y;
  }
  __builtin_amdgcn_wave_barrier();
  if (t < 4){
    const int k = t;
    cf He00 = make_float2(heR[k*4 + 0], heI[k*4 + 0]);
    cf He01 = make_float2(heR[k*4 + 1], heI[k*4 + 1]);
    cf He10 = make_float2(heR[k*4 + 2], heI[k*4 + 2]);
    cf He11 = make_float2(heR[k*4 + 3], heI[k*4 + 3]);
    cf G00 = cadd(cmulc(He00, He00), cmulc(He01, He01));
    cf G01 = cadd(cmulc(He00, He10), cmulc(He01, He11));
    cf G10 = cadd(cmulc(He10, He00), cmulc(He11, He01));
    cf G11 = cadd(cmulc(He10, He10), cmulc(He11, He11));
    cf A00 = make_float2(1.f + Ptv*G00.x, Ptv*G00.y);
    cf A01 = csc(Ptv, G01);
    cf A10 = csc(Ptv, G10);
    cf A11 = make_float2(1.f + Ptv*G11.x, Ptv*G11.y);
    float detre = (A00.x*A11.x - A00.y*A11.y) - (A01.x*A10.x - A01.y*A10.y);
    sKBl[k] = log2f(fabsf(detre) + 1e-12f);
  }
  // beam error
  {
    const int k = t >> 5, i = t & 31;
    const float* rr = R_re + (k*28 + b)*256;
    const float* ri = R_im + (k*28 + b)*256;
    float acc = 0.f;
    #pragma unroll
    for (int c = 0; c < 8; ++c){
      int nv = c*32 + i;
      int n = nv >> 4, v = nv & 15;
      cf xn0 = lX[k*32 + n*2], xn1 = lX[k*32 + n*2 + 1];
      cf xv0 = lX[k*32 + v*2], xv1 = lX[k*32 + v*2 + 1];
      cf C = cadd(cmulc(xn0, xv0), cmulc(xn1, xv1));
      float dr = C.x - rr[nv], di = C.y - ri[nv];
      acc += dr*dr + di*di;
    }
    #pragma unroll
    for (int m = 1; m < 32; m <<= 1) acc += __shfl_xor(acc, m, 64);
    if (i == 0) sKB2l[k] = sqrtf(acc + 1e-12f);
  }
  __syncthreads();
  if (t == 0){
    const int slot = mode ? (it + 1) : 0;
    out[b*121 + slot] = sKBl[0] + sKBl[1] + sKBl[2] + sKBl[3];
    out[O_TAUS + b*121 + slot] = 0.25f*(sKB2l[0] + sKB2l[1] + sKB2l[2] + sKB2l[3]);
  }
  // ---- state features for next iteration (proven in R6-persist)
  if (t < 64){
    cf f = lF[t];
    scrA[t] = sqrtf(f.x*f.x + f.y*f.y);
    scrG[t] = atan2f(f.y, f.x);
  } else if (t < 96){
    cf w = lW[t - 64];
    scrA[t] = sqrtf(w.x*w.x + w.y*w.y);
    scrG[t] = atan2f(w.y, w.x);
  }
  __syncthreads();
  if (t < 8){
    int r = t & 3;
    const float* src = (t < 4) ? scrA : scrG;
    float s = 0.f;
    for (int n = 0; n < 16; ++n) s += src[n*4 + r];
    float* dst = (t < 4) ? wsFeatA : wsFeatG;
    dst[b*4 + r] = s * (1.0f/16.0f);
  } else if (t >= 8 && t < 12){
    int tt = t - 8;
    int u = tt & 1; bool isG = tt >= 2;
    const float* src = isG ? scrG : scrA;
    float s = 0.f;
    for (int i = 0; i < 16; ++i) s += src[64 + i*2 + u];
    wsPart[b*4 + tt] = s;
  }
}

// ===================== K4: final F/W serialization =====================
__global__ __launch_bounds__(1024)
void k_out(const float2* __restrict__ wsFst, const float2* __restrict__ wsWst,
           float* __restrict__ out, int fmode){
  const int t = threadIdx.x;
  if (fmode == 1){
    for (int e = t; e < FN_; e += 1024){
      out[O_F + e]       = wsFst[e].x;
      out[O_F + FN_ + e] = wsFst[e].y;
    }
    for (int e = t; e < WN_; e += 1024){
      out[O_W + e]       = wsWst[e].x;
      out[O_W + WN_ + e] = wsWst[e].y;
    }
  } else if (fmode == 2){
    for (int e = t; e < FN_; e += 1024) out[O_F + e] = wsFst[e].x;
    for (int e = t; e < WN_; e += 1024) out[O_F + FN_ + e] = wsWst[e].x;
  } else {
    for (int e = t; e < FN_; e += 1024){
      out[O_F + 2*e]     = wsFst[e].x;
      out[O_F + 2*e + 1] = wsFst[e].y;
    }
    for (int e = t; e < WN_; e += 1024){
      out[O_W + 2*e]     = wsWst[e].x;
      out[O_W + 2*e + 1] = wsWst[e].y;
    }
  }
}

// ===================== fallback: single-WG monolith (used only if ws too small) =====================
__global__ __launch_bounds__(1024)
void main_kernel(const float* __restrict__ H_re, const float* __restrict__ H_im,
                 const float* __restrict__ R_re, const float* __restrict__ R_im,
                 const float* __restrict__ Pt_p, const float* __restrict__ step_p,
                 const float* __restrict__ qF_W1, const float* __restrict__ qF_b1,
                 const float* __restrict__ qF_W2, const float* __restrict__ qF_b2,
                 const float* __restrict__ qF_W3, const float* __restrict__ qF_b3,
                 const float* __restrict__ qF_qw, const float* __restrict__ qF_Wp,
                 const float* __restrict__ qF_bp,
                 const float* __restrict__ qW_W1, const float* __restrict__ qW_b1,
                 const float* __restrict__ qW_W2, const float* __restrict__ qW_b2,
                 const float* __restrict__ qW_W3, const float* __restrict__ qW_b3,
                 const float* __restrict__ qW_qw, const float* __restrict__ qW_Wp,
                 const float* __restrict__ qW_bp,
                 const float* __restrict__ projW, const float* __restrict__ projB,
                 float* __restrict__ out, int fmode)
{
  const int t = threadIdx.x;
  const int lane = t & 63;
  const int wv = t >> 6;

  __shared__ cf sF[FN_];
  __shared__ cf sW[WN_];
  __shared__ float sS[500];
  __shared__ float sSt[80];
  __shared__ float sScale[B_];
  __shared__ float sKB[112];
  __shared__ float sKB2[112];
  __shared__ float sRed[64];
  __shared__ uint2 sKeys[42];
  __shared__ float sPar[2];
  __shared__ float sUni[21*24*8];
  __shared__ __align__(16) unsigned char uPool[XN_ * sizeof(cf)];
  cf*    sX   = (cf*)uPool;
  cf*    sdF  = (cf*)uPool;
  cf*    sdW  = (cf*)(uPool + NIN_*64*sizeof(cf));
  float* sMLP = (float*)(uPool + NIN_*64*sizeof(cf) + 32*sizeof(cf));

  if (t == 0){ sPar[0] = step_p[0]; sPar[1] = Pt_p[0]; }

  if (t < 504){
    int j = t / 24, gg = t - j*24;
    const float* qw = (j == 20) ? qW_qw : qF_qw + j*72;
    float phi = qw[gg*3], th = qw[gg*3 + 1], om = qw[gg*3 + 2];
    float sh, ch; sincosf(0.5f*th, &sh, &ch);
    float sp, cp; sincosf(0.5f*(phi + om), &sp, &cp);
    float sm, cm; sincosf(0.5f*(phi - om), &sm, &cm);
    float* u = sUni + t*8;
    u[0] =  ch*cp; u[1] = -ch*sp;
    u[2] = -sh*cm; u[3] = -sh*sm;
    u[4] =  sh*cm; u[5] = -sh*sm;
    u[6] =  ch*cp; u[7] =  ch*sp;
  }

  {
    float* scratch = (float*)uPool;
    float local = 0.f;
    for (int i = t; i < 3584; i += 1024) local += sqrtf(H_re[i]*H_re[i] + H_im[i]*H_im[i]);
    scratch[t] = local;
    __syncthreads();
    for (int s = 512; s >= 16; s >>= 1){
      if (t < s) scratch[t] += scratch[t + s];
      __syncthreads();
    }
    if (t < 16) sS[228 + t] = scratch[t] * (1.0f/224.0f);
    __syncthreads();
    local = 0.f;
    for (int i = t; i < 28672; i += 1024) local += sqrtf(R_re[i]*R_re[i] + R_im[i]*R_im[i]);
    scratch[t] = local;
    __syncthreads();
    for (int s = 512; s >= 256; s >>= 1){
      if (t < s) scratch[t] += scratch[t + s];
      __syncthreads();
    }
    if (t < 256) sS[244 + t] = scratch[t] * (1.0f/112.0f);
    __syncthreads();
  }

  {
    if (t == 0){
      uint2 k1, k2; ksplit(make_uint2(0u, 1u), k1, k2);
      sKeys[0] = k1; ksplit(k2, sKeys[1], sKeys[2]);
    }
    __syncthreads();
    const float TWOPI = 6.28318530717958647692f;
    for (int e = t; e < FN_; e += 1024){
      float u = bits_to_unit(rbits(sKeys[0], (uint32_t)e));
      float ph = fmaxf(0.0f, u * TWOPI);
      float s, c; sincosf(ph, &s, &c);
      sF[e] = make_float2(c, s);
    }
    for (int e = t; e < WN_; e += 1024) sW[e] = cnormal(sKeys[1], sKeys[2], (uint32_t)e);
  }
  __syncthreads();

  const float stepv = sPar[0], Ptv = sPar[1];
  const float c1 = stepv * 0.001f;

  for (int it = -1; it < NOUT_; ++it){
    if (it >= 0){
      if (t == 0) noise_key_chain((uint32_t)it, sKeys);
      __syncthreads();
      if (t < 112){
        float sa = 0.f, sg = 0.f;
        for (int n = 0; n < NT_; ++n){
          cf f = sF[n*112 + t];
          sa += sqrtf(f.x*f.x + f.y*f.y);
          sg += atan2f(f.y, f.x);
        }
        sS[t]       = sa * (1.0f/16.0f);
        sS[112 + t] = sg * (1.0f/16.0f);
      }
      {
        float aW = 0.f, gW = 0.f;
        if (t < WN_){
          cf w = sW[t];
          aW = sqrtf(w.x*w.x + w.y*w.y);
          gW = atan2f(w.y, w.x);
        }
        #pragma unroll
        for (int m = 2; m < 64; m <<= 1){
          aW += __shfl_xor(aW, m, 64);
          gW += __shfl_xor(gW, m, 64);
        }
        if (t < WN_ && lane < 2){
          sRed[wv*2 + lane] = aW;
          sRed[32 + wv*2 + lane] = gW;
        }
      }
      __syncthreads();
      if (t < 4){
        int u = t & 1;
        int base = (t >= 2) ? 32 : 0;
        float s = 0.f;
        for (int w = 0; w < 14; ++w) s += sRed[base + w*2 + u];
        sS[224 + t] = s * (1.0f/448.0f);
      }
      __syncthreads();
      if (t < 640){
        int o = t >> 3, i = t & 7;
        const float* row = projW + o*500;
        float acc = 0.f;
        for (int j = i; j < 500; j += 8) acc = fmaf(sS[j], row[j], acc);
        #pragma unroll
        for (int m = 1; m < 8; m <<= 1) acc += __shfl_xor(acc, m, 64);
        if (i == 0) sSt[o] = acc + projB[o];
      }
      __syncthreads();
      for (int rnd = 0; rnd < 2; ++rnd){
        int j = wv + rnd*16;
        if (j < 21){
          const bool isW = (j == 20);
          const float* b1 = isW ? qW_b1 : qF_b1 + j*64;
          const float* b2 = isW ? qW_b2 : qF_b2 + j*32;
          const float* b3 = isW ? qW_b3 : qF_b3 + j*16;
          const float* bp = isW ? qW_bp : qF_bp + j*128;
          float* mlp = sMLP + wv*160;
          const float* W1 = isW ? qW_W1 : qF_W1 + j*(64*80);
          const float* W2 = isW ? qW_W2 : qF_W2 + j*(32*64);
          const float* W3 = isW ? qW_W3 : qF_W3 + j*(16*32);
          const float* Wp = isW ? qW_Wp : qF_Wp + j*(128*8);
          {
            const float* row = W1 + lane*80;
            float acc = b1[lane];
            for (int q = 0; q < 80; ++q) acc = fmaf(row[q], sSt[q], acc);
            mlp[lane] = tanhf(acc);
          }
          __builtin_amdgcn_wave_barrier();
          {
            int i2 = lane & 31;
            const float* row = W2 + i2*64;
            float acc = b2[i2];
            for (int q = 0; q < 64; ++q) acc = fmaf(row[q], mlp[q], acc);
            float h2 = tanhf(acc);
            __builtin_amdgcn_wave_barrier();
            if (lane < 32) mlp[64 + lane] = h2;
          }
          __builtin_amdgcn_wave_barrier();
          {
            int i3 = lane & 15;
            const float* row = W3 + i3*32;
            float acc = b3[i3];
            for (int q = 0; q < 32; ++q) acc = fmaf(row[q], mlp[64 + q], acc);
            __builtin_amdgcn_wave_barrier();
            if (lane < 16) mlp[96 + lane] = acc;
          }
          __builtin_amdgcn_wave_barrier();
          if (lane < 24){
            int i = lane & 7, which = lane >> 3;
            float th = mlp[96 + i], om = mlp[96 + 8 + i];
            float arg = (which == 0) ? 0.5f*th
                      : (which == 1) ? 0.5f*(0.f + om)
                                     : 0.5f*(0.f - om);
            float s, c; sincosf(arg, &s, &c);
            mlp[112 + which*16 + 2*i]     = s;
            mlp[112 + which*16 + 2*i + 1] = c;
          }
          __builtin_amdgcn_wave_barrier();
          float z[8];
          run_circuit2(mlp + 112, sUni + j*192, lane, z);
          if (!isW){
            float o0 = bp[lane];
            float o1 = bp[64 + lane];
            const float* r0 = Wp + lane*8;
            const float* r1 = Wp + (64 + lane)*8;
            #pragma unroll
            for (int i = 0; i < 8; ++i){
              o0 = fmaf(r0[i], z[i], o0);
              o1 = fmaf(r1[i], z[i], o1);
            }
            __builtin_amdgcn_wave_barrier();
            mlp[lane] = o0; mlp[64 + lane] = o1;
            __builtin_amdgcn_wave_barrier();
            sdF[j*64 + lane] = make_float2(mlp[2*lane], mlp[2*lane + 1]);
          } else {
            float o0 = bp[lane];
            const float* r0 = Wp + lane*8;
            #pragma unroll
            for (int i = 0; i < 8; ++i) o0 = fmaf(r0[i], z[i], o0);
            __builtin_amdgcn_wave_barrier();
            mlp[lane] = o0;
            __builtin_amdgcn_wave_barrier();
            if (lane < 32) sdW[lane] = make_float2(mlp[2*lane], mlp[2*lane + 1]);
          }
        }
      }
      __syncthreads();
      if (t < 896){
        cf f0 = sF[t], f1 = sF[t + 896];
        const int dfi0 = (t/112)*4 + (t & 3);
        const int dfi1 = dfi0 + 32;
        for (int j = 0; j < NIN_; ++j){
          cf n0 = cnormal(sKeys[2*j], sKeys[2*j + 1], (uint32_t)t);
          cf n1 = cnormal(sKeys[2*j], sKeys[2*j + 1], (uint32_t)(t + 896));
          cf d0 = sdF[j*64 + dfi0], d1 = sdF[j*64 + dfi1];
          f0.x = f0.x + c1*n0.x + 0.001f*d0.x;
          f0.y = f0.y + c1*n0.y + 0.001f*d0.y;
          f1.x = f1.x + c1*n1.x + 0.001f*d1.x;
          f1.y = f1.y + c1*n1.y + 0.001f*d1.y;
          float r0 = sqrtf(f0.x*f0.x + f0.y*f0.y) + 1e-12f;
          float r1 = sqrtf(f1.x*f1.x + f1.y*f1.y) + 1e-12f;
          f0.x /= r0; f0.y /= r0;
          f1.x /= r1; f1.y /= r1;
        }
        sF[t] = f0; sF[t + 896] = f1;
      }
      if (t < 448){
        cf w0 = sW[t], w1 = sW[t + 448];
        cf n0 = cnormal(sKeys[40], sKeys[41], (uint32_t)t);
        cf n1 = cnormal(sKeys[40], sKeys[41], (uint32_t)(t + 448));
        int dwi0 = (t/224)*8 + (t & 7);
        int dwi1 = ((t + 448)/224)*8 + (t & 7);
        cf d0 = sdW[dwi0], d1 = sdW[dwi1];
        w0.x = w0.x + c1*n0.x + 0.001f*d0.x;
        w0.y = w0.y + c1*n0.y + 0.001f*d0.y;
        w1.x = w1.x + c1*n1.x + 0.001f*d1.x;
        w1.y = w1.y + c1*n1.y + 0.001f*d1.y;
        sW[t] = w0; sW[t + 448] = w1;
      }
      __syncthreads();
    }

    for (int e = t; e < FN_; e += 1024){
      cf f = sF[e];
      float r = sqrtf(f.x*f.x + f.y*f.y) + 1e-12f;
      f.x /= r; f.y /= r;
      sF[e] = f;
    }
    __syncthreads();
    for (int x = t; x < XN_; x += 1024){
      int u = x & 1, n = (x >> 1) & 15, kb = x >> 5;
      int b = kb - (kb/28)*28;
      const cf* fr = sF + n*112 + b*4;
      const cf* wr = sW + kb*8 + u;
      cf acc = cmul(fr[0], wr[0]);
      acc = cadd(acc, cmul(fr[1], wr[2]));
      acc = cadd(acc, cmul(fr[2], wr[4]));
      acc = cadd(acc, cmul(fr[3], wr[6]));
      sX[x] = acc;
    }
    __syncthreads();
    if (t < 896){
      int b = t >> 5, i = t & 31;
      float s = 0.f;
      #pragma unroll
      for (int k = 0; k < 4; ++k){
        cf v = sX[(k*28 + b)*32 + i];
        s += v.x*v.x + v.y*v.y;
      }
      #pragma unroll
      for (int m = 1; m < 32; m <<= 1) s += __shfl_xor(s, m, 64);
      if (i == 0) sScale[b] = sqrtf(Ptv / (s + 1e-12f));
    }
    __syncthreads();
    for (int e = t; e < WN_; e += 1024){
      int kb = e >> 3;
      sW[e] = csc(sScale[kb - (kb/28)*28], sW[e]);
    }
    for (int x = t; x < XN_; x += 1024){
      int kb = x >> 5;
      sX[x] = csc(sScale[kb - (kb/28)*28], sX[x]);
    }
    __syncthreads();
    if (t < 112){
      const int kb = t;
      cf He00 = make_float2(0.f,0.f), He01 = He00, He10 = He00, He11 = He00;
      const float* hr = H_re + kb*32;
      const float* hi = H_im + kb*32;
      for (int n = 0; n < 16; ++n){
        cf x0 = sX[kb*32 + n*2], x1 = sX[kb*32 + n*2 + 1];
        cf h0 = make_float2(hr[n],      hi[n]);
        cf h1 = make_float2(hr[16 + n], hi[16 + n]);
        He00 = cadd(He00, cmul(h0, x0));
        He01 = cadd(He01, cmul(h0, x1));
        He10 = cadd(He10, cmul(h1, x0));
        He11 = cadd(He11, cmul(h1, x1));
      }
      cf G00 = cadd(cmulc(He00, He00), cmulc(He01, He01));
      cf G01 = cadd(cmulc(He00, He10), cmulc(He01, He11));
      cf G10 = cadd(cmulc(He10, He00), cmulc(He11, He01));
      cf G11 = cadd(cmulc(He10, He10), cmulc(He11, He11));
      cf A00 = make_float2(1.f + Ptv*G00.x, Ptv*G00.y);
      cf A01 = csc(Ptv, G01);
      cf A10 = csc(Ptv, G10);
      cf A11 = make_float2(1.f + Ptv*G11.x, Ptv*G11.y);
      float detre = (A00.x*A11.x - A00.y*A11.y) - (A01.x*A10.x - A01.y*A10.y);
      sKB[kb] = log2f(fabsf(detre) + 1e-12f);
    }
    if (t >= 128){
      int tt = t - 128, kb = tt >> 3, i = tt & 7;
      const float* rr = R_re + kb*256;
      const float* ri = R_im + kb*256;
      float acc = 0.f;
      for (int c = 0; c < 32; ++c){
        int nv = i + (c << 3);
        int n = nv >> 4, v = nv & 15;
        cf xn0 = sX[kb*32 + n*2], xn1 = sX[kb*32 + n*2 + 1];
        cf xv0 = sX[kb*32 + v*2], xv1 = sX[kb*32 + v*2 + 1];
        cf C = cadd(cmulc(xn0, xv0), cmulc(xn1, xv1));
        float dr = C.x - rr[nv], di = C.y - ri[nv];
        acc += dr*dr + di*di;
      }
      #pragma unroll
      for (int m = 1; m < 8; m <<= 1) acc += __shfl_xor(acc, m, 64);
      if (i == 0) sKB2[kb] = sqrtf(acc + 1e-12f);
    }
    __syncthreads();
    if (t < 28){
      const int slot = it + 1;
      out[t*121 + slot] = sKB[t] + sKB[28 + t] + sKB[56 + t] + sKB[84 + t];
      out[O_TAUS + t*121 + slot] = 0.25f*(sKB2[t] + sKB2[28 + t] + sKB2[56 + t] + sKB2[84 + t]);
    }
    __syncthreads();
  }

  if (fmode == 1){
    for (int e = t; e < FN_; e += 1024){
      out[O_F + e]       = sF[e].x;
      out[O_F + FN_ + e] = sF[e].y;
    }
    for (int e = t; e < WN_; e += 1024){
      out[O_W + e]       = sW[e].x;
      out[O_W + WN_ + e] = sW[e].y;
    }
  } else if (fmode == 2){
    for (int e = t; e < FN_; e += 1024) out[O_F + e] = sF[e].x;
    for (int e = t; e < WN_; e += 1024) out[O_F + FN_ + e] = sW[e].x;
  } else {
    for (int e = t; e < FN_; e += 1024){
      out[O_F + 2*e]     = sF[e].x;
      out[O_F + 2*e + 1] = sF[e].y;
    }
    for (int e = t; e < WN_; e += 1024){
      out[O_W + 2*e]     = sW[e].x;
      out[O_W + 2*e + 1] = sW[e].y;
    }
  }
}

// ===================== host =====================
extern "C" void kernel_launch(void* const* d_in, const int* in_sizes, int n_in,
                              void* d_out, int out_size, void* d_ws, size_t ws_size,
                              hipStream_t stream){
  (void)in_sizes; (void)n_in;
  const float* H_re  = (const float*)d_in[0];
  const float* H_im  = (const float*)d_in[1];
  const float* R_re  = (const float*)d_in[2];
  const float* R_im  = (const float*)d_in[3];
  const float* Pt    = (const float*)d_in[4];
  const float* stp   = (const float*)d_in[5];
  const float* qF_W1 = (const float*)d_in[6];
  const float* qF_b1 = (const float*)d_in[7];
  const float* qF_W2 = (const float*)d_in[8];
  const float* qF_b2 = (const float*)d_in[9];
  const float* qF_W3 = (const float*)d_in[10];
  const float* qF_b3 = (const float*)d_in[11];
  const float* qF_qw = (const float*)d_in[12];
  const float* qF_Wp = (const float*)d_in[13];
  const float* qF_bp = (const float*)d_in[14];
  const float* qW_W1 = (const float*)d_in[15];
  const float* qW_b1 = (const float*)d_in[16];
  const float* qW_W2 = (const float*)d_in[17];
  const float* qW_b2 = (const float*)d_in[18];
  const float* qW_W3 = (const float*)d_in[19];
  const float* qW_b3 = (const float*)d_in[20];
  const float* qW_qw = (const float*)d_in[21];
  const float* qW_Wp = (const float*)d_in[22];
  const float* qW_bp = (const float*)d_in[23];
  const float* projW = (const float*)d_in[24];
  const float* projB = (const float*)d_in[25];
  float* out = (float*)d_out;

  int fmode = 0;
  if (out_size == 12152) fmode = 1;
  else if (out_size == 9464) fmode = 2;

  const size_t nF = (size_t)NOUT_ * NIN_ * FN_;      // F-noise float2 count
  const size_t nW = (size_t)NOUT_ * WN_;             // W-noise float2 count
  const size_t need = (nF + nW + WN_ + FN_ + WN_ + 1280 + 32) * sizeof(float2)
                    + (TSZ_ + 4032 + 272 + 112 + 112 + 112 + 4) * sizeof(float);
  const int useWs = (d_ws != nullptr && ws_size >= need) ? 1 : 0;

  float2* wsF  = (float2*)d_ws;
  float2* wsW  = wsF + nF;
  float2* wsIW = wsW + nW;
  float*  wsT  = (float*)(wsIW + WN_);
  float*  wsU  = wsT + TSZ_;
  float*  wsC  = wsU + 4032;
  float2* wsFst = (float2*)(wsC + 272);
  float2* wsWst = wsFst + FN_;
  float2* wsdF  = wsWst + WN_;
  float2* wsdW  = wsdF + 1280;
  float*  wsFeatA = (float*)(wsdW + 32);
  float*  wsFeatG = wsFeatA + 112;
  float*  wsPart  = wsFeatG + 112;

  if (useWs){
    rng_kernel<<<dim3(4*NOUT_ + 1 + 21 + 1), dim3(1024), 0, stream>>>(
        wsF, wsW, wsIW, wsT, wsU, wsC, wsFst, wsWst,
        H_re, H_im, R_re, R_im, qF_qw, qW_qw,
        qF_W1, qF_W2, qF_W3, qF_Wp, qW_W1, qW_W2, qW_W3, qW_Wp);
    // init: normalize + slot-0 metrics + features for it=0
    k_update<<<dim3(B_), dim3(128), 0, stream>>>(
        H_re, H_im, R_re, R_im, Pt, stp, wsF, wsW, wsdF, wsdW,
        wsFst, wsWst, wsFeatA, wsFeatG, wsPart, out, 0, 0);
    for (int it = 0; it < NOUT_; ++it){
      k_qblock2<<<dim3(21), dim3(640), 0, stream>>>(
          wsT, wsU, wsC, wsFeatA, wsFeatG, wsPart, projW, projB,
          qF_b1, qF_b2, qF_b3, qF_bp, qW_b1, qW_b2, qW_b3, qW_bp,
          wsdF, wsdW);
      k_update<<<dim3(B_), dim3(128), 0, stream>>>(
          H_re, H_im, R_re, R_im, Pt, stp, wsF, wsW, wsdF, wsdW,
          wsFst, wsWst, wsFeatA, wsFeatG, wsPart, out, it, 1);
    }
    k_out<<<dim3(1), dim3(1024), 0, stream>>>(wsFst, wsWst, out, fmode);
  } else {
    main_kernel<<<dim3(1), dim3(1024), 0, stream>>>(
        H_re, H_im, R_re, R_im, Pt, stp,
        qF_W1, qF_b1, qF_W2, qF_b2, qF_W3, qF_b3, qF_qw, qF_Wp, qF_bp,
        qW_W1, qW_b1, qW_W2, qW_b2, qW_W3, qW_b3, qW_qw, qW_Wp, qW_bp,
        projW, projB, out, fmode);
  }
}